// Round 5
// baseline (202.771 us; speedup 1.0000x reference)
//
#include <hip/hip_runtime.h>
#include <hip/hip_bf16.h>
#include <math.h>

#define N_NODES 50000
#define N_EDGES 800000
#define E_TOT   (N_EDGES + N_NODES)
#define IN_DIM  128
#define HID     128      // HEADS*HIDDEN (layer-1 output width)
#define ODIM    64
#define NEG     0.2f
#define NB1     ((N_NODES + 255) / 256)   // scan blocks = 196
#define NCHUNK  ((N_NODES + 31) / 32)     // 32-node chunks for MFMA GEMMs

typedef short bf16x8 __attribute__((ext_vector_type(8)));
typedef float f32x4 __attribute__((ext_vector_type(4)));
typedef float f32x2 __attribute__((ext_vector_type(2)));
typedef unsigned short ushort_t;

__device__ __forceinline__ float lrelu(float x) { return x >= 0.f ? x : NEG * x; }

// bf16 <-> f32 helpers (RNE rounding on store)
__device__ __forceinline__ unsigned short f2b(float v) {
  unsigned int b = __float_as_uint(v);
  b += 0x7fffu + ((b >> 16) & 1u);
  return (unsigned short)(b >> 16);
}
__device__ __forceinline__ float b2f(unsigned short u) {
  return __uint_as_float(((unsigned int)u) << 16);
}
__device__ __forceinline__ unsigned int f2b2(float lo, float hi) {
  union { __hip_bfloat162 h; unsigned int u; } cv;
  cv.h = __float22bfloat162_rn(make_float2(lo, hi));
  return cv.u;
}
// unpack packed 2xbf16 word
__device__ __forceinline__ float blo(unsigned int v) { return __uint_as_float(v << 16); }
__device__ __forceinline__ float bhi(unsigned int v) { return __uint_as_float(v & 0xffff0000u); }

// fp8 e4m3 (OCP) hardware converts
__device__ __forceinline__ f32x2 f8x2lo(unsigned int v) {
  return __builtin_amdgcn_cvt_pk_f32_fp8((int)v, false);
}
__device__ __forceinline__ f32x2 f8x2hi(unsigned int v) {
  return __builtin_amdgcn_cvt_pk_f32_fp8((int)v, true);
}

// ---------- edge-index dtype detection (int32 vs int64) ----------
__global__ void k_detect(const void* ei, int* flag) {
  if (threadIdx.x == 0 && blockIdx.x == 0) {
    const int* p = (const int*)ei;
    int allz = 1;
    for (int i = 0; i < 64; ++i) if (p[2 * i + 1] != 0) { allz = 0; break; }
    *flag = allz;  // 1 => buffer is int64
  }
}

__device__ __forceinline__ int e_src(const void* ei, int f, int e) {
  if (e >= N_EDGES) return e - N_EDGES;              // self loop
  return f ? (int)((const long long*)ei)[e] : ((const int*)ei)[e];
}
__device__ __forceinline__ int e_dst(const void* ei, int f, int e) {
  if (e >= N_EDGES) return e - N_EDGES;              // self loop
  return f ? (int)((const long long*)ei)[N_EDGES + e] : ((const int*)ei)[N_EDGES + e];
}

// ---------- CSR build ----------
__global__ void k_hist(const void* ei, const int* flag, int* deg, int* rank) {
  int e = blockIdx.x * 256 + threadIdx.x;
  if (e >= E_TOT) return;
  int r = atomicAdd(&deg[e_dst(ei, *flag, e)], 1);
  rank[e] = r;
}

__global__ void k_scan1(const int* __restrict__ deg, int* __restrict__ offs, int* __restrict__ bsums) {
  __shared__ int sm[256];
  int t = threadIdx.x, i = blockIdx.x * 256 + t;
  int v = (i < N_NODES) ? deg[i] : 0;
  sm[t] = v;
  __syncthreads();
  for (int o = 1; o < 256; o <<= 1) {
    int add = (t >= o) ? sm[t - o] : 0;
    __syncthreads();
    sm[t] += add;
    __syncthreads();
  }
  if (i < N_NODES) offs[i] = sm[t] - v;   // exclusive
  if (t == 255) bsums[blockIdx.x] = sm[255];
}

__global__ void k_scan2(int* bsums) {
  __shared__ int sm[256];
  int t = threadIdx.x;
  int v = (t < NB1) ? bsums[t] : 0;
  sm[t] = v;
  __syncthreads();
  for (int o = 1; o < 256; o <<= 1) {
    int add = (t >= o) ? sm[t - o] : 0;
    __syncthreads();
    sm[t] += add;
    __syncthreads();
  }
  if (t < NB1) bsums[t] = sm[t] - v;      // exclusive
}

__global__ void k_scan3(int* __restrict__ offs, const int* __restrict__ bsums) {
  int i = blockIdx.x * 256 + threadIdx.x;
  if (i < N_NODES) offs[i] += bsums[blockIdx.x];
  if (i == 0) offs[N_NODES] = E_TOT;
}

__global__ void k_scatter(const void* ei, const int* __restrict__ flag, const int* __restrict__ offs,
                          const int* __restrict__ rank, int* __restrict__ srcs) {
  int e = blockIdx.x * 256 + threadIdx.x;
  if (e >= E_TOT) return;
  int f = *flag;
  int d = e_dst(ei, f, e);
  srcs[offs[d] + rank[e]] = e_src(ei, f, e);
}

// ---------- weight prep: bf16 W^T for both layers ----------
__global__ void k_prep(const float* __restrict__ W1, const float* __restrict__ W2,
                       ushort_t* __restrict__ Wt1, ushort_t* __restrict__ Wt2) {
  int i = blockIdx.x * 256 + threadIdx.x;
  if (i < 128 * 128) { int k = i >> 7, n = i & 127; Wt1[n * 128 + k] = f2b(W1[i]); }
  if (i < 128 * 64)  { int k = i >> 6, n = i & 63;  Wt2[n * 128 + k] = f2b(W2[i]); }
}

// ---------- bf16 -> fp8 e4m3 conversion (coalesced): 8 elems/thread ----------
__global__ __launch_bounds__(256) void k_cvt(const uint4* __restrict__ in, uint2* __restrict__ out, int n8) {
  int i = blockIdx.x * 256 + threadIdx.x;
  if (i >= n8) return;
  uint4 v = in[i];
  float f0 = blo(v.x), f1 = bhi(v.x), f2 = blo(v.y), f3 = bhi(v.y);
  float f4 = blo(v.z), f5 = bhi(v.z), f6 = blo(v.w), f7 = bhi(v.w);
  int p0 = 0, p1 = 0;
  p0 = __builtin_amdgcn_cvt_pk_fp8_f32(f0, f1, p0, false);
  p0 = __builtin_amdgcn_cvt_pk_fp8_f32(f2, f3, p0, true);
  p1 = __builtin_amdgcn_cvt_pk_fp8_f32(f4, f5, p1, false);
  p1 = __builtin_amdgcn_cvt_pk_fp8_f32(f6, f7, p1, true);
  uint2 r; r.x = (unsigned int)p0; r.y = (unsigned int)p1;
  out[i] = r;
}

// ---------- MFMA GEMM1: h1b[N,128](bf16) = bf16(x[N,128]) @ W1 ----------
__global__ __launch_bounds__(256) void k_mm1(const float* __restrict__ x,
                                             const ushort_t* __restrict__ Wt,
                                             ushort_t* __restrict__ h1b) {
  __shared__ ushort_t xs[32 * 128];   // 8 KB
  int t = threadIdx.x;
  int w = t >> 6, l = t & 63;
  int lr = l & 15, lk = l >> 4;
  int nodeSub = (w & 1) * 16, colBase = (w >> 1) * 64;
  bf16x8 bfrag[4][4];
  #pragma unroll
  for (int ct = 0; ct < 4; ++ct)
    #pragma unroll
    for (int ks = 0; ks < 4; ++ks) {
      int n = colBase + ct * 16 + lr;
      int k = ks * 32 + lk * 8;
      bfrag[ct][ks] = *(const bf16x8*)&Wt[n * 128 + k];
    }
  int rr = t >> 3, c0 = (t & 7) * 16;   // staging: row, 16-elem col group
  for (int chunk = blockIdx.x; chunk < NCHUNK; chunk += gridDim.x) {
    int base = chunk * 32;
    int srcRow = base + rr; if (srcRow >= N_NODES) srcRow = N_NODES - 1;
    const float4* xr = (const float4*)&x[(size_t)srcRow * IN_DIM + c0];
    float4 f0 = xr[0], f1 = xr[1], f2 = xr[2], f3 = xr[3];
    uint4 w0, w1;
    w0.x = f2b2(f0.x, f0.y); w0.y = f2b2(f0.z, f0.w);
    w0.z = f2b2(f1.x, f1.y); w0.w = f2b2(f1.z, f1.w);
    w1.x = f2b2(f2.x, f2.y); w1.y = f2b2(f2.z, f2.w);
    w1.z = f2b2(f3.x, f3.y); w1.w = f2b2(f3.z, f3.w);
    char* xsb = (char*)xs;
    int swz = (rr & 7) << 4;
    *(uint4*)(xsb + rr * 256 + ((c0 * 2 +  0) ^ swz)) = w0;
    *(uint4*)(xsb + rr * 256 + ((c0 * 2 + 16) ^ swz)) = w1;
    __syncthreads();
    f32x4 acc[4] = {{0,0,0,0},{0,0,0,0},{0,0,0,0},{0,0,0,0}};
    int arow = nodeSub + lr;
    #pragma unroll
    for (int ks = 0; ks < 4; ++ks) {
      bf16x8 a = *(const bf16x8*)((const char*)xs + arow * 256 +
                                  ((ks * 64 + lk * 16) ^ ((arow & 7) << 4)));
      #pragma unroll
      for (int ct = 0; ct < 4; ++ct)
        acc[ct] = __builtin_amdgcn_mfma_f32_16x16x32_bf16(a, bfrag[ct][ks], acc[ct], 0, 0, 0);
    }
    __syncthreads();
    #pragma unroll
    for (int ct = 0; ct < 4; ++ct)
      #pragma unroll
      for (int r = 0; r < 4; ++r) {
        int node = base + nodeSub + lk * 4 + r;
        if (node < N_NODES)
          h1b[(size_t)node * HID + colBase + ct * 16 + lr] = f2b(acc[ct][r]);
      }
  }
}

// ---------- MFMA GEMM2: h2b[N,64](bf16) = out1b[N,128] @ W2 ----------
__global__ __launch_bounds__(256) void k_mm2(const ushort_t* __restrict__ xb,
                                             const ushort_t* __restrict__ Wt,
                                             ushort_t* __restrict__ h2b) {
  __shared__ ushort_t xs[32 * 128];   // 8 KB
  int t = threadIdx.x;
  int w = t >> 6, l = t & 63;
  int lr = l & 15, lk = l >> 4;
  int nodeSub = (w & 1) * 16, colBase = (w >> 1) * 32;
  bf16x8 bfrag[2][4];
  #pragma unroll
  for (int ct = 0; ct < 2; ++ct)
    #pragma unroll
    for (int ks = 0; ks < 4; ++ks) {
      int n = colBase + ct * 16 + lr;
      int k = ks * 32 + lk * 8;
      bfrag[ct][ks] = *(const bf16x8*)&Wt[n * 128 + k];
    }
  int rr = t >> 3, c0 = (t & 7) * 16;
  for (int chunk = blockIdx.x; chunk < NCHUNK; chunk += gridDim.x) {
    int base = chunk * 32;
    int srcRow = base + rr; if (srcRow >= N_NODES) srcRow = N_NODES - 1;
    const uint4* xr = (const uint4*)&xb[(size_t)srcRow * HID + c0];
    uint4 w0 = xr[0], w1 = xr[1];
    char* xsb = (char*)xs;
    int swz = (rr & 7) << 4;
    *(uint4*)(xsb + rr * 256 + ((c0 * 2 +  0) ^ swz)) = w0;
    *(uint4*)(xsb + rr * 256 + ((c0 * 2 + 16) ^ swz)) = w1;
    __syncthreads();
    f32x4 acc[2] = {{0,0,0,0},{0,0,0,0}};
    int arow = nodeSub + lr;
    #pragma unroll
    for (int ks = 0; ks < 4; ++ks) {
      bf16x8 a = *(const bf16x8*)((const char*)xs + arow * 256 +
                                  ((ks * 64 + lk * 16) ^ ((arow & 7) << 4)));
      #pragma unroll
      for (int ct = 0; ct < 2; ++ct)
        acc[ct] = __builtin_amdgcn_mfma_f32_16x16x32_bf16(a, bfrag[ct][ks], acc[ct], 0, 0, 0);
    }
    __syncthreads();
    #pragma unroll
    for (int ct = 0; ct < 2; ++ct)
      #pragma unroll
      for (int r = 0; r < 4; ++r) {
        int node = base + nodeSub + lk * 4 + r;
        if (node < N_NODES)
          h2b[(size_t)node * ODIM + colBase + ct * 16 + lr] = f2b(acc[ct][r]);
      }
  }
}

// ---------- attention logits: 16B loads, 8 cols/lane ----------
__global__ __launch_bounds__(256) void k_al1(const ushort_t* __restrict__ h1b,
                                             const float* __restrict__ asrc,
                                             const float* __restrict__ adst, float* __restrict__ als,
                                             float* __restrict__ ald) {
  int t = threadIdx.x;
  int n = blockIdx.x * 16 + (t >> 4);
  int c8 = (t & 15) * 8;
  uint4 v = *(const uint4*)&h1b[(size_t)n * HID + c8];
  float4 a0 = *(const float4*)&asrc[c8], a1 = *(const float4*)&asrc[c8 + 4];
  float4 d0 = *(const float4*)&adst[c8], d1 = *(const float4*)&adst[c8 + 4];
  float f0 = blo(v.x), f1 = bhi(v.x), f2 = blo(v.y), f3 = bhi(v.y);
  float f4 = blo(v.z), f5 = bhi(v.z), f6 = blo(v.w), f7 = bhi(v.w);
  float s = f0*a0.x + f1*a0.y + f2*a0.z + f3*a0.w + f4*a1.x + f5*a1.y + f6*a1.z + f7*a1.w;
  float d = f0*d0.x + f1*d0.y + f2*d0.z + f3*d0.w + f4*d1.x + f5*d1.y + f6*d1.z + f7*d1.w;
  s += __shfl_xor(s, 1); s += __shfl_xor(s, 2);
  d += __shfl_xor(d, 1); d += __shfl_xor(d, 2);
  if ((t & 3) == 0) {
    int head = (t & 15) >> 2;
    als[n * 4 + head] = s;
    ald[n * 4 + head] = d;
  }
}

__global__ __launch_bounds__(256) void k_al2(const ushort_t* __restrict__ h2b,
                                             const float* __restrict__ asrc,
                                             const float* __restrict__ adst, float* __restrict__ als,
                                             float* __restrict__ ald) {
  int t = threadIdx.x;
  int n = blockIdx.x * 32 + (t >> 3);
  if (n >= N_NODES) return;
  int c8 = (t & 7) * 8;
  uint4 v = *(const uint4*)&h2b[(size_t)n * ODIM + c8];
  float4 a0 = *(const float4*)&asrc[c8], a1 = *(const float4*)&asrc[c8 + 4];
  float4 d0 = *(const float4*)&adst[c8], d1 = *(const float4*)&adst[c8 + 4];
  float f0 = blo(v.x), f1 = bhi(v.x), f2 = blo(v.y), f3 = bhi(v.y);
  float f4 = blo(v.z), f5 = bhi(v.z), f6 = blo(v.w), f7 = bhi(v.w);
  float s = f0*a0.x + f1*a0.y + f2*a0.z + f3*a0.w + f4*a1.x + f5*a1.y + f6*a1.z + f7*a1.w;
  float d = f0*d0.x + f1*d0.y + f2*d0.z + f3*d0.w + f4*d1.x + f5*d1.y + f6*d1.z + f7*d1.w;
  s += __shfl_xor(s, 1); s += __shfl_xor(s, 2); s += __shfl_xor(s, 4);
  d += __shfl_xor(d, 1); d += __shfl_xor(d, 2); d += __shfl_xor(d, 4);
  if ((t & 7) == 0) { als[n] = s; ald[n] = d; }
}

// ---------- layer-1 softmax + aggregate: one block (128 thr) per dst node ----------
// gather from fp8 rows (128 B = 1 TCC line): 4 cols/lane via uint, 32 lanes = full row
__global__ __launch_bounds__(128) void k_agg1(const unsigned char* __restrict__ h1f8,
                                              const ushort_t* __restrict__ h1b,
                                              const float* __restrict__ als,
                                              const float* __restrict__ ald, const int* __restrict__ offs,
                                              const int* __restrict__ srcs, const float* __restrict__ b1,
                                              ushort_t* __restrict__ out1b) {
  __shared__ int sl[256];            // pre-shifted byte offsets (s*128)
  __shared__ float sw[4 * 256];
  __shared__ float redm[2][4];
  __shared__ float redd[2][4];
  __shared__ float rednum[32][4];
  int n = blockIdx.x, t = threadIdx.x;
  int w = t >> 6, l = t & 63, lane32 = l & 31;
  int off0 = offs[n], deg = offs[n + 1] - off0;

  if (deg <= 256) {
    const float4* als4 = (const float4*)als;
    float4 ad = ((const float4*)ald)[n];
    // pass A: edge-parallel logits + local max (all 4 heads per thread)
    float lm0 = -INFINITY, lm1 = -INFINITY, lm2 = -INFINITY, lm3 = -INFINITY;
    for (int j = t; j < deg; j += 128) {
      int s = srcs[off0 + j];
      sl[j] = s << 7;                // byte offset into h1f8 (128 B rows)
      float4 a = als4[s];
      float e0 = lrelu(a.x + ad.x), e1 = lrelu(a.y + ad.y);
      float e2 = lrelu(a.z + ad.z), e3 = lrelu(a.w + ad.w);
      sw[0 * 256 + j] = e0; sw[1 * 256 + j] = e1;
      sw[2 * 256 + j] = e2; sw[3 * 256 + j] = e3;
      lm0 = fmaxf(lm0, e0); lm1 = fmaxf(lm1, e1);
      lm2 = fmaxf(lm2, e2); lm3 = fmaxf(lm3, e3);
    }
    #pragma unroll
    for (int o = 32; o >= 1; o >>= 1) {
      lm0 = fmaxf(lm0, __shfl_xor(lm0, o)); lm1 = fmaxf(lm1, __shfl_xor(lm1, o));
      lm2 = fmaxf(lm2, __shfl_xor(lm2, o)); lm3 = fmaxf(lm3, __shfl_xor(lm3, o));
    }
    if (l == 0) { redm[w][0] = lm0; redm[w][1] = lm1; redm[w][2] = lm2; redm[w][3] = lm3; }
    __syncthreads();
    float m0 = fmaxf(redm[0][0], redm[1][0]), m1 = fmaxf(redm[0][1], redm[1][1]);
    float m2 = fmaxf(redm[0][2], redm[1][2]), m3 = fmaxf(redm[0][3], redm[1][3]);
    // pass B: edge-parallel exp + local denom
    float d0 = 0.f, d1 = 0.f, d2 = 0.f, d3 = 0.f;
    for (int j = t; j < deg; j += 128) {
      float w0 = __expf(sw[0 * 256 + j] - m0); sw[0 * 256 + j] = w0; d0 += w0;
      float w1 = __expf(sw[1 * 256 + j] - m1); sw[1 * 256 + j] = w1; d1 += w1;
      float w2 = __expf(sw[2 * 256 + j] - m2); sw[2 * 256 + j] = w2; d2 += w2;
      float w3 = __expf(sw[3 * 256 + j] - m3); sw[3 * 256 + j] = w3; d3 += w3;
    }
    #pragma unroll
    for (int o = 32; o >= 1; o >>= 1) {
      d0 += __shfl_xor(d0, o); d1 += __shfl_xor(d1, o);
      d2 += __shfl_xor(d2, o); d3 += __shfl_xor(d3, o);
    }
    if (l == 0) { redd[w][0] = d0; redd[w][1] = d1; redd[w][2] = d2; redd[w][3] = d3; }
    __syncthreads();
    // pass C: wide fp8 gather. group g handles edges j ≡ g (mod 4)
    int g = w * 2 + (l >> 5);
    int headIdx = lane32 >> 3;
    const float* swh = &sw[headIdx * 256];
    const unsigned char* hb = h1f8 + lane32 * 4;   // col byte offset
    float num0 = 0.f, num1 = 0.f, num2 = 0.f, num3 = 0.f;
    int j = g;
    for (; j + 4 < deg; j += 8) {
      int b0 = sl[j], b1o = sl[j + 4];
      float w0 = swh[j], w1 = swh[j + 4];
      unsigned int v0 = *(const unsigned int*)(hb + b0);
      unsigned int v1 = *(const unsigned int*)(hb + b1o);
      f32x2 lo0 = f8x2lo(v0), hi0 = f8x2hi(v0);
      f32x2 lo1 = f8x2lo(v1), hi1 = f8x2hi(v1);
      num0 = fmaf(w0, lo0.x, num0); num1 = fmaf(w0, lo0.y, num1);
      num2 = fmaf(w0, hi0.x, num2); num3 = fmaf(w0, hi0.y, num3);
      num0 = fmaf(w1, lo1.x, num0); num1 = fmaf(w1, lo1.y, num1);
      num2 = fmaf(w1, hi1.x, num2); num3 = fmaf(w1, hi1.y, num3);
    }
    if (j < deg) {
      int b0 = sl[j];
      float w0 = swh[j];
      unsigned int v0 = *(const unsigned int*)(hb + b0);
      f32x2 lo0 = f8x2lo(v0), hi0 = f8x2hi(v0);
      num0 = fmaf(w0, lo0.x, num0); num1 = fmaf(w0, lo0.y, num1);
      num2 = fmaf(w0, hi0.x, num2); num3 = fmaf(w0, hi0.y, num3);
    }
    // combine half-waves within wave
    num0 += __shfl_xor(num0, 32); num1 += __shfl_xor(num1, 32);
    num2 += __shfl_xor(num2, 32); num3 += __shfl_xor(num3, 32);
    if (w == 1 && l < 32) {
      rednum[l][0] = num0; rednum[l][1] = num1; rednum[l][2] = num2; rednum[l][3] = num3;
    }
    __syncthreads();
    if (w == 0 && l < 32) {
      num0 += rednum[l][0]; num1 += rednum[l][1]; num2 += rednum[l][2]; num3 += rednum[l][3];
      float den = redd[0][headIdx] + redd[1][headIdx];
      int c4 = lane32 * 4;
      float4 bb = *(const float4*)&b1[c4];
      float o0 = fmaxf(num0 / den + bb.x, 0.f);
      float o1 = fmaxf(num1 / den + bb.y, 0.f);
      float o2 = fmaxf(num2 / den + bb.z, 0.f);
      float o3 = fmaxf(num3 / den + bb.w, 0.f);
      uint2 pk; pk.x = f2b2(o0, o1); pk.y = f2b2(o2, o3);
      *(uint2*)&out1b[(size_t)n * HID + c4] = pk;
    }
  } else {  // fallback (not hit at this graph size) — reads bf16 copy
    int head = t >> 5;
    float aldv = ald[n * 4 + head];
    float m = -INFINITY, den = 0.f, num = 0.f;
    for (int j = 0; j < deg; ++j)
      m = fmaxf(m, lrelu(als[srcs[off0 + j] * 4 + head] + aldv));
    for (int j = 0; j < deg; ++j) {
      int s = srcs[off0 + j];
      float wq = __expf(lrelu(als[s * 4 + head] + aldv) - m);
      den += wq;
      num = fmaf(wq, b2f(h1b[(size_t)s * HID + t]), num);
    }
    out1b[(size_t)n * HID + t] = f2b(fmaxf(num / den + b1[t], 0.f));
  }
}

// ---------- layer-2 softmax + aggregate + log_softmax: one wave per node ----------
__global__ __launch_bounds__(64) void k_agg2(const unsigned char* __restrict__ h2f8,
                                             const ushort_t* __restrict__ h2b,
                                             const float* __restrict__ als,
                                             const float* __restrict__ ald, const int* __restrict__ offs,
                                             const int* __restrict__ srcs, const float* __restrict__ b2,
                                             float* __restrict__ out) {
  __shared__ int sl[256];
  __shared__ float sw[256];
  int n = blockIdx.x, t = threadIdx.x;
  int off0 = offs[n], deg = offs[n + 1] - off0;
  float aldv = ald[n];
  if (deg <= 256) {
    float lm = -INFINITY;
    for (int j = t; j < deg; j += 64) {
      int s = srcs[off0 + j];
      sl[j] = s << 6;                 // byte offset into h2f8 (64 B rows)
      float e = lrelu(als[s] + aldv);
      sw[j] = e;
      lm = fmaxf(lm, e);
    }
    #pragma unroll
    for (int o = 32; o >= 1; o >>= 1) lm = fmaxf(lm, __shfl_xor(lm, o));
    __syncthreads();
    float ld = 0.f;
    for (int j = t; j < deg; j += 64) {
      float wq = __expf(sw[j] - lm);
      sw[j] = wq;
      ld += wq;
    }
    #pragma unroll
    for (int o = 32; o >= 1; o >>= 1) ld += __shfl_xor(ld, o);
    float den = ld;
    __syncthreads();
    // wide fp8 gather: 2 cols/lane via ushort, 2 edge groups
    int g = t >> 5, lane32 = t & 31;
    const unsigned char* hb = h2f8 + lane32 * 2;
    float num0 = 0.f, num1 = 0.f;
    int j = g;
    for (; j + 2 < deg; j += 4) {
      int b0 = sl[j], b1o = sl[j + 2];
      float w0 = sw[j], w1 = sw[j + 2];
      unsigned int v0 = *(const unsigned short*)(hb + b0);
      unsigned int v1 = *(const unsigned short*)(hb + b1o);
      f32x2 lo0 = f8x2lo(v0);
      f32x2 lo1 = f8x2lo(v1);
      num0 = fmaf(w0, lo0.x, num0); num1 = fmaf(w0, lo0.y, num1);
      num0 = fmaf(w1, lo1.x, num0); num1 = fmaf(w1, lo1.y, num1);
    }
    if (j < deg) {
      unsigned int v0 = *(const unsigned short*)(hb + sl[j]);
      float w0 = sw[j];
      f32x2 lo0 = f8x2lo(v0);
      num0 = fmaf(w0, lo0.x, num0); num1 = fmaf(w0, lo0.y, num1);
    }
    num0 += __shfl_xor(num0, 32);
    num1 += __shfl_xor(num1, 32);
    if (t < 32) {
      int c2 = lane32 * 2;
      float2 bb = *(const float2*)&b2[c2];
      float val0 = num0 / den + bb.x;
      float val1 = num1 / den + bb.y;
      float mx = fmaxf(val0, val1);
      #pragma unroll
      for (int o = 16; o >= 1; o >>= 1) mx = fmaxf(mx, __shfl_xor(mx, o));
      float sum = __expf(val0 - mx) + __expf(val1 - mx);
      #pragma unroll
      for (int o = 16; o >= 1; o >>= 1) sum += __shfl_xor(sum, o);
      float ls = __logf(sum);
      float2 res; res.x = (val0 - mx) - ls; res.y = (val1 - mx) - ls;
      *(float2*)&out[(size_t)n * ODIM + c2] = res;
    }
  } else {  // fallback — reads bf16 copy
    float lm = -INFINITY;
    float den = 0.f, num = 0.f;
    for (int j = 0; j < deg; ++j) lm = fmaxf(lm, lrelu(als[srcs[off0 + j]] + aldv));
    for (int j = 0; j < deg; ++j) {
      int s = srcs[off0 + j];
      float wq = __expf(lrelu(als[s] + aldv) - lm);
      den += wq;
      num = fmaf(wq, b2f(h2b[(size_t)s * ODIM + t]), num);
    }
    float val = num / den + b2[t];
    float mx = val;
    #pragma unroll
    for (int o = 32; o >= 1; o >>= 1) mx = fmaxf(mx, __shfl_xor(mx, o));
    float ex = __expf(val - mx);
    float sum = ex;
    #pragma unroll
    for (int o = 32; o >= 1; o >>= 1) sum += __shfl_xor(sum, o);
    out[(size_t)n * ODIM + t] = (val - mx) - __logf(sum);
  }
}

extern "C" void kernel_launch(void* const* d_in, const int* in_sizes, int n_in,
                              void* d_out, int out_size, void* d_ws, size_t ws_size,
                              hipStream_t stream) {
  const float* x   = (const float*)d_in[0];
  const void*  ei  = d_in[1];
  const float* W1  = (const float*)d_in[2];
  const float* as1 = (const float*)d_in[3];
  const float* ad1 = (const float*)d_in[4];
  const float* b1  = (const float*)d_in[5];
  const float* W2  = (const float*)d_in[6];
  const float* as2 = (const float*)d_in[7];
  const float* ad2 = (const float*)d_in[8];
  const float* b2  = (const float*)d_in[9];
  float* out = (float*)d_out;

  char* ws = (char*)d_ws;
  size_t o = 0;
  auto alloc = [&](size_t bytes) { void* p = (void*)(ws + o); o += (bytes + 255) & ~(size_t)255; return p; };
  ushort_t* h1b   = (ushort_t*)alloc((size_t)N_NODES * HID * 2);
  ushort_t* out1b = (ushort_t*)alloc((size_t)N_NODES * HID * 2);
  ushort_t* h2b   = (ushort_t*)alloc((size_t)N_NODES * ODIM * 2);
  unsigned char* h1f8 = (unsigned char*)alloc((size_t)N_NODES * HID);
  ushort_t* Wt1   = (ushort_t*)alloc((size_t)128 * 128 * 2);
  ushort_t* Wt2   = (ushort_t*)alloc((size_t)64 * 128 * 2);
  float* als1 = (float*)alloc((size_t)N_NODES * 4 * 4);
  float* ald1 = (float*)alloc((size_t)N_NODES * 4 * 4);
  float* als2 = (float*)alloc((size_t)N_NODES * 4);
  float* ald2 = (float*)alloc((size_t)N_NODES * 4);
  int*   deg  = (int*)alloc((size_t)N_NODES * 4);
  int*   offs = (int*)alloc((size_t)(N_NODES + 1) * 4);
  int*   rank = (int*)alloc((size_t)E_TOT * 4);
  int*   srcs = (int*)alloc((size_t)E_TOT * 4);
  int*   bsums= (int*)alloc((size_t)NB1 * 4);
  int*   flag = (int*)alloc(4);
  // h2f8 (3.2 MB) aliases rank (3.4 MB): rank is dead after k_scatter
  unsigned char* h2f8 = (unsigned char*)rank;

  hipMemsetAsync(deg, 0, (size_t)N_NODES * 4, stream);
  k_detect<<<1, 64, 0, stream>>>(ei, flag);

  int egrid = (E_TOT + 255) / 256;
  k_hist   <<<egrid, 256, 0, stream>>>(ei, flag, deg, rank);
  k_scan1  <<<NB1,   256, 0, stream>>>(deg, offs, bsums);
  k_scan2  <<<1,     256, 0, stream>>>(bsums);
  k_scan3  <<<NB1,   256, 0, stream>>>(offs, bsums);
  k_scatter<<<egrid, 256, 0, stream>>>(ei, flag, offs, rank, srcs);
  k_prep   <<<64,    256, 0, stream>>>(W1, W2, Wt1, Wt2);

  k_mm1  <<<512, 256, 0, stream>>>(x, Wt1, h1b);
  k_cvt  <<<(N_NODES * HID / 8 + 255) / 256, 256, 0, stream>>>((const uint4*)h1b, (uint2*)h1f8, N_NODES * HID / 8);
  k_al1  <<<N_NODES / 16, 256, 0, stream>>>(h1b, as1, ad1, als1, ald1);
  k_agg1 <<<N_NODES, 128, 0, stream>>>(h1f8, h1b, als1, ald1, offs, srcs, b1, out1b);

  k_mm2  <<<512, 256, 0, stream>>>(out1b, Wt2, h2b);
  k_cvt  <<<(N_NODES * ODIM / 8 + 255) / 256, 256, 0, stream>>>((const uint4*)h2b, (uint2*)h2f8, N_NODES * ODIM / 8);
  k_al2  <<<(N_NODES + 31) / 32, 256, 0, stream>>>(h2b, as2, ad2, als2, ald2);
  k_agg2 <<<N_NODES, 64, 0, stream>>>(h2f8, h2b, als2, ald2, offs, srcs, b2, out);
}

// Round 6
// 198.749 us; speedup vs baseline: 1.0202x; 1.0202x over previous
//
#include <hip/hip_runtime.h>
#include <hip/hip_bf16.h>
#include <math.h>

#define N_NODES 50000
#define N_EDGES 800000
#define E_TOT   (N_EDGES + N_NODES)
#define IN_DIM  128
#define HID     128      // HEADS*HIDDEN (layer-1 output width)
#define ODIM    64
#define NEG     0.2f
#define NB1     ((N_NODES + 255) / 256)   // scan blocks = 196
#define NCHUNK  ((N_NODES + 31) / 32)     // 32-node chunks for MFMA GEMMs

typedef short bf16x8 __attribute__((ext_vector_type(8)));
typedef float f32x4 __attribute__((ext_vector_type(4)));
typedef float f32x2 __attribute__((ext_vector_type(2)));
typedef unsigned short ushort_t;

__device__ __forceinline__ float lrelu(float x) { return x >= 0.f ? x : NEG * x; }

// bf16 <-> f32 helpers (RNE rounding on store)
__device__ __forceinline__ unsigned short f2b(float v) {
  unsigned int b = __float_as_uint(v);
  b += 0x7fffu + ((b >> 16) & 1u);
  return (unsigned short)(b >> 16);
}
__device__ __forceinline__ float b2f(unsigned short u) {
  return __uint_as_float(((unsigned int)u) << 16);
}
__device__ __forceinline__ unsigned int f2b2(float lo, float hi) {
  union { __hip_bfloat162 h; unsigned int u; } cv;
  cv.h = __float22bfloat162_rn(make_float2(lo, hi));
  return cv.u;
}
// unpack packed 2xbf16 word
__device__ __forceinline__ float blo(unsigned int v) { return __uint_as_float(v << 16); }
__device__ __forceinline__ float bhi(unsigned int v) { return __uint_as_float(v & 0xffff0000u); }

// fp8 e4m3 (OCP) hardware converts
__device__ __forceinline__ f32x2 f8x2lo(unsigned int v) {
  return __builtin_amdgcn_cvt_pk_f32_fp8((int)v, false);
}
__device__ __forceinline__ f32x2 f8x2hi(unsigned int v) {
  return __builtin_amdgcn_cvt_pk_f32_fp8((int)v, true);
}

// ---------- edge-index dtype detection (int32 vs int64) ----------
__global__ void k_detect(const void* ei, int* flag) {
  if (threadIdx.x == 0 && blockIdx.x == 0) {
    const int* p = (const int*)ei;
    int allz = 1;
    for (int i = 0; i < 64; ++i) if (p[2 * i + 1] != 0) { allz = 0; break; }
    *flag = allz;  // 1 => buffer is int64
  }
}

__device__ __forceinline__ int e_src(const void* ei, int f, int e) {
  if (e >= N_EDGES) return e - N_EDGES;              // self loop
  return f ? (int)((const long long*)ei)[e] : ((const int*)ei)[e];
}
__device__ __forceinline__ int e_dst(const void* ei, int f, int e) {
  if (e >= N_EDGES) return e - N_EDGES;              // self loop
  return f ? (int)((const long long*)ei)[N_EDGES + e] : ((const int*)ei)[N_EDGES + e];
}

// ---------- CSR build ----------
__global__ void k_hist(const void* ei, const int* flag, int* deg, int* rank) {
  int e = blockIdx.x * 256 + threadIdx.x;
  if (e >= E_TOT) return;
  int r = atomicAdd(&deg[e_dst(ei, *flag, e)], 1);
  rank[e] = r;
}

__global__ void k_scan1(const int* __restrict__ deg, int* __restrict__ offs, int* __restrict__ bsums) {
  __shared__ int sm[256];
  int t = threadIdx.x, i = blockIdx.x * 256 + t;
  int v = (i < N_NODES) ? deg[i] : 0;
  sm[t] = v;
  __syncthreads();
  for (int o = 1; o < 256; o <<= 1) {
    int add = (t >= o) ? sm[t - o] : 0;
    __syncthreads();
    sm[t] += add;
    __syncthreads();
  }
  if (i < N_NODES) offs[i] = sm[t] - v;   // exclusive
  if (t == 255) bsums[blockIdx.x] = sm[255];
}

__global__ void k_scan2(int* bsums) {
  __shared__ int sm[256];
  int t = threadIdx.x;
  int v = (t < NB1) ? bsums[t] : 0;
  sm[t] = v;
  __syncthreads();
  for (int o = 1; o < 256; o <<= 1) {
    int add = (t >= o) ? sm[t - o] : 0;
    __syncthreads();
    sm[t] += add;
    __syncthreads();
  }
  if (t < NB1) bsums[t] = sm[t] - v;      // exclusive
}

__global__ void k_scan3(int* __restrict__ offs, const int* __restrict__ bsums) {
  int i = blockIdx.x * 256 + threadIdx.x;
  if (i < N_NODES) offs[i] += bsums[blockIdx.x];
  if (i == 0) offs[N_NODES] = E_TOT;
}

__global__ void k_scatter(const void* ei, const int* __restrict__ flag, const int* __restrict__ offs,
                          const int* __restrict__ rank, int* __restrict__ srcs) {
  int e = blockIdx.x * 256 + threadIdx.x;
  if (e >= E_TOT) return;
  int f = *flag;
  int d = e_dst(ei, f, e);
  srcs[offs[d] + rank[e]] = e_src(ei, f, e);
}

// ---------- weight prep: bf16 W^T for both layers ----------
__global__ void k_prep(const float* __restrict__ W1, const float* __restrict__ W2,
                       ushort_t* __restrict__ Wt1, ushort_t* __restrict__ Wt2) {
  int i = blockIdx.x * 256 + threadIdx.x;
  if (i < 128 * 128) { int k = i >> 7, n = i & 127; Wt1[n * 128 + k] = f2b(W1[i]); }
  if (i < 128 * 64)  { int k = i >> 6, n = i & 63;  Wt2[n * 128 + k] = f2b(W2[i]); }
}

// ---------- bf16 -> fp8 e4m3 conversion (coalesced): 8 elems/thread ----------
__global__ __launch_bounds__(256) void k_cvt(const uint4* __restrict__ in, uint2* __restrict__ out, int n8) {
  int i = blockIdx.x * 256 + threadIdx.x;
  if (i >= n8) return;
  uint4 v = in[i];
  float f0 = blo(v.x), f1 = bhi(v.x), f2 = blo(v.y), f3 = bhi(v.y);
  float f4 = blo(v.z), f5 = bhi(v.z), f6 = blo(v.w), f7 = bhi(v.w);
  int p0 = 0, p1 = 0;
  p0 = __builtin_amdgcn_cvt_pk_fp8_f32(f0, f1, p0, false);
  p0 = __builtin_amdgcn_cvt_pk_fp8_f32(f2, f3, p0, true);
  p1 = __builtin_amdgcn_cvt_pk_fp8_f32(f4, f5, p1, false);
  p1 = __builtin_amdgcn_cvt_pk_fp8_f32(f6, f7, p1, true);
  uint2 r; r.x = (unsigned int)p0; r.y = (unsigned int)p1;
  out[i] = r;
}

// ---------- MFMA GEMM1: h1b[N,128](bf16) = bf16(x[N,128]) @ W1 ----------
__global__ __launch_bounds__(256) void k_mm1(const float* __restrict__ x,
                                             const ushort_t* __restrict__ Wt,
                                             ushort_t* __restrict__ h1b) {
  __shared__ ushort_t xs[32 * 128];   // 8 KB
  int t = threadIdx.x;
  int w = t >> 6, l = t & 63;
  int lr = l & 15, lk = l >> 4;
  int nodeSub = (w & 1) * 16, colBase = (w >> 1) * 64;
  bf16x8 bfrag[4][4];
  #pragma unroll
  for (int ct = 0; ct < 4; ++ct)
    #pragma unroll
    for (int ks = 0; ks < 4; ++ks) {
      int n = colBase + ct * 16 + lr;
      int k = ks * 32 + lk * 8;
      bfrag[ct][ks] = *(const bf16x8*)&Wt[n * 128 + k];
    }
  int rr = t >> 3, c0 = (t & 7) * 16;   // staging: row, 16-elem col group
  for (int chunk = blockIdx.x; chunk < NCHUNK; chunk += gridDim.x) {
    int base = chunk * 32;
    int srcRow = base + rr; if (srcRow >= N_NODES) srcRow = N_NODES - 1;
    const float4* xr = (const float4*)&x[(size_t)srcRow * IN_DIM + c0];
    float4 f0 = xr[0], f1 = xr[1], f2 = xr[2], f3 = xr[3];
    uint4 w0, w1;
    w0.x = f2b2(f0.x, f0.y); w0.y = f2b2(f0.z, f0.w);
    w0.z = f2b2(f1.x, f1.y); w0.w = f2b2(f1.z, f1.w);
    w1.x = f2b2(f2.x, f2.y); w1.y = f2b2(f2.z, f2.w);
    w1.z = f2b2(f3.x, f3.y); w1.w = f2b2(f3.z, f3.w);
    char* xsb = (char*)xs;
    int swz = (rr & 7) << 4;
    *(uint4*)(xsb + rr * 256 + ((c0 * 2 +  0) ^ swz)) = w0;
    *(uint4*)(xsb + rr * 256 + ((c0 * 2 + 16) ^ swz)) = w1;
    __syncthreads();
    f32x4 acc[4] = {{0,0,0,0},{0,0,0,0},{0,0,0,0},{0,0,0,0}};
    int arow = nodeSub + lr;
    #pragma unroll
    for (int ks = 0; ks < 4; ++ks) {
      bf16x8 a = *(const bf16x8*)((const char*)xs + arow * 256 +
                                  ((ks * 64 + lk * 16) ^ ((arow & 7) << 4)));
      #pragma unroll
      for (int ct = 0; ct < 4; ++ct)
        acc[ct] = __builtin_amdgcn_mfma_f32_16x16x32_bf16(a, bfrag[ct][ks], acc[ct], 0, 0, 0);
    }
    __syncthreads();
    #pragma unroll
    for (int ct = 0; ct < 4; ++ct)
      #pragma unroll
      for (int r = 0; r < 4; ++r) {
        int node = base + nodeSub + lk * 4 + r;
        if (node < N_NODES)
          h1b[(size_t)node * HID + colBase + ct * 16 + lr] = f2b(acc[ct][r]);
      }
  }
}

// ---------- MFMA GEMM2: h2b[N,64](bf16) = out1b[N,128] @ W2 ----------
__global__ __launch_bounds__(256) void k_mm2(const ushort_t* __restrict__ xb,
                                             const ushort_t* __restrict__ Wt,
                                             ushort_t* __restrict__ h2b) {
  __shared__ ushort_t xs[32 * 128];   // 8 KB
  int t = threadIdx.x;
  int w = t >> 6, l = t & 63;
  int lr = l & 15, lk = l >> 4;
  int nodeSub = (w & 1) * 16, colBase = (w >> 1) * 32;
  bf16x8 bfrag[2][4];
  #pragma unroll
  for (int ct = 0; ct < 2; ++ct)
    #pragma unroll
    for (int ks = 0; ks < 4; ++ks) {
      int n = colBase + ct * 16 + lr;
      int k = ks * 32 + lk * 8;
      bfrag[ct][ks] = *(const bf16x8*)&Wt[n * 128 + k];
    }
  int rr = t >> 3, c0 = (t & 7) * 16;
  for (int chunk = blockIdx.x; chunk < NCHUNK; chunk += gridDim.x) {
    int base = chunk * 32;
    int srcRow = base + rr; if (srcRow >= N_NODES) srcRow = N_NODES - 1;
    const uint4* xr = (const uint4*)&xb[(size_t)srcRow * HID + c0];
    uint4 w0 = xr[0], w1 = xr[1];
    char* xsb = (char*)xs;
    int swz = (rr & 7) << 4;
    *(uint4*)(xsb + rr * 256 + ((c0 * 2 +  0) ^ swz)) = w0;
    *(uint4*)(xsb + rr * 256 + ((c0 * 2 + 16) ^ swz)) = w1;
    __syncthreads();
    f32x4 acc[2] = {{0,0,0,0},{0,0,0,0}};
    int arow = nodeSub + lr;
    #pragma unroll
    for (int ks = 0; ks < 4; ++ks) {
      bf16x8 a = *(const bf16x8*)((const char*)xs + arow * 256 +
                                  ((ks * 64 + lk * 16) ^ ((arow & 7) << 4)));
      #pragma unroll
      for (int ct = 0; ct < 2; ++ct)
        acc[ct] = __builtin_amdgcn_mfma_f32_16x16x32_bf16(a, bfrag[ct][ks], acc[ct], 0, 0, 0);
    }
    __syncthreads();
    #pragma unroll
    for (int ct = 0; ct < 2; ++ct)
      #pragma unroll
      for (int r = 0; r < 4; ++r) {
        int node = base + nodeSub + lk * 4 + r;
        if (node < N_NODES)
          h2b[(size_t)node * ODIM + colBase + ct * 16 + lr] = f2b(acc[ct][r]);
      }
  }
}

// ---------- attention logits: 16B loads, 8 cols/lane ----------
__global__ __launch_bounds__(256) void k_al1(const ushort_t* __restrict__ h1b,
                                             const float* __restrict__ asrc,
                                             const float* __restrict__ adst, float* __restrict__ als,
                                             float* __restrict__ ald) {
  int t = threadIdx.x;
  int n = blockIdx.x * 16 + (t >> 4);
  int c8 = (t & 15) * 8;
  uint4 v = *(const uint4*)&h1b[(size_t)n * HID + c8];
  float4 a0 = *(const float4*)&asrc[c8], a1 = *(const float4*)&asrc[c8 + 4];
  float4 d0 = *(const float4*)&adst[c8], d1 = *(const float4*)&adst[c8 + 4];
  float f0 = blo(v.x), f1 = bhi(v.x), f2 = blo(v.y), f3 = bhi(v.y);
  float f4 = blo(v.z), f5 = bhi(v.z), f6 = blo(v.w), f7 = bhi(v.w);
  float s = f0*a0.x + f1*a0.y + f2*a0.z + f3*a0.w + f4*a1.x + f5*a1.y + f6*a1.z + f7*a1.w;
  float d = f0*d0.x + f1*d0.y + f2*d0.z + f3*d0.w + f4*d1.x + f5*d1.y + f6*d1.z + f7*d1.w;
  s += __shfl_xor(s, 1); s += __shfl_xor(s, 2);
  d += __shfl_xor(d, 1); d += __shfl_xor(d, 2);
  if ((t & 3) == 0) {
    int head = (t & 15) >> 2;
    als[n * 4 + head] = s;
    ald[n * 4 + head] = d;
  }
}

__global__ __launch_bounds__(256) void k_al2(const ushort_t* __restrict__ h2b,
                                             const float* __restrict__ asrc,
                                             const float* __restrict__ adst, float* __restrict__ als,
                                             float* __restrict__ ald) {
  int t = threadIdx.x;
  int n = blockIdx.x * 32 + (t >> 3);
  if (n >= N_NODES) return;
  int c8 = (t & 7) * 8;
  uint4 v = *(const uint4*)&h2b[(size_t)n * ODIM + c8];
  float4 a0 = *(const float4*)&asrc[c8], a1 = *(const float4*)&asrc[c8 + 4];
  float4 d0 = *(const float4*)&adst[c8], d1 = *(const float4*)&adst[c8 + 4];
  float f0 = blo(v.x), f1 = bhi(v.x), f2 = blo(v.y), f3 = bhi(v.y);
  float f4 = blo(v.z), f5 = bhi(v.z), f6 = blo(v.w), f7 = bhi(v.w);
  float s = f0*a0.x + f1*a0.y + f2*a0.z + f3*a0.w + f4*a1.x + f5*a1.y + f6*a1.z + f7*a1.w;
  float d = f0*d0.x + f1*d0.y + f2*d0.z + f3*d0.w + f4*d1.x + f5*d1.y + f6*d1.z + f7*d1.w;
  s += __shfl_xor(s, 1); s += __shfl_xor(s, 2); s += __shfl_xor(s, 4);
  d += __shfl_xor(d, 1); d += __shfl_xor(d, 2); d += __shfl_xor(d, 4);
  if ((t & 7) == 0) { als[n] = s; ald[n] = d; }
}

// ---------- layer-1 softmax + aggregate: ONE WAVE per dst node, no LDS, no barriers ----------
// lane j owns edge j (chunked by 64); softmax in registers via shuffles;
// gather: half-waves take 2 edges/iter, 32 lanes x 4B = full 128B fp8 row.
__global__ __launch_bounds__(256) void k_agg1(const unsigned char* __restrict__ h1f8,
                                              const float* __restrict__ als,
                                              const float* __restrict__ ald, const int* __restrict__ offs,
                                              const int* __restrict__ srcs, const float* __restrict__ b1,
                                              ushort_t* __restrict__ out1b) {
  int t = threadIdx.x;
  int w = t >> 6, l = t & 63, lane32 = l & 31, hw = l >> 5;
  int n = blockIdx.x * 4 + w;
  int off0 = offs[n], deg = offs[n + 1] - off0;
  const float4* als4 = (const float4*)als;
  float4 ad = ((const float4*)ald)[n];

  // phase 1: lane-parallel logits + wave max (all 4 heads)
  int s0 = 0;
  float e0 = -INFINITY, e1 = -INFINITY, e2 = -INFINITY, e3 = -INFINITY;
  if (l < deg) {
    s0 = srcs[off0 + l];
    float4 a = als4[s0];
    e0 = lrelu(a.x + ad.x); e1 = lrelu(a.y + ad.y);
    e2 = lrelu(a.z + ad.z); e3 = lrelu(a.w + ad.w);
  }
  float m0 = e0, m1 = e1, m2 = e2, m3 = e3;
  for (int j = 64 + l; j < deg; j += 64) {   // rare: deg > 64
    int s = srcs[off0 + j];
    float4 a = als4[s];
    m0 = fmaxf(m0, lrelu(a.x + ad.x)); m1 = fmaxf(m1, lrelu(a.y + ad.y));
    m2 = fmaxf(m2, lrelu(a.z + ad.z)); m3 = fmaxf(m3, lrelu(a.w + ad.w));
  }
  #pragma unroll
  for (int o = 32; o >= 1; o >>= 1) {
    m0 = fmaxf(m0, __shfl_xor(m0, o)); m1 = fmaxf(m1, __shfl_xor(m1, o));
    m2 = fmaxf(m2, __shfl_xor(m2, o)); m3 = fmaxf(m3, __shfl_xor(m3, o));
  }

  // phase 2, chunk 0: weights in registers
  float w0 = 0.f, w1 = 0.f, w2 = 0.f, w3 = 0.f;
  if (l < deg) {
    w0 = __expf(e0 - m0); w1 = __expf(e1 - m1);
    w2 = __expf(e2 - m2); w3 = __expf(e3 - m3);
  }
  float dn0 = w0, dn1 = w1, dn2 = w2, dn3 = w3;
  int head = lane32 >> 3;
  const unsigned char* hb = h1f8 + lane32 * 4;
  float num0 = 0.f, num1 = 0.f, num2 = 0.f, num3 = 0.f;
  int sb = s0 << 7;                       // byte offset of lane's edge row
  int nedge = deg < 64 ? deg : 64;
  for (int jj = 0; jj < nedge; jj += 2) {
    int j = jj + hw;
    int bo = __shfl(sb, j);
    float a0 = __shfl(w0, j), a1 = __shfl(w1, j), a2 = __shfl(w2, j), a3 = __shfl(w3, j);
    float wj = head == 0 ? a0 : head == 1 ? a1 : head == 2 ? a2 : a3;
    if (j < nedge) {
      unsigned int v = *(const unsigned int*)(hb + bo);
      f32x2 lo = f8x2lo(v), hi = f8x2hi(v);
      num0 = fmaf(wj, lo.x, num0); num1 = fmaf(wj, lo.y, num1);
      num2 = fmaf(wj, hi.x, num2); num3 = fmaf(wj, hi.y, num3);
    }
  }
  // rare extra chunks (deg > 64)
  for (int base = 64; base < deg; base += 64) {
    int j0 = base + l;
    float v0 = 0.f, v1 = 0.f, v2 = 0.f, v3 = 0.f;
    int sbx = 0;
    if (j0 < deg) {
      int s = srcs[off0 + j0];
      sbx = s << 7;
      float4 a = als4[s];
      v0 = __expf(lrelu(a.x + ad.x) - m0); v1 = __expf(lrelu(a.y + ad.y) - m1);
      v2 = __expf(lrelu(a.z + ad.z) - m2); v3 = __expf(lrelu(a.w + ad.w) - m3);
      dn0 += v0; dn1 += v1; dn2 += v2; dn3 += v3;
    }
    int cn = (deg - base) < 64 ? (deg - base) : 64;
    for (int jj = 0; jj < cn; jj += 2) {
      int j = jj + hw;
      int bo = __shfl(sbx, j);
      float a0 = __shfl(v0, j), a1 = __shfl(v1, j), a2 = __shfl(v2, j), a3 = __shfl(v3, j);
      float wj = head == 0 ? a0 : head == 1 ? a1 : head == 2 ? a2 : a3;
      if (j < cn) {
        unsigned int v = *(const unsigned int*)(hb + bo);
        f32x2 lo = f8x2lo(v), hi = f8x2hi(v);
        num0 = fmaf(wj, lo.x, num0); num1 = fmaf(wj, lo.y, num1);
        num2 = fmaf(wj, hi.x, num2); num3 = fmaf(wj, hi.y, num3);
      }
    }
  }
  // denominators: sum each lane's weights across the wave
  #pragma unroll
  for (int o = 32; o >= 1; o >>= 1) {
    dn0 += __shfl_xor(dn0, o); dn1 += __shfl_xor(dn1, o);
    dn2 += __shfl_xor(dn2, o); dn3 += __shfl_xor(dn3, o);
  }
  // combine half-waves (even + odd edges)
  num0 += __shfl_xor(num0, 32); num1 += __shfl_xor(num1, 32);
  num2 += __shfl_xor(num2, 32); num3 += __shfl_xor(num3, 32);
  if (l < 32) {
    float den = head == 0 ? dn0 : head == 1 ? dn1 : head == 2 ? dn2 : dn3;
    float rd = 1.f / den;
    int c4 = lane32 * 4;
    float4 bb = *(const float4*)&b1[c4];
    float o0 = fmaxf(num0 * rd + bb.x, 0.f);
    float o1 = fmaxf(num1 * rd + bb.y, 0.f);
    float o2 = fmaxf(num2 * rd + bb.z, 0.f);
    float o3 = fmaxf(num3 * rd + bb.w, 0.f);
    uint2 pk; pk.x = f2b2(o0, o1); pk.y = f2b2(o2, o3);
    *(uint2*)&out1b[(size_t)n * HID + c4] = pk;
  }
}

// ---------- layer-2 softmax + aggregate + log_softmax: ONE WAVE per node ----------
__global__ __launch_bounds__(256) void k_agg2(const unsigned char* __restrict__ h2f8,
                                              const float* __restrict__ als,
                                              const float* __restrict__ ald, const int* __restrict__ offs,
                                              const int* __restrict__ srcs, const float* __restrict__ b2,
                                              float* __restrict__ out) {
  int t = threadIdx.x;
  int w = t >> 6, l = t & 63, lane32 = l & 31, hw = l >> 5;
  int n = blockIdx.x * 4 + w;
  int off0 = offs[n], deg = offs[n + 1] - off0;
  float adv = ald[n];

  int s0 = 0;
  float e = -INFINITY;
  if (l < deg) { s0 = srcs[off0 + l]; e = lrelu(als[s0] + adv); }
  float m = e;
  for (int j = 64 + l; j < deg; j += 64)
    m = fmaxf(m, lrelu(als[srcs[off0 + j]] + adv));
  #pragma unroll
  for (int o = 32; o >= 1; o >>= 1) m = fmaxf(m, __shfl_xor(m, o));

  float wv = (l < deg) ? __expf(e - m) : 0.f;
  float dn = wv;
  const unsigned char* hb = h2f8 + lane32 * 2;
  float num0 = 0.f, num1 = 0.f;
  int sb = s0 << 6;                      // 64 B rows
  int nedge = deg < 64 ? deg : 64;
  for (int jj = 0; jj < nedge; jj += 2) {
    int j = jj + hw;
    int bo = __shfl(sb, j);
    float wj = __shfl(wv, j);
    if (j < nedge) {
      unsigned int v = *(const unsigned short*)(hb + bo);
      f32x2 lo = f8x2lo(v);
      num0 = fmaf(wj, lo.x, num0); num1 = fmaf(wj, lo.y, num1);
    }
  }
  for (int base = 64; base < deg; base += 64) {   // rare
    int j0 = base + l;
    float v0 = 0.f; int sbx = 0;
    if (j0 < deg) {
      int s = srcs[off0 + j0];
      sbx = s << 6;
      v0 = __expf(lrelu(als[s] + adv) - m);
      dn += v0;
    }
    int cn = (deg - base) < 64 ? (deg - base) : 64;
    for (int jj = 0; jj < cn; jj += 2) {
      int j = jj + hw;
      int bo = __shfl(sbx, j);
      float wj = __shfl(v0, j);
      if (j < cn) {
        unsigned int v = *(const unsigned short*)(hb + bo);
        f32x2 lo = f8x2lo(v);
        num0 = fmaf(wj, lo.x, num0); num1 = fmaf(wj, lo.y, num1);
      }
    }
  }
  #pragma unroll
  for (int o = 32; o >= 1; o >>= 1) dn += __shfl_xor(dn, o);
  num0 += __shfl_xor(num0, 32);
  num1 += __shfl_xor(num1, 32);
  if (l < 32) {
    float rd = 1.f / dn;
    int c2 = lane32 * 2;
    float2 bb = *(const float2*)&b2[c2];
    float val0 = num0 * rd + bb.x;
    float val1 = num1 * rd + bb.y;
    float mx = fmaxf(val0, val1);
    #pragma unroll
    for (int o = 16; o >= 1; o >>= 1) mx = fmaxf(mx, __shfl_xor(mx, o));
    float sum = __expf(val0 - mx) + __expf(val1 - mx);
    #pragma unroll
    for (int o = 16; o >= 1; o >>= 1) sum += __shfl_xor(sum, o);
    float ls = __logf(sum);
    float2 res; res.x = (val0 - mx) - ls; res.y = (val1 - mx) - ls;
    *(float2*)&out[(size_t)n * ODIM + c2] = res;
  }
}

extern "C" void kernel_launch(void* const* d_in, const int* in_sizes, int n_in,
                              void* d_out, int out_size, void* d_ws, size_t ws_size,
                              hipStream_t stream) {
  const float* x   = (const float*)d_in[0];
  const void*  ei  = d_in[1];
  const float* W1  = (const float*)d_in[2];
  const float* as1 = (const float*)d_in[3];
  const float* ad1 = (const float*)d_in[4];
  const float* b1  = (const float*)d_in[5];
  const float* W2  = (const float*)d_in[6];
  const float* as2 = (const float*)d_in[7];
  const float* ad2 = (const float*)d_in[8];
  const float* b2  = (const float*)d_in[9];
  float* out = (float*)d_out;

  char* ws = (char*)d_ws;
  size_t o = 0;
  auto alloc = [&](size_t bytes) { void* p = (void*)(ws + o); o += (bytes + 255) & ~(size_t)255; return p; };
  ushort_t* h1b   = (ushort_t*)alloc((size_t)N_NODES * HID * 2);
  ushort_t* out1b = (ushort_t*)alloc((size_t)N_NODES * HID * 2);
  ushort_t* h2b   = (ushort_t*)alloc((size_t)N_NODES * ODIM * 2);
  unsigned char* h1f8 = (unsigned char*)alloc((size_t)N_NODES * HID);
  ushort_t* Wt1   = (ushort_t*)alloc((size_t)128 * 128 * 2);
  ushort_t* Wt2   = (ushort_t*)alloc((size_t)64 * 128 * 2);
  float* als1 = (float*)alloc((size_t)N_NODES * 4 * 4);
  float* ald1 = (float*)alloc((size_t)N_NODES * 4 * 4);
  float* als2 = (float*)alloc((size_t)N_NODES * 4);
  float* ald2 = (float*)alloc((size_t)N_NODES * 4);
  int*   deg  = (int*)alloc((size_t)N_NODES * 4);
  int*   offs = (int*)alloc((size_t)(N_NODES + 1) * 4);
  int*   rank = (int*)alloc((size_t)E_TOT * 4);
  int*   srcs = (int*)alloc((size_t)E_TOT * 4);
  int*   bsums= (int*)alloc((size_t)NB1 * 4);
  int*   flag = (int*)alloc(4);
  // h2f8 (3.2 MB) aliases rank (3.4 MB): rank is dead after k_scatter
  unsigned char* h2f8 = (unsigned char*)rank;

  hipMemsetAsync(deg, 0, (size_t)N_NODES * 4, stream);
  k_detect<<<1, 64, 0, stream>>>(ei, flag);

  int egrid = (E_TOT + 255) / 256;
  k_hist   <<<egrid, 256, 0, stream>>>(ei, flag, deg, rank);
  k_scan1  <<<NB1,   256, 0, stream>>>(deg, offs, bsums);
  k_scan2  <<<1,     256, 0, stream>>>(bsums);
  k_scan3  <<<NB1,   256, 0, stream>>>(offs, bsums);
  k_scatter<<<egrid, 256, 0, stream>>>(ei, flag, offs, rank, srcs);
  k_prep   <<<64,    256, 0, stream>>>(W1, W2, Wt1, Wt2);

  k_mm1  <<<512, 256, 0, stream>>>(x, Wt1, h1b);
  k_cvt  <<<(N_NODES * HID / 8 + 255) / 256, 256, 0, stream>>>((const uint4*)h1b, (uint2*)h1f8, N_NODES * HID / 8);
  k_al1  <<<N_NODES / 16, 256, 0, stream>>>(h1b, as1, ad1, als1, ald1);
  k_agg1 <<<(N_NODES + 3) / 4, 256, 0, stream>>>(h1f8, als1, ald1, offs, srcs, b1, out1b);

  k_mm2  <<<512, 256, 0, stream>>>(out1b, Wt2, h2b);
  k_cvt  <<<(N_NODES * ODIM / 8 + 255) / 256, 256, 0, stream>>>((const uint4*)h2b, (uint2*)h2f8, N_NODES * ODIM / 8);
  k_al2  <<<(N_NODES + 31) / 32, 256, 0, stream>>>(h2b, as2, ad2, als2, ald2);
  k_agg2 <<<(N_NODES + 3) / 4, 256, 0, stream>>>(h2f8, als2, ald2, offs, srcs, b2, out);
}

// Round 7
// 165.350 us; speedup vs baseline: 1.2263x; 1.2020x over previous
//
#include <hip/hip_runtime.h>
#include <hip/hip_bf16.h>
#include <math.h>

#define N_NODES 50000
#define N_EDGES 800000
#define E_TOT   (N_EDGES + N_NODES)
#define IN_DIM  128
#define HID     128      // HEADS*HIDDEN (layer-1 output width)
#define ODIM    64
#define NEG     0.2f
#define NB1     ((N_NODES + 255) / 256)   // scan blocks = 196
#define NCHUNK  ((N_NODES + 31) / 32)     // 32-node chunks for MFMA GEMMs

typedef short bf16x8 __attribute__((ext_vector_type(8)));
typedef float f32x4 __attribute__((ext_vector_type(4)));
typedef float f32x2 __attribute__((ext_vector_type(2)));
typedef unsigned short ushort_t;

__device__ __forceinline__ float lrelu(float x) { return x >= 0.f ? x : NEG * x; }

// bf16 <-> f32 helpers (RNE rounding on store)
__device__ __forceinline__ unsigned short f2b(float v) {
  unsigned int b = __float_as_uint(v);
  b += 0x7fffu + ((b >> 16) & 1u);
  return (unsigned short)(b >> 16);
}
__device__ __forceinline__ float b2f(unsigned short u) {
  return __uint_as_float(((unsigned int)u) << 16);
}
__device__ __forceinline__ unsigned int f2b2(float lo, float hi) {
  union { __hip_bfloat162 h; unsigned int u; } cv;
  cv.h = __float22bfloat162_rn(make_float2(lo, hi));
  return cv.u;
}
// unpack packed 2xbf16 word
__device__ __forceinline__ float blo(unsigned int v) { return __uint_as_float(v << 16); }
__device__ __forceinline__ float bhi(unsigned int v) { return __uint_as_float(v & 0xffff0000u); }

// fp8 e4m3 (OCP) hardware converts
__device__ __forceinline__ f32x2 f8x2lo(unsigned int v) {
  return __builtin_amdgcn_cvt_pk_f32_fp8((int)v, false);
}
__device__ __forceinline__ f32x2 f8x2hi(unsigned int v) {
  return __builtin_amdgcn_cvt_pk_f32_fp8((int)v, true);
}
__device__ __forceinline__ unsigned char f2f8(float v) {
  return (unsigned char)(__builtin_amdgcn_cvt_pk_fp8_f32(v, v, 0, false) & 0xff);
}

// ---------- edge-index dtype detection (int32 vs int64) ----------
__global__ void k_detect(const void* ei, int* flag) {
  if (threadIdx.x == 0 && blockIdx.x == 0) {
    const int* p = (const int*)ei;
    int allz = 1;
    for (int i = 0; i < 64; ++i) if (p[2 * i + 1] != 0) { allz = 0; break; }
    *flag = allz;  // 1 => buffer is int64
  }
}

__device__ __forceinline__ int e_src(const void* ei, int f, int e) {
  if (e >= N_EDGES) return e - N_EDGES;              // self loop
  return f ? (int)((const long long*)ei)[e] : ((const int*)ei)[e];
}
__device__ __forceinline__ int e_dst(const void* ei, int f, int e) {
  if (e >= N_EDGES) return e - N_EDGES;              // self loop
  return f ? (int)((const long long*)ei)[N_EDGES + e] : ((const int*)ei)[N_EDGES + e];
}

// ---------- CSR build ----------
__global__ void k_hist(const void* ei, const int* flag, int* deg, int* rank) {
  int e = blockIdx.x * 256 + threadIdx.x;
  if (e >= E_TOT) return;
  int r = atomicAdd(&deg[e_dst(ei, *flag, e)], 1);
  rank[e] = r;
}

__global__ void k_scan1(const int* __restrict__ deg, int* __restrict__ offs, int* __restrict__ bsums) {
  __shared__ int sm[256];
  int t = threadIdx.x, i = blockIdx.x * 256 + t;
  int v = (i < N_NODES) ? deg[i] : 0;
  sm[t] = v;
  __syncthreads();
  for (int o = 1; o < 256; o <<= 1) {
    int add = (t >= o) ? sm[t - o] : 0;
    __syncthreads();
    sm[t] += add;
    __syncthreads();
  }
  if (i < N_NODES) offs[i] = sm[t] - v;   // exclusive
  if (t == 255) bsums[blockIdx.x] = sm[255];
}

__global__ void k_scan2(int* bsums) {
  __shared__ int sm[256];
  int t = threadIdx.x;
  int v = (t < NB1) ? bsums[t] : 0;
  sm[t] = v;
  __syncthreads();
  for (int o = 1; o < 256; o <<= 1) {
    int add = (t >= o) ? sm[t - o] : 0;
    __syncthreads();
    sm[t] += add;
    __syncthreads();
  }
  if (t < NB1) bsums[t] = sm[t] - v;      // exclusive
}

__global__ void k_scan3(int* __restrict__ offs, const int* __restrict__ bsums) {
  int i = blockIdx.x * 256 + threadIdx.x;
  if (i < N_NODES) offs[i] += bsums[blockIdx.x];
  if (i == 0) offs[N_NODES] = E_TOT;
}

__global__ void k_scatter(const void* ei, const int* __restrict__ flag, const int* __restrict__ offs,
                          const int* __restrict__ rank, int* __restrict__ srcs) {
  int e = blockIdx.x * 256 + threadIdx.x;
  if (e >= E_TOT) return;
  int f = *flag;
  int d = e_dst(ei, f, e);
  srcs[offs[d] + rank[e]] = e_src(ei, f, e);
}

// ---------- weight prep: bf16 W^T for both layers ----------
__global__ void k_prep(const float* __restrict__ W1, const float* __restrict__ W2,
                       ushort_t* __restrict__ Wt1, ushort_t* __restrict__ Wt2) {
  int i = blockIdx.x * 256 + threadIdx.x;
  if (i < 128 * 128) { int k = i >> 7, n = i & 127; Wt1[n * 128 + k] = f2b(W1[i]); }
  if (i < 128 * 64)  { int k = i >> 6, n = i & 63;  Wt2[n * 128 + k] = f2b(W2[i]); }
}

// ---------- MFMA GEMM1: h1b(bf16) + h1f8(fp8) = bf16(x) @ W1 ----------
__global__ __launch_bounds__(256) void k_mm1(const float* __restrict__ x,
                                             const ushort_t* __restrict__ Wt,
                                             ushort_t* __restrict__ h1b,
                                             unsigned char* __restrict__ h1f8) {
  __shared__ ushort_t xs[32 * 128];   // 8 KB
  int t = threadIdx.x;
  int w = t >> 6, l = t & 63;
  int lr = l & 15, lk = l >> 4;
  int nodeSub = (w & 1) * 16, colBase = (w >> 1) * 64;
  bf16x8 bfrag[4][4];
  #pragma unroll
  for (int ct = 0; ct < 4; ++ct)
    #pragma unroll
    for (int ks = 0; ks < 4; ++ks) {
      int n = colBase + ct * 16 + lr;
      int k = ks * 32 + lk * 8;
      bfrag[ct][ks] = *(const bf16x8*)&Wt[n * 128 + k];
    }
  int rr = t >> 3, c0 = (t & 7) * 16;   // staging: row, 16-elem col group
  for (int chunk = blockIdx.x; chunk < NCHUNK; chunk += gridDim.x) {
    int base = chunk * 32;
    int srcRow = base + rr; if (srcRow >= N_NODES) srcRow = N_NODES - 1;
    const float4* xr = (const float4*)&x[(size_t)srcRow * IN_DIM + c0];
    float4 f0 = xr[0], f1 = xr[1], f2 = xr[2], f3 = xr[3];
    uint4 w0, w1;
    w0.x = f2b2(f0.x, f0.y); w0.y = f2b2(f0.z, f0.w);
    w0.z = f2b2(f1.x, f1.y); w0.w = f2b2(f1.z, f1.w);
    w1.x = f2b2(f2.x, f2.y); w1.y = f2b2(f2.z, f2.w);
    w1.z = f2b2(f3.x, f3.y); w1.w = f2b2(f3.z, f3.w);
    char* xsb = (char*)xs;
    int swz = (rr & 7) << 4;
    *(uint4*)(xsb + rr * 256 + ((c0 * 2 +  0) ^ swz)) = w0;
    *(uint4*)(xsb + rr * 256 + ((c0 * 2 + 16) ^ swz)) = w1;
    __syncthreads();
    f32x4 acc[4] = {{0,0,0,0},{0,0,0,0},{0,0,0,0},{0,0,0,0}};
    int arow = nodeSub + lr;
    #pragma unroll
    for (int ks = 0; ks < 4; ++ks) {
      bf16x8 a = *(const bf16x8*)((const char*)xs + arow * 256 +
                                  ((ks * 64 + lk * 16) ^ ((arow & 7) << 4)));
      #pragma unroll
      for (int ct = 0; ct < 4; ++ct)
        acc[ct] = __builtin_amdgcn_mfma_f32_16x16x32_bf16(a, bfrag[ct][ks], acc[ct], 0, 0, 0);
    }
    __syncthreads();
    #pragma unroll
    for (int ct = 0; ct < 4; ++ct)
      #pragma unroll
      for (int r = 0; r < 4; ++r) {
        int node = base + nodeSub + lk * 4 + r;
        if (node < N_NODES) {
          float v = acc[ct][r];
          int col = colBase + ct * 16 + lr;
          h1b[(size_t)node * HID + col] = f2b(v);
          h1f8[(size_t)node * HID + col] = f2f8(v);
        }
      }
  }
}

// ---------- MFMA GEMM2: h2b(bf16) + h2f8(fp8) = out1b @ W2 ----------
__global__ __launch_bounds__(256) void k_mm2(const ushort_t* __restrict__ xb,
                                             const ushort_t* __restrict__ Wt,
                                             ushort_t* __restrict__ h2b,
                                             unsigned char* __restrict__ h2f8) {
  __shared__ ushort_t xs[32 * 128];   // 8 KB
  int t = threadIdx.x;
  int w = t >> 6, l = t & 63;
  int lr = l & 15, lk = l >> 4;
  int nodeSub = (w & 1) * 16, colBase = (w >> 1) * 32;
  bf16x8 bfrag[2][4];
  #pragma unroll
  for (int ct = 0; ct < 2; ++ct)
    #pragma unroll
    for (int ks = 0; ks < 4; ++ks) {
      int n = colBase + ct * 16 + lr;
      int k = ks * 32 + lk * 8;
      bfrag[ct][ks] = *(const bf16x8*)&Wt[n * 128 + k];
    }
  int rr = t >> 3, c0 = (t & 7) * 16;
  for (int chunk = blockIdx.x; chunk < NCHUNK; chunk += gridDim.x) {
    int base = chunk * 32;
    int srcRow = base + rr; if (srcRow >= N_NODES) srcRow = N_NODES - 1;
    const uint4* xr = (const uint4*)&xb[(size_t)srcRow * HID + c0];
    uint4 w0 = xr[0], w1 = xr[1];
    char* xsb = (char*)xs;
    int swz = (rr & 7) << 4;
    *(uint4*)(xsb + rr * 256 + ((c0 * 2 +  0) ^ swz)) = w0;
    *(uint4*)(xsb + rr * 256 + ((c0 * 2 + 16) ^ swz)) = w1;
    __syncthreads();
    f32x4 acc[2] = {{0,0,0,0},{0,0,0,0}};
    int arow = nodeSub + lr;
    #pragma unroll
    for (int ks = 0; ks < 4; ++ks) {
      bf16x8 a = *(const bf16x8*)((const char*)xs + arow * 256 +
                                  ((ks * 64 + lk * 16) ^ ((arow & 7) << 4)));
      #pragma unroll
      for (int ct = 0; ct < 2; ++ct)
        acc[ct] = __builtin_amdgcn_mfma_f32_16x16x32_bf16(a, bfrag[ct][ks], acc[ct], 0, 0, 0);
    }
    __syncthreads();
    #pragma unroll
    for (int ct = 0; ct < 2; ++ct)
      #pragma unroll
      for (int r = 0; r < 4; ++r) {
        int node = base + nodeSub + lk * 4 + r;
        if (node < N_NODES) {
          float v = acc[ct][r];
          int col = colBase + ct * 16 + lr;
          h2b[(size_t)node * ODIM + col] = f2b(v);
          h2f8[(size_t)node * ODIM + col] = f2f8(v);
        }
      }
  }
}

// ---------- attention logits: 16B loads, 8 cols/lane ----------
__global__ __launch_bounds__(256) void k_al1(const ushort_t* __restrict__ h1b,
                                             const float* __restrict__ asrc,
                                             const float* __restrict__ adst, float* __restrict__ als,
                                             float* __restrict__ ald) {
  int t = threadIdx.x;
  int n = blockIdx.x * 16 + (t >> 4);
  int c8 = (t & 15) * 8;
  uint4 v = *(const uint4*)&h1b[(size_t)n * HID + c8];
  float4 a0 = *(const float4*)&asrc[c8], a1 = *(const float4*)&asrc[c8 + 4];
  float4 d0 = *(const float4*)&adst[c8], d1 = *(const float4*)&adst[c8 + 4];
  float f0 = blo(v.x), f1 = bhi(v.x), f2 = blo(v.y), f3 = bhi(v.y);
  float f4 = blo(v.z), f5 = bhi(v.z), f6 = blo(v.w), f7 = bhi(v.w);
  float s = f0*a0.x + f1*a0.y + f2*a0.z + f3*a0.w + f4*a1.x + f5*a1.y + f6*a1.z + f7*a1.w;
  float d = f0*d0.x + f1*d0.y + f2*d0.z + f3*d0.w + f4*d1.x + f5*d1.y + f6*d1.z + f7*d1.w;
  s += __shfl_xor(s, 1); s += __shfl_xor(s, 2);
  d += __shfl_xor(d, 1); d += __shfl_xor(d, 2);
  if ((t & 3) == 0) {
    int head = (t & 15) >> 2;
    als[n * 4 + head] = s;
    ald[n * 4 + head] = d;
  }
}

__global__ __launch_bounds__(256) void k_al2(const ushort_t* __restrict__ h2b,
                                             const float* __restrict__ asrc,
                                             const float* __restrict__ adst, float* __restrict__ als,
                                             float* __restrict__ ald) {
  int t = threadIdx.x;
  int n = blockIdx.x * 32 + (t >> 3);
  if (n >= N_NODES) return;
  int c8 = (t & 7) * 8;
  uint4 v = *(const uint4*)&h2b[(size_t)n * ODIM + c8];
  float4 a0 = *(const float4*)&asrc[c8], a1 = *(const float4*)&asrc[c8 + 4];
  float4 d0 = *(const float4*)&adst[c8], d1 = *(const float4*)&adst[c8 + 4];
  float f0 = blo(v.x), f1 = bhi(v.x), f2 = blo(v.y), f3 = bhi(v.y);
  float f4 = blo(v.z), f5 = bhi(v.z), f6 = blo(v.w), f7 = bhi(v.w);
  float s = f0*a0.x + f1*a0.y + f2*a0.z + f3*a0.w + f4*a1.x + f5*a1.y + f6*a1.z + f7*a1.w;
  float d = f0*d0.x + f1*d0.y + f2*d0.z + f3*d0.w + f4*d1.x + f5*d1.y + f6*d1.z + f7*d1.w;
  s += __shfl_xor(s, 1); s += __shfl_xor(s, 2); s += __shfl_xor(s, 4);
  d += __shfl_xor(d, 1); d += __shfl_xor(d, 2); d += __shfl_xor(d, 4);
  if ((t & 7) == 0) { als[n] = s; ald[n] = d; }
}

// ---------- layer-1 aggregate: ONE WAVE per node; no max-subtraction (logits O(1));
// gather 4 edges/instr: 16 lanes x 8B = full 128B fp8 row; weights broadcast as packed bf16.
__global__ __launch_bounds__(256) void k_agg1(const unsigned char* __restrict__ h1f8,
                                              const float* __restrict__ als,
                                              const float* __restrict__ ald, const int* __restrict__ offs,
                                              const int* __restrict__ srcs, const float* __restrict__ b1,
                                              ushort_t* __restrict__ out1b) {
  int t = threadIdx.x;
  int w = t >> 6, l = t & 63;
  int eg = l >> 4, cl = l & 15, head = cl >> 2;
  int n = blockIdx.x * 4 + w;
  int off0 = offs[n], deg = offs[n + 1] - off0;
  const float4* als4 = (const float4*)als;
  float4 ad = ((const float4*)ald)[n];
  const unsigned char* hb = h1f8 + cl * 8;

  float dn0 = 0.f, dn1 = 0.f, dn2 = 0.f, dn3 = 0.f;
  float num0 = 0, num1 = 0, num2 = 0, num3 = 0, num4 = 0, num5 = 0, num6 = 0, num7 = 0;

  for (int cbase = 0; cbase < deg; cbase += 64) {
    int j0 = cbase + l;
    float w0 = 0.f, w1 = 0.f, w2 = 0.f, w3 = 0.f;
    int sb = 0;
    if (j0 < deg) {
      int s = srcs[off0 + j0];
      sb = s << 7;
      float4 a = als4[s];
      w0 = __expf(lrelu(a.x + ad.x)); w1 = __expf(lrelu(a.y + ad.y));
      w2 = __expf(lrelu(a.z + ad.z)); w3 = __expf(lrelu(a.w + ad.w));
      dn0 += w0; dn1 += w1; dn2 += w2; dn3 += w3;
    }
    int pw01 = (int)f2b2(w0, w1), pw23 = (int)f2b2(w2, w3);
    int cn = (deg - cbase) < 64 ? (deg - cbase) : 64;
    for (int jj = 0; jj < cn; jj += 4) {
      int j = jj + eg;
      int bo = __shfl(sb, j);
      unsigned int u01 = (unsigned int)__shfl(pw01, j);
      unsigned int u23 = (unsigned int)__shfl(pw23, j);
      unsigned int up = head < 2 ? u01 : u23;
      float wj = (head & 1) ? bhi(up) : blo(up);
      if (j < cn) {
        uint2 v = *(const uint2*)(hb + bo);
        f32x2 p0 = f8x2lo(v.x), p1 = f8x2hi(v.x);
        f32x2 p2 = f8x2lo(v.y), p3 = f8x2hi(v.y);
        num0 = fmaf(wj, p0.x, num0); num1 = fmaf(wj, p0.y, num1);
        num2 = fmaf(wj, p1.x, num2); num3 = fmaf(wj, p1.y, num3);
        num4 = fmaf(wj, p2.x, num4); num5 = fmaf(wj, p2.y, num5);
        num6 = fmaf(wj, p3.x, num6); num7 = fmaf(wj, p3.y, num7);
      }
    }
  }
  // reduce denominators across wave
  #pragma unroll
  for (int o = 32; o >= 1; o >>= 1) {
    dn0 += __shfl_xor(dn0, o); dn1 += __shfl_xor(dn1, o);
    dn2 += __shfl_xor(dn2, o); dn3 += __shfl_xor(dn3, o);
  }
  // combine the 4 edge-subgroups (lanes with equal cl)
  #pragma unroll
  for (int o = 16; o <= 32; o <<= 1) {
    num0 += __shfl_xor(num0, o); num1 += __shfl_xor(num1, o);
    num2 += __shfl_xor(num2, o); num3 += __shfl_xor(num3, o);
    num4 += __shfl_xor(num4, o); num5 += __shfl_xor(num5, o);
    num6 += __shfl_xor(num6, o); num7 += __shfl_xor(num7, o);
  }
  if (l < 16) {
    float den = head == 0 ? dn0 : head == 1 ? dn1 : head == 2 ? dn2 : dn3;
    float rd = 1.f / den;
    int c8 = cl * 8;
    float4 bb0 = *(const float4*)&b1[c8];
    float4 bb1 = *(const float4*)&b1[c8 + 4];
    float o0 = fmaxf(num0 * rd + bb0.x, 0.f);
    float o1 = fmaxf(num1 * rd + bb0.y, 0.f);
    float o2 = fmaxf(num2 * rd + bb0.z, 0.f);
    float o3 = fmaxf(num3 * rd + bb0.w, 0.f);
    float o4 = fmaxf(num4 * rd + bb1.x, 0.f);
    float o5 = fmaxf(num5 * rd + bb1.y, 0.f);
    float o6 = fmaxf(num6 * rd + bb1.z, 0.f);
    float o7 = fmaxf(num7 * rd + bb1.w, 0.f);
    uint4 pk;
    pk.x = f2b2(o0, o1); pk.y = f2b2(o2, o3);
    pk.z = f2b2(o4, o5); pk.w = f2b2(o6, o7);
    *(uint4*)&out1b[(size_t)n * HID + c8] = pk;
  }
}

// ---------- layer-2 aggregate + log_softmax: ONE WAVE per node;
// gather 8 edges/instr: 8 lanes x 8B = full 64B fp8 row.
__global__ __launch_bounds__(256) void k_agg2(const unsigned char* __restrict__ h2f8,
                                              const float* __restrict__ als,
                                              const float* __restrict__ ald, const int* __restrict__ offs,
                                              const int* __restrict__ srcs, const float* __restrict__ b2,
                                              float* __restrict__ out) {
  int t = threadIdx.x;
  int w = t >> 6, l = t & 63;
  int eg = l >> 3, cl = l & 7;
  int n = blockIdx.x * 4 + w;
  int off0 = offs[n], deg = offs[n + 1] - off0;
  float adv = ald[n];
  const unsigned char* hb = h2f8 + cl * 8;

  float dn = 0.f;
  float num0 = 0, num1 = 0, num2 = 0, num3 = 0, num4 = 0, num5 = 0, num6 = 0, num7 = 0;

  for (int cbase = 0; cbase < deg; cbase += 64) {
    int j0 = cbase + l;
    float wv = 0.f;
    int sb = 0;
    if (j0 < deg) {
      int s = srcs[off0 + j0];
      sb = s << 6;
      wv = __expf(lrelu(als[s] + adv));
      dn += wv;
    }
    int cn = (deg - cbase) < 64 ? (deg - cbase) : 64;
    for (int jj = 0; jj < cn; jj += 8) {
      int j = jj + eg;
      int bo = __shfl(sb, j);
      float wj = __shfl(wv, j);
      if (j < cn) {
        uint2 v = *(const uint2*)(hb + bo);
        f32x2 p0 = f8x2lo(v.x), p1 = f8x2hi(v.x);
        f32x2 p2 = f8x2lo(v.y), p3 = f8x2hi(v.y);
        num0 = fmaf(wj, p0.x, num0); num1 = fmaf(wj, p0.y, num1);
        num2 = fmaf(wj, p1.x, num2); num3 = fmaf(wj, p1.y, num3);
        num4 = fmaf(wj, p2.x, num4); num5 = fmaf(wj, p2.y, num5);
        num6 = fmaf(wj, p3.x, num6); num7 = fmaf(wj, p3.y, num7);
      }
    }
  }
  #pragma unroll
  for (int o = 32; o >= 1; o >>= 1) dn += __shfl_xor(dn, o);
  #pragma unroll
  for (int o = 8; o <= 32; o <<= 1) {
    num0 += __shfl_xor(num0, o); num1 += __shfl_xor(num1, o);
    num2 += __shfl_xor(num2, o); num3 += __shfl_xor(num3, o);
    num4 += __shfl_xor(num4, o); num5 += __shfl_xor(num5, o);
    num6 += __shfl_xor(num6, o); num7 += __shfl_xor(num7, o);
  }
  if (l < 8) {
    float rd = 1.f / dn;
    int c8 = cl * 8;
    float4 bb0 = *(const float4*)&b2[c8];
    float4 bb1 = *(const float4*)&b2[c8 + 4];
    float v0 = num0 * rd + bb0.x, v1 = num1 * rd + bb0.y;
    float v2 = num2 * rd + bb0.z, v3 = num3 * rd + bb0.w;
    float v4 = num4 * rd + bb1.x, v5 = num5 * rd + bb1.y;
    float v6 = num6 * rd + bb1.z, v7 = num7 * rd + bb1.w;
    // log_softmax over 64 outputs held by 8 lanes x 8 regs
    float mx = fmaxf(fmaxf(fmaxf(v0, v1), fmaxf(v2, v3)), fmaxf(fmaxf(v4, v5), fmaxf(v6, v7)));
    #pragma unroll
    for (int o = 1; o <= 4; o <<= 1) mx = fmaxf(mx, __shfl_xor(mx, o));
    float sum = __expf(v0 - mx) + __expf(v1 - mx) + __expf(v2 - mx) + __expf(v3 - mx)
              + __expf(v4 - mx) + __expf(v5 - mx) + __expf(v6 - mx) + __expf(v7 - mx);
    #pragma unroll
    for (int o = 1; o <= 4; o <<= 1) sum += __shfl_xor(sum, o);
    float ls = __logf(sum);
    float4 r0, r1;
    r0.x = (v0 - mx) - ls; r0.y = (v1 - mx) - ls; r0.z = (v2 - mx) - ls; r0.w = (v3 - mx) - ls;
    r1.x = (v4 - mx) - ls; r1.y = (v5 - mx) - ls; r1.z = (v6 - mx) - ls; r1.w = (v7 - mx) - ls;
    *(float4*)&out[(size_t)n * ODIM + c8] = r0;
    *(float4*)&out[(size_t)n * ODIM + c8 + 4] = r1;
  }
}

extern "C" void kernel_launch(void* const* d_in, const int* in_sizes, int n_in,
                              void* d_out, int out_size, void* d_ws, size_t ws_size,
                              hipStream_t stream) {
  const float* x   = (const float*)d_in[0];
  const void*  ei  = d_in[1];
  const float* W1  = (const float*)d_in[2];
  const float* as1 = (const float*)d_in[3];
  const float* ad1 = (const float*)d_in[4];
  const float* b1  = (const float*)d_in[5];
  const float* W2  = (const float*)d_in[6];
  const float* as2 = (const float*)d_in[7];
  const float* ad2 = (const float*)d_in[8];
  const float* b2  = (const float*)d_in[9];
  float* out = (float*)d_out;

  char* ws = (char*)d_ws;
  size_t o = 0;
  auto alloc = [&](size_t bytes) { void* p = (void*)(ws + o); o += (bytes + 255) & ~(size_t)255; return p; };
  ushort_t* h1b   = (ushort_t*)alloc((size_t)N_NODES * HID * 2);
  ushort_t* out1b = (ushort_t*)alloc((size_t)N_NODES * HID * 2);
  ushort_t* h2b   = (ushort_t*)alloc((size_t)N_NODES * ODIM * 2);
  unsigned char* h1f8 = (unsigned char*)alloc((size_t)N_NODES * HID);
  ushort_t* Wt1   = (ushort_t*)alloc((size_t)128 * 128 * 2);
  ushort_t* Wt2   = (ushort_t*)alloc((size_t)64 * 128 * 2);
  float* als1 = (float*)alloc((size_t)N_NODES * 4 * 4);
  float* ald1 = (float*)alloc((size_t)N_NODES * 4 * 4);
  float* als2 = (float*)alloc((size_t)N_NODES * 4);
  float* ald2 = (float*)alloc((size_t)N_NODES * 4);
  int*   deg  = (int*)alloc((size_t)N_NODES * 4);
  int*   offs = (int*)alloc((size_t)(N_NODES + 1) * 4);
  int*   rank = (int*)alloc((size_t)E_TOT * 4);
  int*   srcs = (int*)alloc((size_t)E_TOT * 4);
  int*   bsums= (int*)alloc((size_t)NB1 * 4);
  int*   flag = (int*)alloc(4);
  // h2f8 (3.2 MB) aliases rank (3.4 MB): rank is dead after k_scatter
  unsigned char* h2f8 = (unsigned char*)rank;

  hipMemsetAsync(deg, 0, (size_t)N_NODES * 4, stream);
  k_detect<<<1, 64, 0, stream>>>(ei, flag);

  int egrid = (E_TOT + 255) / 256;
  k_hist   <<<egrid, 256, 0, stream>>>(ei, flag, deg, rank);
  k_scan1  <<<NB1,   256, 0, stream>>>(deg, offs, bsums);
  k_scan2  <<<1,     256, 0, stream>>>(bsums);
  k_scan3  <<<NB1,   256, 0, stream>>>(offs, bsums);
  k_scatter<<<egrid, 256, 0, stream>>>(ei, flag, offs, rank, srcs);
  k_prep   <<<64,    256, 0, stream>>>(W1, W2, Wt1, Wt2);

  k_mm1  <<<512, 256, 0, stream>>>(x, Wt1, h1b, h1f8);
  k_al1  <<<N_NODES / 16, 256, 0, stream>>>(h1b, as1, ad1, als1, ald1);
  k_agg1 <<<(N_NODES + 3) / 4, 256, 0, stream>>>(h1f8, als1, ald1, offs, srcs, b1, out1b);

  k_mm2  <<<512, 256, 0, stream>>>(out1b, Wt2, h2b, h2f8);
  k_al2  <<<(N_NODES + 31) / 32, 256, 0, stream>>>(h2b, as2, ad2, als2, ald2);
  k_agg2 <<<(N_NODES + 3) / 4, 256, 0, stream>>>(h2f8, als2, ald2, offs, srcs, b2, out);
}

// Round 8
// 160.630 us; speedup vs baseline: 1.2623x; 1.0294x over previous
//
#include <hip/hip_runtime.h>
#include <hip/hip_bf16.h>
#include <math.h>

#define N_NODES 50000
#define N_EDGES 800000
#define E_TOT   (N_EDGES + N_NODES)
#define IN_DIM  128
#define HID     128      // HEADS*HIDDEN (layer-1 output width)
#define ODIM    64
#define NEG     0.2f
#define NB1     ((N_NODES + 255) / 256)   // scan blocks = 196
#define NCHUNK  ((N_NODES + 31) / 32)     // 32-node chunks for MFMA GEMMs
#define NREP    8

typedef short bf16x8 __attribute__((ext_vector_type(8)));
typedef float f32x4 __attribute__((ext_vector_type(4)));
typedef float f32x2 __attribute__((ext_vector_type(2)));
typedef unsigned short ushort_t;

__device__ __forceinline__ float lrelu(float x) { return x >= 0.f ? x : NEG * x; }

// bf16 <-> f32 helpers (RNE rounding on store)
__device__ __forceinline__ unsigned short f2b(float v) {
  unsigned int b = __float_as_uint(v);
  b += 0x7fffu + ((b >> 16) & 1u);
  return (unsigned short)(b >> 16);
}
__device__ __forceinline__ float b2f(unsigned short u) {
  return __uint_as_float(((unsigned int)u) << 16);
}
__device__ __forceinline__ unsigned int f2b2(float lo, float hi) {
  union { __hip_bfloat162 h; unsigned int u; } cv;
  cv.h = __float22bfloat162_rn(make_float2(lo, hi));
  return cv.u;
}
// unpack packed 2xbf16 word
__device__ __forceinline__ float blo(unsigned int v) { return __uint_as_float(v << 16); }
__device__ __forceinline__ float bhi(unsigned int v) { return __uint_as_float(v & 0xffff0000u); }

// fp8 e4m3 (OCP) hardware converts
__device__ __forceinline__ f32x2 f8x2lo(unsigned int v) {
  return __builtin_amdgcn_cvt_pk_f32_fp8((int)v, false);
}
__device__ __forceinline__ f32x2 f8x2hi(unsigned int v) {
  return __builtin_amdgcn_cvt_pk_f32_fp8((int)v, true);
}
__device__ __forceinline__ unsigned char f2f8(float v) {
  return (unsigned char)(__builtin_amdgcn_cvt_pk_fp8_f32(v, v, 0, false) & 0xff);
}

// ---------- edge-index dtype detection (int32 vs int64) ----------
__global__ void k_detect(const void* ei, int* flag) {
  if (threadIdx.x == 0 && blockIdx.x == 0) {
    const int* p = (const int*)ei;
    int allz = 1;
    for (int i = 0; i < 64; ++i) if (p[2 * i + 1] != 0) { allz = 0; break; }
    *flag = allz;  // 1 => buffer is int64
  }
}

__device__ __forceinline__ int e_src(const void* ei, int f, int e) {
  if (e >= N_EDGES) return e - N_EDGES;              // self loop
  return f ? (int)((const long long*)ei)[e] : ((const int*)ei)[e];
}
__device__ __forceinline__ int e_dst(const void* ei, int f, int e) {
  if (e >= N_EDGES) return e - N_EDGES;              // self loop
  return f ? (int)((const long long*)ei)[N_EDGES + e] : ((const int*)ei)[N_EDGES + e];
}

// ---------- CSR build: 8-way replicated histogram (cuts atomic line-bounce) ----------
__global__ void k_hist(const void* ei, const int* flag, int* degr, int* rank) {
  int e = blockIdx.x * 256 + threadIdx.x;
  if (e >= E_TOT) return;
  int r = blockIdx.x & (NREP - 1);
  int d = e_dst(ei, *flag, e);
  rank[e] = atomicAdd(&degr[r * N_NODES + d], 1);
}

__global__ void k_scan1(const int* __restrict__ degr, int* __restrict__ offs, int* __restrict__ bsums) {
  __shared__ int sm[256];
  int t = threadIdx.x, i = blockIdx.x * 256 + t;
  int v = 0;
  if (i < N_NODES) {
    #pragma unroll
    for (int r = 0; r < NREP; ++r) v += degr[r * N_NODES + i];
  }
  sm[t] = v;
  __syncthreads();
  for (int o = 1; o < 256; o <<= 1) {
    int add = (t >= o) ? sm[t - o] : 0;
    __syncthreads();
    sm[t] += add;
    __syncthreads();
  }
  if (i < N_NODES) offs[i] = sm[t] - v;   // exclusive (block-local)
  if (t == 255) bsums[blockIdx.x] = sm[255];
}

__global__ void k_scan2(int* bsums) {
  __shared__ int sm[256];
  int t = threadIdx.x;
  int v = (t < NB1) ? bsums[t] : 0;
  sm[t] = v;
  __syncthreads();
  for (int o = 1; o < 256; o <<= 1) {
    int add = (t >= o) ? sm[t - o] : 0;
    __syncthreads();
    sm[t] += add;
    __syncthreads();
  }
  if (t < NB1) bsums[t] = sm[t] - v;      // exclusive
}

// finalize offs and compute per-replica bases
__global__ void k_scan3(int* __restrict__ offs, const int* __restrict__ bsums,
                        const int* __restrict__ degr, int* __restrict__ repbase) {
  int i = blockIdx.x * 256 + threadIdx.x;
  if (i < N_NODES) {
    int o = offs[i] + bsums[blockIdx.x];
    offs[i] = o;
    int run = o;
    #pragma unroll
    for (int r = 0; r < NREP; ++r) {
      repbase[r * N_NODES + i] = run;
      run += degr[r * N_NODES + i];
    }
  }
  if (i == 0) offs[N_NODES] = E_TOT;
}

__global__ void k_scatter(const void* ei, const int* __restrict__ flag,
                          const int* __restrict__ repbase,
                          const int* __restrict__ rank, int* __restrict__ srcs) {
  int e = blockIdx.x * 256 + threadIdx.x;
  if (e >= E_TOT) return;
  int f = *flag;
  int d = e_dst(ei, f, e);
  int r = blockIdx.x & (NREP - 1);
  srcs[repbase[r * N_NODES + d] + rank[e]] = e_src(ei, f, e);
}

// ---------- weight prep: bf16 W^T for both layers ----------
__global__ void k_prep(const float* __restrict__ W1, const float* __restrict__ W2,
                       ushort_t* __restrict__ Wt1, ushort_t* __restrict__ Wt2) {
  int i = blockIdx.x * 256 + threadIdx.x;
  if (i < 128 * 128) { int k = i >> 7, n = i & 127; Wt1[n * 128 + k] = f2b(W1[i]); }
  if (i < 128 * 64)  { int k = i >> 6, n = i & 63;  Wt2[n * 128 + k] = f2b(W2[i]); }
}

// ---------- MFMA GEMM1: h1b(bf16) + h1f8(fp8) = bf16(x) @ W1 ----------
__global__ __launch_bounds__(256) void k_mm1(const float* __restrict__ x,
                                             const ushort_t* __restrict__ Wt,
                                             ushort_t* __restrict__ h1b,
                                             unsigned char* __restrict__ h1f8) {
  __shared__ ushort_t xs[32 * 128];   // 8 KB
  int t = threadIdx.x;
  int w = t >> 6, l = t & 63;
  int lr = l & 15, lk = l >> 4;
  int nodeSub = (w & 1) * 16, colBase = (w >> 1) * 64;
  bf16x8 bfrag[4][4];
  #pragma unroll
  for (int ct = 0; ct < 4; ++ct)
    #pragma unroll
    for (int ks = 0; ks < 4; ++ks) {
      int n = colBase + ct * 16 + lr;
      int k = ks * 32 + lk * 8;
      bfrag[ct][ks] = *(const bf16x8*)&Wt[n * 128 + k];
    }
  int rr = t >> 3, c0 = (t & 7) * 16;   // staging: row, 16-elem col group
  for (int chunk = blockIdx.x; chunk < NCHUNK; chunk += gridDim.x) {
    int base = chunk * 32;
    int srcRow = base + rr; if (srcRow >= N_NODES) srcRow = N_NODES - 1;
    const float4* xr = (const float4*)&x[(size_t)srcRow * IN_DIM + c0];
    float4 f0 = xr[0], f1 = xr[1], f2 = xr[2], f3 = xr[3];
    uint4 w0, w1;
    w0.x = f2b2(f0.x, f0.y); w0.y = f2b2(f0.z, f0.w);
    w0.z = f2b2(f1.x, f1.y); w0.w = f2b2(f1.z, f1.w);
    w1.x = f2b2(f2.x, f2.y); w1.y = f2b2(f2.z, f2.w);
    w1.z = f2b2(f3.x, f3.y); w1.w = f2b2(f3.z, f3.w);
    char* xsb = (char*)xs;
    int swz = (rr & 7) << 4;
    *(uint4*)(xsb + rr * 256 + ((c0 * 2 +  0) ^ swz)) = w0;
    *(uint4*)(xsb + rr * 256 + ((c0 * 2 + 16) ^ swz)) = w1;
    __syncthreads();
    f32x4 acc[4] = {{0,0,0,0},{0,0,0,0},{0,0,0,0},{0,0,0,0}};
    int arow = nodeSub + lr;
    #pragma unroll
    for (int ks = 0; ks < 4; ++ks) {
      bf16x8 a = *(const bf16x8*)((const char*)xs + arow * 256 +
                                  ((ks * 64 + lk * 16) ^ ((arow & 7) << 4)));
      #pragma unroll
      for (int ct = 0; ct < 4; ++ct)
        acc[ct] = __builtin_amdgcn_mfma_f32_16x16x32_bf16(a, bfrag[ct][ks], acc[ct], 0, 0, 0);
    }
    __syncthreads();
    #pragma unroll
    for (int ct = 0; ct < 4; ++ct)
      #pragma unroll
      for (int r = 0; r < 4; ++r) {
        int node = base + nodeSub + lk * 4 + r;
        if (node < N_NODES) {
          float v = acc[ct][r];
          int col = colBase + ct * 16 + lr;
          h1b[(size_t)node * HID + col] = f2b(v);
          h1f8[(size_t)node * HID + col] = f2f8(v);
        }
      }
  }
}

// ---------- MFMA GEMM2: h2b(bf16) + h2f8(fp8) = out1b @ W2 ----------
__global__ __launch_bounds__(256) void k_mm2(const ushort_t* __restrict__ xb,
                                             const ushort_t* __restrict__ Wt,
                                             ushort_t* __restrict__ h2b,
                                             unsigned char* __restrict__ h2f8) {
  __shared__ ushort_t xs[32 * 128];   // 8 KB
  int t = threadIdx.x;
  int w = t >> 6, l = t & 63;
  int lr = l & 15, lk = l >> 4;
  int nodeSub = (w & 1) * 16, colBase = (w >> 1) * 32;
  bf16x8 bfrag[2][4];
  #pragma unroll
  for (int ct = 0; ct < 2; ++ct)
    #pragma unroll
    for (int ks = 0; ks < 4; ++ks) {
      int n = colBase + ct * 16 + lr;
      int k = ks * 32 + lk * 8;
      bfrag[ct][ks] = *(const bf16x8*)&Wt[n * 128 + k];
    }
  int rr = t >> 3, c0 = (t & 7) * 16;
  for (int chunk = blockIdx.x; chunk < NCHUNK; chunk += gridDim.x) {
    int base = chunk * 32;
    int srcRow = base + rr; if (srcRow >= N_NODES) srcRow = N_NODES - 1;
    const uint4* xr = (const uint4*)&xb[(size_t)srcRow * HID + c0];
    uint4 w0 = xr[0], w1 = xr[1];
    char* xsb = (char*)xs;
    int swz = (rr & 7) << 4;
    *(uint4*)(xsb + rr * 256 + ((c0 * 2 +  0) ^ swz)) = w0;
    *(uint4*)(xsb + rr * 256 + ((c0 * 2 + 16) ^ swz)) = w1;
    __syncthreads();
    f32x4 acc[2] = {{0,0,0,0},{0,0,0,0}};
    int arow = nodeSub + lr;
    #pragma unroll
    for (int ks = 0; ks < 4; ++ks) {
      bf16x8 a = *(const bf16x8*)((const char*)xs + arow * 256 +
                                  ((ks * 64 + lk * 16) ^ ((arow & 7) << 4)));
      #pragma unroll
      for (int ct = 0; ct < 2; ++ct)
        acc[ct] = __builtin_amdgcn_mfma_f32_16x16x32_bf16(a, bfrag[ct][ks], acc[ct], 0, 0, 0);
    }
    __syncthreads();
    #pragma unroll
    for (int ct = 0; ct < 2; ++ct)
      #pragma unroll
      for (int r = 0; r < 4; ++r) {
        int node = base + nodeSub + lk * 4 + r;
        if (node < N_NODES) {
          float v = acc[ct][r];
          int col = colBase + ct * 16 + lr;
          h2b[(size_t)node * ODIM + col] = f2b(v);
          h2f8[(size_t)node * ODIM + col] = f2f8(v);
        }
      }
  }
}

// ---------- attention logits: 16B loads, 8 cols/lane ----------
__global__ __launch_bounds__(256) void k_al1(const ushort_t* __restrict__ h1b,
                                             const float* __restrict__ asrc,
                                             const float* __restrict__ adst, float* __restrict__ als,
                                             float* __restrict__ ald) {
  int t = threadIdx.x;
  int n = blockIdx.x * 16 + (t >> 4);
  int c8 = (t & 15) * 8;
  uint4 v = *(const uint4*)&h1b[(size_t)n * HID + c8];
  float4 a0 = *(const float4*)&asrc[c8], a1 = *(const float4*)&asrc[c8 + 4];
  float4 d0 = *(const float4*)&adst[c8], d1 = *(const float4*)&adst[c8 + 4];
  float f0 = blo(v.x), f1 = bhi(v.x), f2 = blo(v.y), f3 = bhi(v.y);
  float f4 = blo(v.z), f5 = bhi(v.z), f6 = blo(v.w), f7 = bhi(v.w);
  float s = f0*a0.x + f1*a0.y + f2*a0.z + f3*a0.w + f4*a1.x + f5*a1.y + f6*a1.z + f7*a1.w;
  float d = f0*d0.x + f1*d0.y + f2*d0.z + f3*d0.w + f4*d1.x + f5*d1.y + f6*d1.z + f7*d1.w;
  s += __shfl_xor(s, 1); s += __shfl_xor(s, 2);
  d += __shfl_xor(d, 1); d += __shfl_xor(d, 2);
  if ((t & 3) == 0) {
    int head = (t & 15) >> 2;
    als[n * 4 + head] = s;
    ald[n * 4 + head] = d;
  }
}

__global__ __launch_bounds__(256) void k_al2(const ushort_t* __restrict__ h2b,
                                             const float* __restrict__ asrc,
                                             const float* __restrict__ adst, float* __restrict__ als,
                                             float* __restrict__ ald) {
  int t = threadIdx.x;
  int n = blockIdx.x * 32 + (t >> 3);
  if (n >= N_NODES) return;
  int c8 = (t & 7) * 8;
  uint4 v = *(const uint4*)&h2b[(size_t)n * ODIM + c8];
  float4 a0 = *(const float4*)&asrc[c8], a1 = *(const float4*)&asrc[c8 + 4];
  float4 d0 = *(const float4*)&adst[c8], d1 = *(const float4*)&adst[c8 + 4];
  float f0 = blo(v.x), f1 = bhi(v.x), f2 = blo(v.y), f3 = bhi(v.y);
  float f4 = blo(v.z), f5 = bhi(v.z), f6 = blo(v.w), f7 = bhi(v.w);
  float s = f0*a0.x + f1*a0.y + f2*a0.z + f3*a0.w + f4*a1.x + f5*a1.y + f6*a1.z + f7*a1.w;
  float d = f0*d0.x + f1*d0.y + f2*d0.z + f3*d0.w + f4*d1.x + f5*d1.y + f6*d1.z + f7*d1.w;
  s += __shfl_xor(s, 1); s += __shfl_xor(s, 2); s += __shfl_xor(s, 4);
  d += __shfl_xor(d, 1); d += __shfl_xor(d, 2); d += __shfl_xor(d, 4);
  if ((t & 7) == 0) { als[n] = s; ald[n] = d; }
}

// ---------- layer-1 aggregate: ONE WAVE per node; no max-subtraction (logits O(1));
// gather 4 edges/instr: 16 lanes x 8B = full 128B fp8 row; weights broadcast as packed bf16.
__global__ __launch_bounds__(256) void k_agg1(const unsigned char* __restrict__ h1f8,
                                              const float* __restrict__ als,
                                              const float* __restrict__ ald, const int* __restrict__ offs,
                                              const int* __restrict__ srcs, const float* __restrict__ b1,
                                              ushort_t* __restrict__ out1b) {
  int t = threadIdx.x;
  int w = t >> 6, l = t & 63;
  int eg = l >> 4, cl = l & 15, head = cl >> 2;
  int n = blockIdx.x * 4 + w;
  int off0 = offs[n], deg = offs[n + 1] - off0;
  const float4* als4 = (const float4*)als;
  float4 ad = ((const float4*)ald)[n];
  const unsigned char* hb = h1f8 + cl * 8;

  float dn0 = 0.f, dn1 = 0.f, dn2 = 0.f, dn3 = 0.f;
  float num0 = 0, num1 = 0, num2 = 0, num3 = 0, num4 = 0, num5 = 0, num6 = 0, num7 = 0;

  for (int cbase = 0; cbase < deg; cbase += 64) {
    int j0 = cbase + l;
    float w0 = 0.f, w1 = 0.f, w2 = 0.f, w3 = 0.f;
    int sb = 0;
    if (j0 < deg) {
      int s = srcs[off0 + j0];
      sb = s << 7;
      float4 a = als4[s];
      w0 = __expf(lrelu(a.x + ad.x)); w1 = __expf(lrelu(a.y + ad.y));
      w2 = __expf(lrelu(a.z + ad.z)); w3 = __expf(lrelu(a.w + ad.w));
      dn0 += w0; dn1 += w1; dn2 += w2; dn3 += w3;
    }
    int pw01 = (int)f2b2(w0, w1), pw23 = (int)f2b2(w2, w3);
    int cn = (deg - cbase) < 64 ? (deg - cbase) : 64;
    for (int jj = 0; jj < cn; jj += 4) {
      int j = jj + eg;
      int bo = __shfl(sb, j);
      unsigned int u01 = (unsigned int)__shfl(pw01, j);
      unsigned int u23 = (unsigned int)__shfl(pw23, j);
      unsigned int up = head < 2 ? u01 : u23;
      float wj = (head & 1) ? bhi(up) : blo(up);
      if (j < cn) {
        uint2 v = *(const uint2*)(hb + bo);
        f32x2 p0 = f8x2lo(v.x), p1 = f8x2hi(v.x);
        f32x2 p2 = f8x2lo(v.y), p3 = f8x2hi(v.y);
        num0 = fmaf(wj, p0.x, num0); num1 = fmaf(wj, p0.y, num1);
        num2 = fmaf(wj, p1.x, num2); num3 = fmaf(wj, p1.y, num3);
        num4 = fmaf(wj, p2.x, num4); num5 = fmaf(wj, p2.y, num5);
        num6 = fmaf(wj, p3.x, num6); num7 = fmaf(wj, p3.y, num7);
      }
    }
  }
  // reduce denominators across wave
  #pragma unroll
  for (int o = 32; o >= 1; o >>= 1) {
    dn0 += __shfl_xor(dn0, o); dn1 += __shfl_xor(dn1, o);
    dn2 += __shfl_xor(dn2, o); dn3 += __shfl_xor(dn3, o);
  }
  // combine the 4 edge-subgroups (lanes with equal cl)
  #pragma unroll
  for (int o = 16; o <= 32; o <<= 1) {
    num0 += __shfl_xor(num0, o); num1 += __shfl_xor(num1, o);
    num2 += __shfl_xor(num2, o); num3 += __shfl_xor(num3, o);
    num4 += __shfl_xor(num4, o); num5 += __shfl_xor(num5, o);
    num6 += __shfl_xor(num6, o); num7 += __shfl_xor(num7, o);
  }
  if (l < 16) {
    float den = head == 0 ? dn0 : head == 1 ? dn1 : head == 2 ? dn2 : dn3;
    float rd = 1.f / den;
    int c8 = cl * 8;
    float4 bb0 = *(const float4*)&b1[c8];
    float4 bb1 = *(const float4*)&b1[c8 + 4];
    float o0 = fmaxf(num0 * rd + bb0.x, 0.f);
    float o1 = fmaxf(num1 * rd + bb0.y, 0.f);
    float o2 = fmaxf(num2 * rd + bb0.z, 0.f);
    float o3 = fmaxf(num3 * rd + bb0.w, 0.f);
    float o4 = fmaxf(num4 * rd + bb1.x, 0.f);
    float o5 = fmaxf(num5 * rd + bb1.y, 0.f);
    float o6 = fmaxf(num6 * rd + bb1.z, 0.f);
    float o7 = fmaxf(num7 * rd + bb1.w, 0.f);
    uint4 pk;
    pk.x = f2b2(o0, o1); pk.y = f2b2(o2, o3);
    pk.z = f2b2(o4, o5); pk.w = f2b2(o6, o7);
    *(uint4*)&out1b[(size_t)n * HID + c8] = pk;
  }
}

// ---------- layer-2 aggregate + log_softmax: ONE WAVE per node;
// gather 8 edges/instr: 8 lanes x 8B = full 64B fp8 row.
__global__ __launch_bounds__(256) void k_agg2(const unsigned char* __restrict__ h2f8,
                                              const float* __restrict__ als,
                                              const float* __restrict__ ald, const int* __restrict__ offs,
                                              const int* __restrict__ srcs, const float* __restrict__ b2,
                                              float* __restrict__ out) {
  int t = threadIdx.x;
  int w = t >> 6, l = t & 63;
  int eg = l >> 3, cl = l & 7;
  int n = blockIdx.x * 4 + w;
  int off0 = offs[n], deg = offs[n + 1] - off0;
  float adv = ald[n];
  const unsigned char* hb = h2f8 + cl * 8;

  float dn = 0.f;
  float num0 = 0, num1 = 0, num2 = 0, num3 = 0, num4 = 0, num5 = 0, num6 = 0, num7 = 0;

  for (int cbase = 0; cbase < deg; cbase += 64) {
    int j0 = cbase + l;
    float wv = 0.f;
    int sb = 0;
    if (j0 < deg) {
      int s = srcs[off0 + j0];
      sb = s << 6;
      wv = __expf(lrelu(als[s] + adv));
      dn += wv;
    }
    int cn = (deg - cbase) < 64 ? (deg - cbase) : 64;
    for (int jj = 0; jj < cn; jj += 8) {
      int j = jj + eg;
      int bo = __shfl(sb, j);
      float wj = __shfl(wv, j);
      if (j < cn) {
        uint2 v = *(const uint2*)(hb + bo);
        f32x2 p0 = f8x2lo(v.x), p1 = f8x2hi(v.x);
        f32x2 p2 = f8x2lo(v.y), p3 = f8x2hi(v.y);
        num0 = fmaf(wj, p0.x, num0); num1 = fmaf(wj, p0.y, num1);
        num2 = fmaf(wj, p1.x, num2); num3 = fmaf(wj, p1.y, num3);
        num4 = fmaf(wj, p2.x, num4); num5 = fmaf(wj, p2.y, num5);
        num6 = fmaf(wj, p3.x, num6); num7 = fmaf(wj, p3.y, num7);
      }
    }
  }
  #pragma unroll
  for (int o = 32; o >= 1; o >>= 1) dn += __shfl_xor(dn, o);
  #pragma unroll
  for (int o = 8; o <= 32; o <<= 1) {
    num0 += __shfl_xor(num0, o); num1 += __shfl_xor(num1, o);
    num2 += __shfl_xor(num2, o); num3 += __shfl_xor(num3, o);
    num4 += __shfl_xor(num4, o); num5 += __shfl_xor(num5, o);
    num6 += __shfl_xor(num6, o); num7 += __shfl_xor(num7, o);
  }
  if (l < 8) {
    float rd = 1.f / dn;
    int c8 = cl * 8;
    float4 bb0 = *(const float4*)&b2[c8];
    float4 bb1 = *(const float4*)&b2[c8 + 4];
    float v0 = num0 * rd + bb0.x, v1 = num1 * rd + bb0.y;
    float v2 = num2 * rd + bb0.z, v3 = num3 * rd + bb0.w;
    float v4 = num4 * rd + bb1.x, v5 = num5 * rd + bb1.y;
    float v6 = num6 * rd + bb1.z, v7 = num7 * rd + bb1.w;
    // log_softmax over 64 outputs held by 8 lanes x 8 regs
    float mx = fmaxf(fmaxf(fmaxf(v0, v1), fmaxf(v2, v3)), fmaxf(fmaxf(v4, v5), fmaxf(v6, v7)));
    #pragma unroll
    for (int o = 1; o <= 4; o <<= 1) mx = fmaxf(mx, __shfl_xor(mx, o));
    float sum = __expf(v0 - mx) + __expf(v1 - mx) + __expf(v2 - mx) + __expf(v3 - mx)
              + __expf(v4 - mx) + __expf(v5 - mx) + __expf(v6 - mx) + __expf(v7 - mx);
    #pragma unroll
    for (int o = 1; o <= 4; o <<= 1) sum += __shfl_xor(sum, o);
    float ls = __logf(sum);
    float4 r0, r1;
    r0.x = (v0 - mx) - ls; r0.y = (v1 - mx) - ls; r0.z = (v2 - mx) - ls; r0.w = (v3 - mx) - ls;
    r1.x = (v4 - mx) - ls; r1.y = (v5 - mx) - ls; r1.z = (v6 - mx) - ls; r1.w = (v7 - mx) - ls;
    *(float4*)&out[(size_t)n * ODIM + c8] = r0;
    *(float4*)&out[(size_t)n * ODIM + c8 + 4] = r1;
  }
}

extern "C" void kernel_launch(void* const* d_in, const int* in_sizes, int n_in,
                              void* d_out, int out_size, void* d_ws, size_t ws_size,
                              hipStream_t stream) {
  const float* x   = (const float*)d_in[0];
  const void*  ei  = d_in[1];
  const float* W1  = (const float*)d_in[2];
  const float* as1 = (const float*)d_in[3];
  const float* ad1 = (const float*)d_in[4];
  const float* b1  = (const float*)d_in[5];
  const float* W2  = (const float*)d_in[6];
  const float* as2 = (const float*)d_in[7];
  const float* ad2 = (const float*)d_in[8];
  const float* b2  = (const float*)d_in[9];
  float* out = (float*)d_out;

  char* ws = (char*)d_ws;
  size_t o = 0;
  auto alloc = [&](size_t bytes) { void* p = (void*)(ws + o); o += (bytes + 255) & ~(size_t)255; return p; };
  ushort_t* h1b   = (ushort_t*)alloc((size_t)N_NODES * HID * 2);
  ushort_t* out1b = (ushort_t*)alloc((size_t)N_NODES * HID * 2);
  ushort_t* h2b   = (ushort_t*)alloc((size_t)N_NODES * ODIM * 2);
  unsigned char* h1f8 = (unsigned char*)alloc((size_t)N_NODES * HID);
  ushort_t* Wt1   = (ushort_t*)alloc((size_t)128 * 128 * 2);
  ushort_t* Wt2   = (ushort_t*)alloc((size_t)64 * 128 * 2);
  float* als1 = (float*)alloc((size_t)N_NODES * 4 * 4);
  float* ald1 = (float*)alloc((size_t)N_NODES * 4 * 4);
  float* als2 = (float*)alloc((size_t)N_NODES * 4);
  float* ald2 = (float*)alloc((size_t)N_NODES * 4);
  int*   degr = (int*)alloc((size_t)NREP * N_NODES * 4);
  int*   repbase = (int*)alloc((size_t)NREP * N_NODES * 4);
  int*   offs = (int*)alloc((size_t)(N_NODES + 1) * 4);
  int*   rank = (int*)alloc((size_t)E_TOT * 4);
  int*   srcs = (int*)alloc((size_t)E_TOT * 4);
  int*   bsums= (int*)alloc((size_t)NB1 * 4);
  int*   flag = (int*)alloc(4);
  // h2f8 (3.2 MB) aliases rank (3.4 MB): rank is dead after k_scatter
  unsigned char* h2f8 = (unsigned char*)rank;

  hipMemsetAsync(degr, 0, (size_t)NREP * N_NODES * 4, stream);
  k_detect<<<1, 64, 0, stream>>>(ei, flag);

  int egrid = (E_TOT + 255) / 256;
  k_hist   <<<egrid, 256, 0, stream>>>(ei, flag, degr, rank);
  k_scan1  <<<NB1,   256, 0, stream>>>(degr, offs, bsums);
  k_scan2  <<<1,     256, 0, stream>>>(bsums);
  k_scan3  <<<NB1,   256, 0, stream>>>(offs, bsums, degr, repbase);
  k_scatter<<<egrid, 256, 0, stream>>>(ei, flag, repbase, rank, srcs);
  k_prep   <<<64,    256, 0, stream>>>(W1, W2, Wt1, Wt2);

  k_mm1  <<<512, 256, 0, stream>>>(x, Wt1, h1b, h1f8);
  k_al1  <<<N_NODES / 16, 256, 0, stream>>>(h1b, as1, ad1, als1, ald1);
  k_agg1 <<<(N_NODES + 3) / 4, 256, 0, stream>>>(h1f8, als1, ald1, offs, srcs, b1, out1b);

  k_mm2  <<<512, 256, 0, stream>>>(out1b, Wt2, h2b, h2f8);
  k_al2  <<<(N_NODES + 31) / 32, 256, 0, stream>>>(h2b, as2, ad2, als2, ald2);
  k_agg2 <<<(N_NODES + 3) / 4, 256, 0, stream>>>(h2f8, als2, ald2, offs, srcs, b2, out);
}

// Round 9
// 148.552 us; speedup vs baseline: 1.3650x; 1.0813x over previous
//
#include <hip/hip_runtime.h>
#include <hip/hip_bf16.h>
#include <math.h>

#define N_NODES 50000
#define N_EDGES 800000
#define E_TOT   (N_EDGES + N_NODES)
#define IN_DIM  128
#define HID     128      // HEADS*HIDDEN (layer-1 output width)
#define ODIM    64
#define NEG     0.2f
#define NB1     ((N_NODES + 255) / 256)   // scan blocks = 196
#define NCHUNK  ((N_NODES + 31) / 32)     // 32-node chunks for MFMA GEMMs
#define NREP    8

typedef short bf16x8 __attribute__((ext_vector_type(8)));
typedef float f32x4 __attribute__((ext_vector_type(4)));
typedef float f32x2 __attribute__((ext_vector_type(2)));
typedef unsigned short ushort_t;

__device__ __forceinline__ float lrelu(float x) { return x >= 0.f ? x : NEG * x; }

// bf16 <-> f32 helpers (RNE rounding on store)
__device__ __forceinline__ unsigned short f2b(float v) {
  unsigned int b = __float_as_uint(v);
  b += 0x7fffu + ((b >> 16) & 1u);
  return (unsigned short)(b >> 16);
}
__device__ __forceinline__ float b2f(unsigned short u) {
  return __uint_as_float(((unsigned int)u) << 16);
}
__device__ __forceinline__ unsigned int f2b2(float lo, float hi) {
  union { __hip_bfloat162 h; unsigned int u; } cv;
  cv.h = __float22bfloat162_rn(make_float2(lo, hi));
  return cv.u;
}
// unpack packed 2xbf16 word
__device__ __forceinline__ float blo(unsigned int v) { return __uint_as_float(v << 16); }
__device__ __forceinline__ float bhi(unsigned int v) { return __uint_as_float(v & 0xffff0000u); }

// fp8 e4m3 (OCP) hardware converts
__device__ __forceinline__ f32x2 f8x2lo(unsigned int v) {
  return __builtin_amdgcn_cvt_pk_f32_fp8((int)v, false);
}
__device__ __forceinline__ f32x2 f8x2hi(unsigned int v) {
  return __builtin_amdgcn_cvt_pk_f32_fp8((int)v, true);
}
__device__ __forceinline__ unsigned char f2f8(float v) {
  return (unsigned char)(__builtin_amdgcn_cvt_pk_fp8_f32(v, v, 0, false) & 0xff);
}

// ---------- edge-index dtype detection (int32 vs int64) ----------
__global__ void k_detect(const void* ei, int* flag) {
  if (threadIdx.x == 0 && blockIdx.x == 0) {
    const int* p = (const int*)ei;
    int allz = 1;
    for (int i = 0; i < 64; ++i) if (p[2 * i + 1] != 0) { allz = 0; break; }
    *flag = allz;  // 1 => buffer is int64
  }
}

__device__ __forceinline__ int e_src(const void* ei, int f, int e) {
  if (e >= N_EDGES) return e - N_EDGES;              // self loop
  return f ? (int)((const long long*)ei)[e] : ((const int*)ei)[e];
}
__device__ __forceinline__ int e_dst(const void* ei, int f, int e) {
  if (e >= N_EDGES) return e - N_EDGES;              // self loop
  return f ? (int)((const long long*)ei)[N_EDGES + e] : ((const int*)ei)[N_EDGES + e];
}

// ---------- CSR build: 8-way replicated histogram (cuts atomic line-bounce) ----------
__global__ void k_hist(const void* ei, const int* flag, int* degr, int* rank) {
  int e = blockIdx.x * 256 + threadIdx.x;
  if (e >= E_TOT) return;
  int r = blockIdx.x & (NREP - 1);
  int d = e_dst(ei, *flag, e);
  rank[e] = atomicAdd(&degr[r * N_NODES + d], 1);
}

__global__ void k_scan1(const int* __restrict__ degr, int* __restrict__ offs, int* __restrict__ bsums) {
  __shared__ int sm[256];
  int t = threadIdx.x, i = blockIdx.x * 256 + t;
  int v = 0;
  if (i < N_NODES) {
    #pragma unroll
    for (int r = 0; r < NREP; ++r) v += degr[r * N_NODES + i];
  }
  sm[t] = v;
  __syncthreads();
  for (int o = 1; o < 256; o <<= 1) {
    int add = (t >= o) ? sm[t - o] : 0;
    __syncthreads();
    sm[t] += add;
    __syncthreads();
  }
  if (i < N_NODES) offs[i] = sm[t] - v;   // exclusive (block-local)
  if (t == 255) bsums[blockIdx.x] = sm[255];
}

__global__ void k_scan2(int* bsums) {
  __shared__ int sm[256];
  int t = threadIdx.x;
  int v = (t < NB1) ? bsums[t] : 0;
  sm[t] = v;
  __syncthreads();
  for (int o = 1; o < 256; o <<= 1) {
    int add = (t >= o) ? sm[t - o] : 0;
    __syncthreads();
    sm[t] += add;
    __syncthreads();
  }
  if (t < NB1) bsums[t] = sm[t] - v;      // exclusive
}

// finalize offs and compute per-replica bases
__global__ void k_scan3(int* __restrict__ offs, const int* __restrict__ bsums,
                        const int* __restrict__ degr, int* __restrict__ repbase) {
  int i = blockIdx.x * 256 + threadIdx.x;
  if (i < N_NODES) {
    int o = offs[i] + bsums[blockIdx.x];
    offs[i] = o;
    int run = o;
    #pragma unroll
    for (int r = 0; r < NREP; ++r) {
      repbase[r * N_NODES + i] = run;
      run += degr[r * N_NODES + i];
    }
  }
  if (i == 0) offs[N_NODES] = E_TOT;
}

__global__ void k_scatter(const void* ei, const int* __restrict__ flag,
                          const int* __restrict__ repbase,
                          const int* __restrict__ rank, int* __restrict__ srcs) {
  int e = blockIdx.x * 256 + threadIdx.x;
  if (e >= E_TOT) return;
  int f = *flag;
  int d = e_dst(ei, f, e);
  int r = blockIdx.x & (NREP - 1);
  srcs[repbase[r * N_NODES + d] + rank[e]] = e_src(ei, f, e);
}

// ---------- weight prep: bf16 W^T for both layers ----------
__global__ void k_prep(const float* __restrict__ W1, const float* __restrict__ W2,
                       ushort_t* __restrict__ Wt1, ushort_t* __restrict__ Wt2) {
  int i = blockIdx.x * 256 + threadIdx.x;
  if (i < 128 * 128) { int k = i >> 7, n = i & 127; Wt1[n * 128 + k] = f2b(W1[i]); }
  if (i < 128 * 64)  { int k = i >> 6, n = i & 63;  Wt2[n * 128 + k] = f2b(W2[i]); }
}

// ---------- MFMA GEMM1: h1b(bf16) + h1f8(fp8) = bf16(x) @ W1 ----------
__global__ __launch_bounds__(256) void k_mm1(const float* __restrict__ x,
                                             const ushort_t* __restrict__ Wt,
                                             ushort_t* __restrict__ h1b,
                                             unsigned char* __restrict__ h1f8) {
  __shared__ ushort_t xs[32 * 128];   // 8 KB
  int t = threadIdx.x;
  int w = t >> 6, l = t & 63;
  int lr = l & 15, lk = l >> 4;
  int nodeSub = (w & 1) * 16, colBase = (w >> 1) * 64;
  bf16x8 bfrag[4][4];
  #pragma unroll
  for (int ct = 0; ct < 4; ++ct)
    #pragma unroll
    for (int ks = 0; ks < 4; ++ks) {
      int n = colBase + ct * 16 + lr;
      int k = ks * 32 + lk * 8;
      bfrag[ct][ks] = *(const bf16x8*)&Wt[n * 128 + k];
    }
  int rr = t >> 3, c0 = (t & 7) * 16;   // staging: row, 16-elem col group
  for (int chunk = blockIdx.x; chunk < NCHUNK; chunk += gridDim.x) {
    int base = chunk * 32;
    int srcRow = base + rr; if (srcRow >= N_NODES) srcRow = N_NODES - 1;
    const float4* xr = (const float4*)&x[(size_t)srcRow * IN_DIM + c0];
    float4 f0 = xr[0], f1 = xr[1], f2 = xr[2], f3 = xr[3];
    uint4 w0, w1;
    w0.x = f2b2(f0.x, f0.y); w0.y = f2b2(f0.z, f0.w);
    w0.z = f2b2(f1.x, f1.y); w0.w = f2b2(f1.z, f1.w);
    w1.x = f2b2(f2.x, f2.y); w1.y = f2b2(f2.z, f2.w);
    w1.z = f2b2(f3.x, f3.y); w1.w = f2b2(f3.z, f3.w);
    char* xsb = (char*)xs;
    int swz = (rr & 7) << 4;
    *(uint4*)(xsb + rr * 256 + ((c0 * 2 +  0) ^ swz)) = w0;
    *(uint4*)(xsb + rr * 256 + ((c0 * 2 + 16) ^ swz)) = w1;
    __syncthreads();
    f32x4 acc[4] = {{0,0,0,0},{0,0,0,0},{0,0,0,0},{0,0,0,0}};
    int arow = nodeSub + lr;
    #pragma unroll
    for (int ks = 0; ks < 4; ++ks) {
      bf16x8 a = *(const bf16x8*)((const char*)xs + arow * 256 +
                                  ((ks * 64 + lk * 16) ^ ((arow & 7) << 4)));
      #pragma unroll
      for (int ct = 0; ct < 4; ++ct)
        acc[ct] = __builtin_amdgcn_mfma_f32_16x16x32_bf16(a, bfrag[ct][ks], acc[ct], 0, 0, 0);
    }
    __syncthreads();
    #pragma unroll
    for (int ct = 0; ct < 4; ++ct)
      #pragma unroll
      for (int r = 0; r < 4; ++r) {
        int node = base + nodeSub + lk * 4 + r;
        if (node < N_NODES) {
          float v = acc[ct][r];
          int col = colBase + ct * 16 + lr;
          h1b[(size_t)node * HID + col] = f2b(v);
          h1f8[(size_t)node * HID + col] = f2f8(v);
        }
      }
  }
}

// ---------- MFMA GEMM2: h2b(bf16) + h2f8(fp8) = out1b @ W2 ----------
__global__ __launch_bounds__(256) void k_mm2(const ushort_t* __restrict__ xb,
                                             const ushort_t* __restrict__ Wt,
                                             ushort_t* __restrict__ h2b,
                                             unsigned char* __restrict__ h2f8) {
  __shared__ ushort_t xs[32 * 128];   // 8 KB
  int t = threadIdx.x;
  int w = t >> 6, l = t & 63;
  int lr = l & 15, lk = l >> 4;
  int nodeSub = (w & 1) * 16, colBase = (w >> 1) * 32;
  bf16x8 bfrag[2][4];
  #pragma unroll
  for (int ct = 0; ct < 2; ++ct)
    #pragma unroll
    for (int ks = 0; ks < 4; ++ks) {
      int n = colBase + ct * 16 + lr;
      int k = ks * 32 + lk * 8;
      bfrag[ct][ks] = *(const bf16x8*)&Wt[n * 128 + k];
    }
  int rr = t >> 3, c0 = (t & 7) * 16;
  for (int chunk = blockIdx.x; chunk < NCHUNK; chunk += gridDim.x) {
    int base = chunk * 32;
    int srcRow = base + rr; if (srcRow >= N_NODES) srcRow = N_NODES - 1;
    const uint4* xr = (const uint4*)&xb[(size_t)srcRow * HID + c0];
    uint4 w0 = xr[0], w1 = xr[1];
    char* xsb = (char*)xs;
    int swz = (rr & 7) << 4;
    *(uint4*)(xsb + rr * 256 + ((c0 * 2 +  0) ^ swz)) = w0;
    *(uint4*)(xsb + rr * 256 + ((c0 * 2 + 16) ^ swz)) = w1;
    __syncthreads();
    f32x4 acc[2] = {{0,0,0,0},{0,0,0,0}};
    int arow = nodeSub + lr;
    #pragma unroll
    for (int ks = 0; ks < 4; ++ks) {
      bf16x8 a = *(const bf16x8*)((const char*)xs + arow * 256 +
                                  ((ks * 64 + lk * 16) ^ ((arow & 7) << 4)));
      #pragma unroll
      for (int ct = 0; ct < 2; ++ct)
        acc[ct] = __builtin_amdgcn_mfma_f32_16x16x32_bf16(a, bfrag[ct][ks], acc[ct], 0, 0, 0);
    }
    __syncthreads();
    #pragma unroll
    for (int ct = 0; ct < 2; ++ct)
      #pragma unroll
      for (int r = 0; r < 4; ++r) {
        int node = base + nodeSub + lk * 4 + r;
        if (node < N_NODES) {
          float v = acc[ct][r];
          int col = colBase + ct * 16 + lr;
          h2b[(size_t)node * ODIM + col] = f2b(v);
          h2f8[(size_t)node * ODIM + col] = f2f8(v);
        }
      }
  }
}

// ---------- attention logits: 16B loads, 8 cols/lane ----------
__global__ __launch_bounds__(256) void k_al1(const ushort_t* __restrict__ h1b,
                                             const float* __restrict__ asrc,
                                             const float* __restrict__ adst, float* __restrict__ als,
                                             float* __restrict__ ald) {
  int t = threadIdx.x;
  int n = blockIdx.x * 16 + (t >> 4);
  int c8 = (t & 15) * 8;
  uint4 v = *(const uint4*)&h1b[(size_t)n * HID + c8];
  float4 a0 = *(const float4*)&asrc[c8], a1 = *(const float4*)&asrc[c8 + 4];
  float4 d0 = *(const float4*)&adst[c8], d1 = *(const float4*)&adst[c8 + 4];
  float f0 = blo(v.x), f1 = bhi(v.x), f2 = blo(v.y), f3 = bhi(v.y);
  float f4 = blo(v.z), f5 = bhi(v.z), f6 = blo(v.w), f7 = bhi(v.w);
  float s = f0*a0.x + f1*a0.y + f2*a0.z + f3*a0.w + f4*a1.x + f5*a1.y + f6*a1.z + f7*a1.w;
  float d = f0*d0.x + f1*d0.y + f2*d0.z + f3*d0.w + f4*d1.x + f5*d1.y + f6*d1.z + f7*d1.w;
  s += __shfl_xor(s, 1); s += __shfl_xor(s, 2);
  d += __shfl_xor(d, 1); d += __shfl_xor(d, 2);
  if ((t & 3) == 0) {
    int head = (t & 15) >> 2;
    als[n * 4 + head] = s;
    ald[n * 4 + head] = d;
  }
}

__global__ __launch_bounds__(256) void k_al2(const ushort_t* __restrict__ h2b,
                                             const float* __restrict__ asrc,
                                             const float* __restrict__ adst, float* __restrict__ als,
                                             float* __restrict__ ald) {
  int t = threadIdx.x;
  int n = blockIdx.x * 32 + (t >> 3);
  if (n >= N_NODES) return;
  int c8 = (t & 7) * 8;
  uint4 v = *(const uint4*)&h2b[(size_t)n * ODIM + c8];
  float4 a0 = *(const float4*)&asrc[c8], a1 = *(const float4*)&asrc[c8 + 4];
  float4 d0 = *(const float4*)&adst[c8], d1 = *(const float4*)&adst[c8 + 4];
  float f0 = blo(v.x), f1 = bhi(v.x), f2 = blo(v.y), f3 = bhi(v.y);
  float f4 = blo(v.z), f5 = bhi(v.z), f6 = blo(v.w), f7 = bhi(v.w);
  float s = f0*a0.x + f1*a0.y + f2*a0.z + f3*a0.w + f4*a1.x + f5*a1.y + f6*a1.z + f7*a1.w;
  float d = f0*d0.x + f1*d0.y + f2*d0.z + f3*d0.w + f4*d1.x + f5*d1.y + f6*d1.z + f7*d1.w;
  s += __shfl_xor(s, 1); s += __shfl_xor(s, 2); s += __shfl_xor(s, 4);
  d += __shfl_xor(d, 1); d += __shfl_xor(d, 2); d += __shfl_xor(d, 4);
  if ((t & 7) == 0) { als[n] = s; ald[n] = d; }
}

// ---------- layer-1 aggregate: ONE WAVE per node; fused denominator;
// gather 8 edges/iter with 2 loads in flight; unconditional fma (invalid edges carry w=0).
__global__ __launch_bounds__(256) void k_agg1(const unsigned char* __restrict__ h1f8,
                                              const float* __restrict__ als,
                                              const float* __restrict__ ald, const int* __restrict__ offs,
                                              const int* __restrict__ srcs, const float* __restrict__ b1,
                                              ushort_t* __restrict__ out1b) {
  int t = threadIdx.x;
  int w = t >> 6, l = t & 63;
  int eg = l >> 4, cl = l & 15, head = cl >> 2;
  int n = blockIdx.x * 4 + w;
  int off0 = offs[n], deg = offs[n + 1] - off0;
  const float4* als4 = (const float4*)als;
  float4 ad = ((const float4*)ald)[n];
  const unsigned char* hb = h1f8 + cl * 8;

  float ds = 0.f;
  float num0 = 0, num1 = 0, num2 = 0, num3 = 0, num4 = 0, num5 = 0, num6 = 0, num7 = 0;

  for (int cbase = 0; cbase < deg; cbase += 64) {
    int j0 = cbase + l;
    float w0 = 0.f, w1 = 0.f, w2 = 0.f, w3 = 0.f;
    int sb = 0;
    if (j0 < deg) {
      int s = srcs[off0 + j0];
      sb = s << 7;
      float4 a = als4[s];
      w0 = __expf(lrelu(a.x + ad.x)); w1 = __expf(lrelu(a.y + ad.y));
      w2 = __expf(lrelu(a.z + ad.z)); w3 = __expf(lrelu(a.w + ad.w));
    }
    int pw01 = (int)f2b2(w0, w1), pw23 = (int)f2b2(w2, w3);
    int cn = (deg - cbase) < 64 ? (deg - cbase) : 64;
    for (int jj = 0; jj < cn; jj += 8) {
      int jA = jj + eg, jB = jj + 4 + eg;
      int boA = __shfl(sb, jA), boB = __shfl(sb, jB);
      uint2 vA = *(const uint2*)(hb + boA);     // both loads issued before
      uint2 vB = *(const uint2*)(hb + boB);     // either result is consumed
      unsigned int uA01 = (unsigned int)__shfl(pw01, jA);
      unsigned int uA23 = (unsigned int)__shfl(pw23, jA);
      unsigned int uB01 = (unsigned int)__shfl(pw01, jB);
      unsigned int uB23 = (unsigned int)__shfl(pw23, jB);
      unsigned int upA = head < 2 ? uA01 : uA23;
      unsigned int upB = head < 2 ? uB01 : uB23;
      float wA = (head & 1) ? bhi(upA) : blo(upA);
      float wB = (head & 1) ? bhi(upB) : blo(upB);
      ds += wA + wB;                            // fused denominator
      f32x2 p0 = f8x2lo(vA.x), p1 = f8x2hi(vA.x);
      f32x2 p2 = f8x2lo(vA.y), p3 = f8x2hi(vA.y);
      num0 = fmaf(wA, p0.x, num0); num1 = fmaf(wA, p0.y, num1);
      num2 = fmaf(wA, p1.x, num2); num3 = fmaf(wA, p1.y, num3);
      num4 = fmaf(wA, p2.x, num4); num5 = fmaf(wA, p2.y, num5);
      num6 = fmaf(wA, p3.x, num6); num7 = fmaf(wA, p3.y, num7);
      p0 = f8x2lo(vB.x); p1 = f8x2hi(vB.x);
      p2 = f8x2lo(vB.y); p3 = f8x2hi(vB.y);
      num0 = fmaf(wB, p0.x, num0); num1 = fmaf(wB, p0.y, num1);
      num2 = fmaf(wB, p1.x, num2); num3 = fmaf(wB, p1.y, num3);
      num4 = fmaf(wB, p2.x, num4); num5 = fmaf(wB, p2.y, num5);
      num6 = fmaf(wB, p3.x, num6); num7 = fmaf(wB, p3.y, num7);
    }
  }
  // combine the 4 edge-subgroups (lanes with equal cl); ds rides along
  #pragma unroll
  for (int o = 16; o <= 32; o <<= 1) {
    num0 += __shfl_xor(num0, o); num1 += __shfl_xor(num1, o);
    num2 += __shfl_xor(num2, o); num3 += __shfl_xor(num3, o);
    num4 += __shfl_xor(num4, o); num5 += __shfl_xor(num5, o);
    num6 += __shfl_xor(num6, o); num7 += __shfl_xor(num7, o);
    ds += __shfl_xor(ds, o);
  }
  if (l < 16) {
    float rd = 1.f / ds;
    int c8 = cl * 8;
    float4 bb0 = *(const float4*)&b1[c8];
    float4 bb1 = *(const float4*)&b1[c8 + 4];
    float o0 = fmaxf(num0 * rd + bb0.x, 0.f);
    float o1 = fmaxf(num1 * rd + bb0.y, 0.f);
    float o2 = fmaxf(num2 * rd + bb0.z, 0.f);
    float o3 = fmaxf(num3 * rd + bb0.w, 0.f);
    float o4 = fmaxf(num4 * rd + bb1.x, 0.f);
    float o5 = fmaxf(num5 * rd + bb1.y, 0.f);
    float o6 = fmaxf(num6 * rd + bb1.z, 0.f);
    float o7 = fmaxf(num7 * rd + bb1.w, 0.f);
    uint4 pk;
    pk.x = f2b2(o0, o1); pk.y = f2b2(o2, o3);
    pk.z = f2b2(o4, o5); pk.w = f2b2(o6, o7);
    *(uint4*)&out1b[(size_t)n * HID + c8] = pk;
  }
}

// ---------- layer-2 aggregate + log_softmax: ONE WAVE per node; fused denominator;
// gather 16 edges/iter with 2 loads in flight; unconditional fma.
__global__ __launch_bounds__(256) void k_agg2(const unsigned char* __restrict__ h2f8,
                                              const float* __restrict__ als,
                                              const float* __restrict__ ald, const int* __restrict__ offs,
                                              const int* __restrict__ srcs, const float* __restrict__ b2,
                                              float* __restrict__ out) {
  int t = threadIdx.x;
  int w = t >> 6, l = t & 63;
  int eg = l >> 3, cl = l & 7;
  int n = blockIdx.x * 4 + w;
  int off0 = offs[n], deg = offs[n + 1] - off0;
  float adv = ald[n];
  const unsigned char* hb = h2f8 + cl * 8;

  float ds = 0.f;
  float num0 = 0, num1 = 0, num2 = 0, num3 = 0, num4 = 0, num5 = 0, num6 = 0, num7 = 0;

  for (int cbase = 0; cbase < deg; cbase += 64) {
    int j0 = cbase + l;
    float wv = 0.f;
    int sb = 0;
    if (j0 < deg) {
      int s = srcs[off0 + j0];
      sb = s << 6;
      wv = __expf(lrelu(als[s] + adv));
    }
    int cn = (deg - cbase) < 64 ? (deg - cbase) : 64;
    for (int jj = 0; jj < cn; jj += 16) {
      int jA = jj + eg, jB = jj + 8 + eg;
      int boA = __shfl(sb, jA), boB = __shfl(sb, jB);
      uint2 vA = *(const uint2*)(hb + boA);
      uint2 vB = *(const uint2*)(hb + boB);
      float wA = __shfl(wv, jA), wB = __shfl(wv, jB);
      ds += wA + wB;
      f32x2 p0 = f8x2lo(vA.x), p1 = f8x2hi(vA.x);
      f32x2 p2 = f8x2lo(vA.y), p3 = f8x2hi(vA.y);
      num0 = fmaf(wA, p0.x, num0); num1 = fmaf(wA, p0.y, num1);
      num2 = fmaf(wA, p1.x, num2); num3 = fmaf(wA, p1.y, num3);
      num4 = fmaf(wA, p2.x, num4); num5 = fmaf(wA, p2.y, num5);
      num6 = fmaf(wA, p3.x, num6); num7 = fmaf(wA, p3.y, num7);
      p0 = f8x2lo(vB.x); p1 = f8x2hi(vB.x);
      p2 = f8x2lo(vB.y); p3 = f8x2hi(vB.y);
      num0 = fmaf(wB, p0.x, num0); num1 = fmaf(wB, p0.y, num1);
      num2 = fmaf(wB, p1.x, num2); num3 = fmaf(wB, p1.y, num3);
      num4 = fmaf(wB, p2.x, num4); num5 = fmaf(wB, p2.y, num5);
      num6 = fmaf(wB, p3.x, num6); num7 = fmaf(wB, p3.y, num7);
    }
  }
  #pragma unroll
  for (int o = 8; o <= 32; o <<= 1) {
    num0 += __shfl_xor(num0, o); num1 += __shfl_xor(num1, o);
    num2 += __shfl_xor(num2, o); num3 += __shfl_xor(num3, o);
    num4 += __shfl_xor(num4, o); num5 += __shfl_xor(num5, o);
    num6 += __shfl_xor(num6, o); num7 += __shfl_xor(num7, o);
    ds += __shfl_xor(ds, o);
  }
  if (l < 8) {
    float rd = 1.f / ds;
    int c8 = cl * 8;
    float4 bb0 = *(const float4*)&b2[c8];
    float4 bb1 = *(const float4*)&b2[c8 + 4];
    float v0 = num0 * rd + bb0.x, v1 = num1 * rd + bb0.y;
    float v2 = num2 * rd + bb0.z, v3 = num3 * rd + bb0.w;
    float v4 = num4 * rd + bb1.x, v5 = num5 * rd + bb1.y;
    float v6 = num6 * rd + bb1.z, v7 = num7 * rd + bb1.w;
    // log_softmax over 64 outputs held by 8 lanes x 8 regs
    float mx = fmaxf(fmaxf(fmaxf(v0, v1), fmaxf(v2, v3)), fmaxf(fmaxf(v4, v5), fmaxf(v6, v7)));
    #pragma unroll
    for (int o = 1; o <= 4; o <<= 1) mx = fmaxf(mx, __shfl_xor(mx, o));
    float sum = __expf(v0 - mx) + __expf(v1 - mx) + __expf(v2 - mx) + __expf(v3 - mx)
              + __expf(v4 - mx) + __expf(v5 - mx) + __expf(v6 - mx) + __expf(v7 - mx);
    #pragma unroll
    for (int o = 1; o <= 4; o <<= 1) sum += __shfl_xor(sum, o);
    float ls = __logf(sum);
    float4 r0, r1;
    r0.x = (v0 - mx) - ls; r0.y = (v1 - mx) - ls; r0.z = (v2 - mx) - ls; r0.w = (v3 - mx) - ls;
    r1.x = (v4 - mx) - ls; r1.y = (v5 - mx) - ls; r1.z = (v6 - mx) - ls; r1.w = (v7 - mx) - ls;
    *(float4*)&out[(size_t)n * ODIM + c8] = r0;
    *(float4*)&out[(size_t)n * ODIM + c8 + 4] = r1;
  }
}

extern "C" void kernel_launch(void* const* d_in, const int* in_sizes, int n_in,
                              void* d_out, int out_size, void* d_ws, size_t ws_size,
                              hipStream_t stream) {
  const float* x   = (const float*)d_in[0];
  const void*  ei  = d_in[1];
  const float* W1  = (const float*)d_in[2];
  const float* as1 = (const float*)d_in[3];
  const float* ad1 = (const float*)d_in[4];
  const float* b1  = (const float*)d_in[5];
  const float* W2  = (const float*)d_in[6];
  const float* as2 = (const float*)d_in[7];
  const float* ad2 = (const float*)d_in[8];
  const float* b2  = (const float*)d_in[9];
  float* out = (float*)d_out;

  char* ws = (char*)d_ws;
  size_t o = 0;
  auto alloc = [&](size_t bytes) { void* p = (void*)(ws + o); o += (bytes + 255) & ~(size_t)255; return p; };
  ushort_t* h1b   = (ushort_t*)alloc((size_t)N_NODES * HID * 2);
  ushort_t* out1b = (ushort_t*)alloc((size_t)N_NODES * HID * 2);
  ushort_t* h2b   = (ushort_t*)alloc((size_t)N_NODES * ODIM * 2);
  unsigned char* h1f8 = (unsigned char*)alloc((size_t)N_NODES * HID);
  ushort_t* Wt1   = (ushort_t*)alloc((size_t)128 * 128 * 2);
  ushort_t* Wt2   = (ushort_t*)alloc((size_t)64 * 128 * 2);
  float* als1 = (float*)alloc((size_t)N_NODES * 4 * 4);
  float* ald1 = (float*)alloc((size_t)N_NODES * 4 * 4);
  float* als2 = (float*)alloc((size_t)N_NODES * 4);
  float* ald2 = (float*)alloc((size_t)N_NODES * 4);
  int*   degr = (int*)alloc((size_t)NREP * N_NODES * 4);
  int*   repbase = (int*)alloc((size_t)NREP * N_NODES * 4);
  int*   offs = (int*)alloc((size_t)(N_NODES + 1) * 4);
  int*   rank = (int*)alloc((size_t)E_TOT * 4);
  int*   srcs = (int*)alloc((size_t)E_TOT * 4);
  int*   bsums= (int*)alloc((size_t)NB1 * 4);
  int*   flag = (int*)alloc(4);
  // h2f8 (3.2 MB) aliases rank (3.4 MB): rank is dead after k_scatter
  unsigned char* h2f8 = (unsigned char*)rank;

  hipMemsetAsync(degr, 0, (size_t)NREP * N_NODES * 4, stream);
  k_detect<<<1, 64, 0, stream>>>(ei, flag);

  int egrid = (E_TOT + 255) / 256;
  k_hist   <<<egrid, 256, 0, stream>>>(ei, flag, degr, rank);
  k_scan1  <<<NB1,   256, 0, stream>>>(degr, offs, bsums);
  k_scan2  <<<1,     256, 0, stream>>>(bsums);
  k_scan3  <<<NB1,   256, 0, stream>>>(offs, bsums, degr, repbase);
  k_scatter<<<egrid, 256, 0, stream>>>(ei, flag, repbase, rank, srcs);
  k_prep   <<<64,    256, 0, stream>>>(W1, W2, Wt1, Wt2);

  k_mm1  <<<512, 256, 0, stream>>>(x, Wt1, h1b, h1f8);
  k_al1  <<<N_NODES / 16, 256, 0, stream>>>(h1b, as1, ad1, als1, ald1);
  k_agg1 <<<(N_NODES + 3) / 4, 256, 0, stream>>>(h1f8, als1, ald1, offs, srcs, b1, out1b);

  k_mm2  <<<512, 256, 0, stream>>>(out1b, Wt2, h2b, h2f8);
  k_al2  <<<(N_NODES + 31) / 32, 256, 0, stream>>>(h2b, as2, ad2, als2, ald2);
  k_agg2 <<<(N_NODES + 3) / 4, 256, 0, stream>>>(h2f8, als2, ald2, offs, srcs, b2, out);
}

// Round 10
// 134.332 us; speedup vs baseline: 1.5095x; 1.1059x over previous
//
#include <hip/hip_runtime.h>
#include <hip/hip_bf16.h>
#include <math.h>

#define N_NODES 50000
#define N_EDGES 800000
#define E_TOT   (N_EDGES + N_NODES)
#define IN_DIM  128
#define HID     128      // HEADS*HIDDEN (layer-1 output width)
#define ODIM    64
#define NEG     0.2f
#define NB1     ((N_NODES + 255) / 256)   // scan blocks = 196
#define NCHUNK  ((N_NODES + 31) / 32)     // 32-node chunks for MFMA GEMMs
#define NREP    8

typedef short bf16x8 __attribute__((ext_vector_type(8)));
typedef float f32x4 __attribute__((ext_vector_type(4)));
typedef float f32x2 __attribute__((ext_vector_type(2)));
typedef unsigned short ushort_t;

__device__ __forceinline__ float lrelu(float x) { return x >= 0.f ? x : NEG * x; }

// bf16 <-> f32 helpers (RNE rounding on store)
__device__ __forceinline__ unsigned short f2b(float v) {
  unsigned int b = __float_as_uint(v);
  b += 0x7fffu + ((b >> 16) & 1u);
  return (unsigned short)(b >> 16);
}
__device__ __forceinline__ float b2f(unsigned short u) {
  return __uint_as_float(((unsigned int)u) << 16);
}
__device__ __forceinline__ unsigned int f2b2(float lo, float hi) {
  union { __hip_bfloat162 h; unsigned int u; } cv;
  cv.h = __float22bfloat162_rn(make_float2(lo, hi));
  return cv.u;
}
// unpack packed 2xbf16 word
__device__ __forceinline__ float blo(unsigned int v) { return __uint_as_float(v << 16); }
__device__ __forceinline__ float bhi(unsigned int v) { return __uint_as_float(v & 0xffff0000u); }

// fp8 e4m3 (OCP) hardware converts
__device__ __forceinline__ f32x2 f8x2lo(unsigned int v) {
  return __builtin_amdgcn_cvt_pk_f32_fp8((int)v, false);
}
__device__ __forceinline__ f32x2 f8x2hi(unsigned int v) {
  return __builtin_amdgcn_cvt_pk_f32_fp8((int)v, true);
}
__device__ __forceinline__ unsigned char f2f8(float v) {
  return (unsigned char)(__builtin_amdgcn_cvt_pk_fp8_f32(v, v, 0, false) & 0xff);
}

__device__ __forceinline__ int e_src(const void* ei, int f, int e) {
  if (e >= N_EDGES) return e - N_EDGES;              // self loop
  return f ? (int)((const long long*)ei)[e] : ((const int*)ei)[e];
}
__device__ __forceinline__ int e_dst(const void* ei, int f, int e) {
  if (e >= N_EDGES) return e - N_EDGES;              // self loop
  return f ? (int)((const long long*)ei)[N_EDGES + e] : ((const int*)ei)[N_EDGES + e];
}

// ---------- weight prep (bf16 W^T) + edge-index dtype detection (block 64) ----------
__global__ void k_prep(const float* __restrict__ W1, const float* __restrict__ W2,
                       ushort_t* __restrict__ Wt1, ushort_t* __restrict__ Wt2,
                       const void* ei, int* flag) {
  if (blockIdx.x == 64) {
    if (threadIdx.x == 0) {
      const int* p = (const int*)ei;
      int allz = 1;
      for (int i = 0; i < 64; ++i) if (p[2 * i + 1] != 0) { allz = 0; break; }
      *flag = allz;  // 1 => buffer is int64
    }
    return;
  }
  int i = blockIdx.x * 256 + threadIdx.x;
  if (i < 128 * 128) { int k = i >> 7, n = i & 127; Wt1[n * 128 + k] = f2b(W1[i]); }
  if (i < 128 * 64)  { int k = i >> 6, n = i & 63;  Wt2[n * 128 + k] = f2b(W2[i]); }
}

// ---------- CSR build: 8-way replicated histogram (cuts atomic line-bounce) ----------
__global__ void k_hist(const void* ei, const int* flag, int* degr, int* rank) {
  int e = blockIdx.x * 256 + threadIdx.x;
  if (e >= E_TOT) return;
  int r = blockIdx.x & (NREP - 1);
  int d = e_dst(ei, *flag, e);
  rank[e] = atomicAdd(&degr[r * N_NODES + d], 1);
}

__global__ void k_scan1(const int* __restrict__ degr, int* __restrict__ offs, int* __restrict__ bsums) {
  __shared__ int sm[256];
  int t = threadIdx.x, i = blockIdx.x * 256 + t;
  int v = 0;
  if (i < N_NODES) {
    #pragma unroll
    for (int r = 0; r < NREP; ++r) v += degr[r * N_NODES + i];
  }
  sm[t] = v;
  __syncthreads();
  for (int o = 1; o < 256; o <<= 1) {
    int add = (t >= o) ? sm[t - o] : 0;
    __syncthreads();
    sm[t] += add;
    __syncthreads();
  }
  if (i < N_NODES) offs[i] = sm[t] - v;   // exclusive (block-local)
  if (t == 255) bsums[blockIdx.x] = sm[255];
}

__global__ void k_scan2(int* bsums) {
  __shared__ int sm[256];
  int t = threadIdx.x;
  int v = (t < NB1) ? bsums[t] : 0;
  sm[t] = v;
  __syncthreads();
  for (int o = 1; o < 256; o <<= 1) {
    int add = (t >= o) ? sm[t - o] : 0;
    __syncthreads();
    sm[t] += add;
    __syncthreads();
  }
  if (t < NB1) bsums[t] = sm[t] - v;      // exclusive
}

// finalize offs and compute per-replica bases
__global__ void k_scan3(int* __restrict__ offs, const int* __restrict__ bsums,
                        const int* __restrict__ degr, int* __restrict__ repbase) {
  int i = blockIdx.x * 256 + threadIdx.x;
  if (i < N_NODES) {
    int o = offs[i] + bsums[blockIdx.x];
    offs[i] = o;
    int run = o;
    #pragma unroll
    for (int r = 0; r < NREP; ++r) {
      repbase[r * N_NODES + i] = run;
      run += degr[r * N_NODES + i];
    }
  }
  if (i == 0) offs[N_NODES] = E_TOT;
}

__global__ void k_scatter(const void* ei, const int* __restrict__ flag,
                          const int* __restrict__ repbase,
                          const int* __restrict__ rank, int* __restrict__ srcs) {
  int e = blockIdx.x * 256 + threadIdx.x;
  if (e >= E_TOT) return;
  int f = *flag;
  int d = e_dst(ei, f, e);
  int r = blockIdx.x & (NREP - 1);
  srcs[repbase[r * N_NODES + d] + rank[e]] = e_src(ei, f, e);
}

// ---------- MFMA GEMM1: h1b(bf16) + h1f8(fp8) = bf16(x) @ W1 ----------
__global__ __launch_bounds__(256) void k_mm1(const float* __restrict__ x,
                                             const ushort_t* __restrict__ Wt,
                                             ushort_t* __restrict__ h1b,
                                             unsigned char* __restrict__ h1f8) {
  __shared__ ushort_t xs[32 * 128];   // 8 KB
  int t = threadIdx.x;
  int w = t >> 6, l = t & 63;
  int lr = l & 15, lk = l >> 4;
  int nodeSub = (w & 1) * 16, colBase = (w >> 1) * 64;
  bf16x8 bfrag[4][4];
  #pragma unroll
  for (int ct = 0; ct < 4; ++ct)
    #pragma unroll
    for (int ks = 0; ks < 4; ++ks) {
      int n = colBase + ct * 16 + lr;
      int k = ks * 32 + lk * 8;
      bfrag[ct][ks] = *(const bf16x8*)&Wt[n * 128 + k];
    }
  int rr = t >> 3, c0 = (t & 7) * 16;   // staging: row, 16-elem col group
  for (int chunk = blockIdx.x; chunk < NCHUNK; chunk += gridDim.x) {
    int base = chunk * 32;
    int srcRow = base + rr; if (srcRow >= N_NODES) srcRow = N_NODES - 1;
    const float4* xr = (const float4*)&x[(size_t)srcRow * IN_DIM + c0];
    float4 f0 = xr[0], f1 = xr[1], f2 = xr[2], f3 = xr[3];
    uint4 w0, w1;
    w0.x = f2b2(f0.x, f0.y); w0.y = f2b2(f0.z, f0.w);
    w0.z = f2b2(f1.x, f1.y); w0.w = f2b2(f1.z, f1.w);
    w1.x = f2b2(f2.x, f2.y); w1.y = f2b2(f2.z, f2.w);
    w1.z = f2b2(f3.x, f3.y); w1.w = f2b2(f3.z, f3.w);
    char* xsb = (char*)xs;
    int swz = (rr & 7) << 4;
    *(uint4*)(xsb + rr * 256 + ((c0 * 2 +  0) ^ swz)) = w0;
    *(uint4*)(xsb + rr * 256 + ((c0 * 2 + 16) ^ swz)) = w1;
    __syncthreads();
    f32x4 acc[4] = {{0,0,0,0},{0,0,0,0},{0,0,0,0},{0,0,0,0}};
    int arow = nodeSub + lr;
    #pragma unroll
    for (int ks = 0; ks < 4; ++ks) {
      bf16x8 a = *(const bf16x8*)((const char*)xs + arow * 256 +
                                  ((ks * 64 + lk * 16) ^ ((arow & 7) << 4)));
      #pragma unroll
      for (int ct = 0; ct < 4; ++ct)
        acc[ct] = __builtin_amdgcn_mfma_f32_16x16x32_bf16(a, bfrag[ct][ks], acc[ct], 0, 0, 0);
    }
    __syncthreads();
    #pragma unroll
    for (int ct = 0; ct < 4; ++ct)
      #pragma unroll
      for (int r = 0; r < 4; ++r) {
        int node = base + nodeSub + lk * 4 + r;
        if (node < N_NODES) {
          float v = acc[ct][r];
          int col = colBase + ct * 16 + lr;
          h1b[(size_t)node * HID + col] = f2b(v);
          h1f8[(size_t)node * HID + col] = f2f8(v);
        }
      }
  }
}

// ---------- MFMA GEMM2: h2b(bf16) + h2f8(fp8) = out1b @ W2 ----------
__global__ __launch_bounds__(256) void k_mm2(const ushort_t* __restrict__ xb,
                                             const ushort_t* __restrict__ Wt,
                                             ushort_t* __restrict__ h2b,
                                             unsigned char* __restrict__ h2f8) {
  __shared__ ushort_t xs[32 * 128];   // 8 KB
  int t = threadIdx.x;
  int w = t >> 6, l = t & 63;
  int lr = l & 15, lk = l >> 4;
  int nodeSub = (w & 1) * 16, colBase = (w >> 1) * 32;
  bf16x8 bfrag[2][4];
  #pragma unroll
  for (int ct = 0; ct < 2; ++ct)
    #pragma unroll
    for (int ks = 0; ks < 4; ++ks) {
      int n = colBase + ct * 16 + lr;
      int k = ks * 32 + lk * 8;
      bfrag[ct][ks] = *(const bf16x8*)&Wt[n * 128 + k];
    }
  int rr = t >> 3, c0 = (t & 7) * 16;
  for (int chunk = blockIdx.x; chunk < NCHUNK; chunk += gridDim.x) {
    int base = chunk * 32;
    int srcRow = base + rr; if (srcRow >= N_NODES) srcRow = N_NODES - 1;
    const uint4* xr = (const uint4*)&xb[(size_t)srcRow * HID + c0];
    uint4 w0 = xr[0], w1 = xr[1];
    char* xsb = (char*)xs;
    int swz = (rr & 7) << 4;
    *(uint4*)(xsb + rr * 256 + ((c0 * 2 +  0) ^ swz)) = w0;
    *(uint4*)(xsb + rr * 256 + ((c0 * 2 + 16) ^ swz)) = w1;
    __syncthreads();
    f32x4 acc[2] = {{0,0,0,0},{0,0,0,0}};
    int arow = nodeSub + lr;
    #pragma unroll
    for (int ks = 0; ks < 4; ++ks) {
      bf16x8 a = *(const bf16x8*)((const char*)xs + arow * 256 +
                                  ((ks * 64 + lk * 16) ^ ((arow & 7) << 4)));
      #pragma unroll
      for (int ct = 0; ct < 2; ++ct)
        acc[ct] = __builtin_amdgcn_mfma_f32_16x16x32_bf16(a, bfrag[ct][ks], acc[ct], 0, 0, 0);
    }
    __syncthreads();
    #pragma unroll
    for (int ct = 0; ct < 2; ++ct)
      #pragma unroll
      for (int r = 0; r < 4; ++r) {
        int node = base + nodeSub + lk * 4 + r;
        if (node < N_NODES) {
          float v = acc[ct][r];
          int col = colBase + ct * 16 + lr;
          h2b[(size_t)node * ODIM + col] = f2b(v);
          h2f8[(size_t)node * ODIM + col] = f2f8(v);
        }
      }
  }
}

// ---------- attention logits: 16B loads, 8 cols/lane ----------
__global__ __launch_bounds__(256) void k_al1(const ushort_t* __restrict__ h1b,
                                             const float* __restrict__ asrc,
                                             const float* __restrict__ adst, float* __restrict__ als,
                                             float* __restrict__ ald) {
  int t = threadIdx.x;
  int n = blockIdx.x * 16 + (t >> 4);
  int c8 = (t & 15) * 8;
  uint4 v = *(const uint4*)&h1b[(size_t)n * HID + c8];
  float4 a0 = *(const float4*)&asrc[c8], a1 = *(const float4*)&asrc[c8 + 4];
  float4 d0 = *(const float4*)&adst[c8], d1 = *(const float4*)&adst[c8 + 4];
  float f0 = blo(v.x), f1 = bhi(v.x), f2 = blo(v.y), f3 = bhi(v.y);
  float f4 = blo(v.z), f5 = bhi(v.z), f6 = blo(v.w), f7 = bhi(v.w);
  float s = f0*a0.x + f1*a0.y + f2*a0.z + f3*a0.w + f4*a1.x + f5*a1.y + f6*a1.z + f7*a1.w;
  float d = f0*d0.x + f1*d0.y + f2*d0.z + f3*d0.w + f4*d1.x + f5*d1.y + f6*d1.z + f7*d1.w;
  s += __shfl_xor(s, 1); s += __shfl_xor(s, 2);
  d += __shfl_xor(d, 1); d += __shfl_xor(d, 2);
  if ((t & 3) == 0) {
    int head = (t & 15) >> 2;
    als[n * 4 + head] = s;
    ald[n * 4 + head] = d;
  }
}

__global__ __launch_bounds__(256) void k_al2(const ushort_t* __restrict__ h2b,
                                             const float* __restrict__ asrc,
                                             const float* __restrict__ adst, float* __restrict__ als,
                                             float* __restrict__ ald) {
  int t = threadIdx.x;
  int n = blockIdx.x * 32 + (t >> 3);
  if (n >= N_NODES) return;
  int c8 = (t & 7) * 8;
  uint4 v = *(const uint4*)&h2b[(size_t)n * ODIM + c8];
  float4 a0 = *(const float4*)&asrc[c8], a1 = *(const float4*)&asrc[c8 + 4];
  float4 d0 = *(const float4*)&adst[c8], d1 = *(const float4*)&adst[c8 + 4];
  float f0 = blo(v.x), f1 = bhi(v.x), f2 = blo(v.y), f3 = bhi(v.y);
  float f4 = blo(v.z), f5 = bhi(v.z), f6 = blo(v.w), f7 = bhi(v.w);
  float s = f0*a0.x + f1*a0.y + f2*a0.z + f3*a0.w + f4*a1.x + f5*a1.y + f6*a1.z + f7*a1.w;
  float d = f0*d0.x + f1*d0.y + f2*d0.z + f3*d0.w + f4*d1.x + f5*d1.y + f6*d1.z + f7*d1.w;
  s += __shfl_xor(s, 1); s += __shfl_xor(s, 2); s += __shfl_xor(s, 4);
  d += __shfl_xor(d, 1); d += __shfl_xor(d, 2); d += __shfl_xor(d, 4);
  if ((t & 7) == 0) { als[n] = s; ald[n] = d; }
}

// ---------- layer-1 aggregate: TWO nodes per wave (32-lane half per node);
// fused denominator; 2 subgroups/half, 4 edges/iter, 2 loads in flight per subgroup pair.
__global__ __launch_bounds__(256) void k_agg1(const unsigned char* __restrict__ h1f8,
                                              const float* __restrict__ als,
                                              const float* __restrict__ ald, const int* __restrict__ offs,
                                              const int* __restrict__ srcs, const float* __restrict__ b1,
                                              ushort_t* __restrict__ out1b) {
  int t = threadIdx.x;
  int w = t >> 6, l = t & 63;
  int hw = l >> 5, lh = l & 31;          // half index, lane-in-half
  int sg = lh >> 4, cl = lh & 15, head = cl >> 2;
  int lbase = hw << 5;                   // absolute lane base of this half
  int n = blockIdx.x * 8 + w * 2 + hw;   // grid = N/8 = 6250 exact
  int off0 = offs[n], deg = offs[n + 1] - off0;
  const float4* als4 = (const float4*)als;
  float4 ad = ((const float4*)ald)[n];
  const unsigned char* hb = h1f8 + cl * 8;

  float ds = 0.f;
  float num0 = 0, num1 = 0, num2 = 0, num3 = 0, num4 = 0, num5 = 0, num6 = 0, num7 = 0;

  for (int cbase = 0; cbase < deg; cbase += 32) {
    int j0 = cbase + lh;
    float w0 = 0.f, w1 = 0.f, w2 = 0.f, w3 = 0.f;
    int sb = 0;
    if (j0 < deg) {
      int s = srcs[off0 + j0];
      sb = s << 7;
      float4 a = als4[s];
      w0 = __expf(lrelu(a.x + ad.x)); w1 = __expf(lrelu(a.y + ad.y));
      w2 = __expf(lrelu(a.z + ad.z)); w3 = __expf(lrelu(a.w + ad.w));
    }
    int pw01 = (int)f2b2(w0, w1), pw23 = (int)f2b2(w2, w3);
    int cn = (deg - cbase) < 32 ? (deg - cbase) : 32;
    for (int jj = 0; jj < cn; jj += 4) {
      int jA = jj + sg, jB = jj + 2 + sg;          // jB <= 31 always
      int boA = __shfl(sb, lbase + jA), boB = __shfl(sb, lbase + jB);
      uint2 vA = *(const uint2*)(hb + boA);         // both loads issued before
      uint2 vB = *(const uint2*)(hb + boB);         // either result is consumed
      unsigned int uA01 = (unsigned int)__shfl(pw01, lbase + jA);
      unsigned int uA23 = (unsigned int)__shfl(pw23, lbase + jA);
      unsigned int uB01 = (unsigned int)__shfl(pw01, lbase + jB);
      unsigned int uB23 = (unsigned int)__shfl(pw23, lbase + jB);
      unsigned int upA = head < 2 ? uA01 : uA23;
      unsigned int upB = head < 2 ? uB01 : uB23;
      float wA = (head & 1) ? bhi(upA) : blo(upA);
      float wB = (head & 1) ? bhi(upB) : blo(upB);
      ds += wA + wB;                                // fused denominator
      f32x2 p0 = f8x2lo(vA.x), p1 = f8x2hi(vA.x);
      f32x2 p2 = f8x2lo(vA.y), p3 = f8x2hi(vA.y);
      num0 = fmaf(wA, p0.x, num0); num1 = fmaf(wA, p0.y, num1);
      num2 = fmaf(wA, p1.x, num2); num3 = fmaf(wA, p1.y, num3);
      num4 = fmaf(wA, p2.x, num4); num5 = fmaf(wA, p2.y, num5);
      num6 = fmaf(wA, p3.x, num6); num7 = fmaf(wA, p3.y, num7);
      p0 = f8x2lo(vB.x); p1 = f8x2hi(vB.x);
      p2 = f8x2lo(vB.y); p3 = f8x2hi(vB.y);
      num0 = fmaf(wB, p0.x, num0); num1 = fmaf(wB, p0.y, num1);
      num2 = fmaf(wB, p1.x, num2); num3 = fmaf(wB, p1.y, num3);
      num4 = fmaf(wB, p2.x, num4); num5 = fmaf(wB, p2.y, num5);
      num6 = fmaf(wB, p3.x, num6); num7 = fmaf(wB, p3.y, num7);
    }
  }
  // combine the 2 edge-subgroups within the half (never crosses the 32-lane boundary)
  num0 += __shfl_xor(num0, 16); num1 += __shfl_xor(num1, 16);
  num2 += __shfl_xor(num2, 16); num3 += __shfl_xor(num3, 16);
  num4 += __shfl_xor(num4, 16); num5 += __shfl_xor(num5, 16);
  num6 += __shfl_xor(num6, 16); num7 += __shfl_xor(num7, 16);
  ds += __shfl_xor(ds, 16);
  if (lh < 16) {
    float rd = 1.f / ds;
    int c8 = cl * 8;
    float4 bb0 = *(const float4*)&b1[c8];
    float4 bb1 = *(const float4*)&b1[c8 + 4];
    float o0 = fmaxf(num0 * rd + bb0.x, 0.f);
    float o1 = fmaxf(num1 * rd + bb0.y, 0.f);
    float o2 = fmaxf(num2 * rd + bb0.z, 0.f);
    float o3 = fmaxf(num3 * rd + bb0.w, 0.f);
    float o4 = fmaxf(num4 * rd + bb1.x, 0.f);
    float o5 = fmaxf(num5 * rd + bb1.y, 0.f);
    float o6 = fmaxf(num6 * rd + bb1.z, 0.f);
    float o7 = fmaxf(num7 * rd + bb1.w, 0.f);
    uint4 pk;
    pk.x = f2b2(o0, o1); pk.y = f2b2(o2, o3);
    pk.z = f2b2(o4, o5); pk.w = f2b2(o6, o7);
    *(uint4*)&out1b[(size_t)n * HID + c8] = pk;
  }
}

// ---------- layer-2 aggregate + log_softmax: TWO nodes per wave;
// 4 subgroups/half (8 lanes x 8B = full 64B row), 8 edges/iter.
__global__ __launch_bounds__(256) void k_agg2(const unsigned char* __restrict__ h2f8,
                                              const float* __restrict__ als,
                                              const float* __restrict__ ald, const int* __restrict__ offs,
                                              const int* __restrict__ srcs, const float* __restrict__ b2,
                                              float* __restrict__ out) {
  int t = threadIdx.x;
  int w = t >> 6, l = t & 63;
  int hw = l >> 5, lh = l & 31;
  int sg = lh >> 3, cl = lh & 7;
  int lbase = hw << 5;
  int n = blockIdx.x * 8 + w * 2 + hw;
  int off0 = offs[n], deg = offs[n + 1] - off0;
  float adv = ald[n];
  const unsigned char* hb = h2f8 + cl * 8;

  float ds = 0.f;
  float num0 = 0, num1 = 0, num2 = 0, num3 = 0, num4 = 0, num5 = 0, num6 = 0, num7 = 0;

  for (int cbase = 0; cbase < deg; cbase += 32) {
    int j0 = cbase + lh;
    float wv = 0.f;
    int sb = 0;
    if (j0 < deg) {
      int s = srcs[off0 + j0];
      sb = s << 6;
      wv = __expf(lrelu(als[s] + adv));
    }
    int cn = (deg - cbase) < 32 ? (deg - cbase) : 32;
    for (int jj = 0; jj < cn; jj += 8) {
      int jA = jj + sg, jB = jj + 4 + sg;          // jB <= 31 always
      int boA = __shfl(sb, lbase + jA), boB = __shfl(sb, lbase + jB);
      uint2 vA = *(const uint2*)(hb + boA);
      uint2 vB = *(const uint2*)(hb + boB);
      float wA = __shfl(wv, lbase + jA), wB = __shfl(wv, lbase + jB);
      ds += wA + wB;
      f32x2 p0 = f8x2lo(vA.x), p1 = f8x2hi(vA.x);
      f32x2 p2 = f8x2lo(vA.y), p3 = f8x2hi(vA.y);
      num0 = fmaf(wA, p0.x, num0); num1 = fmaf(wA, p0.y, num1);
      num2 = fmaf(wA, p1.x, num2); num3 = fmaf(wA, p1.y, num3);
      num4 = fmaf(wA, p2.x, num4); num5 = fmaf(wA, p2.y, num5);
      num6 = fmaf(wA, p3.x, num6); num7 = fmaf(wA, p3.y, num7);
      p0 = f8x2lo(vB.x); p1 = f8x2hi(vB.x);
      p2 = f8x2lo(vB.y); p3 = f8x2hi(vB.y);
      num0 = fmaf(wB, p0.x, num0); num1 = fmaf(wB, p0.y, num1);
      num2 = fmaf(wB, p1.x, num2); num3 = fmaf(wB, p1.y, num3);
      num4 = fmaf(wB, p2.x, num4); num5 = fmaf(wB, p2.y, num5);
      num6 = fmaf(wB, p3.x, num6); num7 = fmaf(wB, p3.y, num7);
    }
  }
  // combine the 4 subgroups within the half (offsets 8,16 stay inside 32 lanes)
  #pragma unroll
  for (int o = 8; o <= 16; o <<= 1) {
    num0 += __shfl_xor(num0, o); num1 += __shfl_xor(num1, o);
    num2 += __shfl_xor(num2, o); num3 += __shfl_xor(num3, o);
    num4 += __shfl_xor(num4, o); num5 += __shfl_xor(num5, o);
    num6 += __shfl_xor(num6, o); num7 += __shfl_xor(num7, o);
    ds += __shfl_xor(ds, o);
  }
  if (lh < 8) {
    float rd = 1.f / ds;
    int c8 = cl * 8;
    float4 bb0 = *(const float4*)&b2[c8];
    float4 bb1 = *(const float4*)&b2[c8 + 4];
    float v0 = num0 * rd + bb0.x, v1 = num1 * rd + bb0.y;
    float v2 = num2 * rd + bb0.z, v3 = num3 * rd + bb0.w;
    float v4 = num4 * rd + bb1.x, v5 = num5 * rd + bb1.y;
    float v6 = num6 * rd + bb1.z, v7 = num7 * rd + bb1.w;
    // log_softmax over 64 outputs held by 8 lanes x 8 regs (xor 1,2,4 stays in the 8-lane group)
    float mx = fmaxf(fmaxf(fmaxf(v0, v1), fmaxf(v2, v3)), fmaxf(fmaxf(v4, v5), fmaxf(v6, v7)));
    #pragma unroll
    for (int o = 1; o <= 4; o <<= 1) mx = fmaxf(mx, __shfl_xor(mx, o));
    float sum = __expf(v0 - mx) + __expf(v1 - mx) + __expf(v2 - mx) + __expf(v3 - mx)
              + __expf(v4 - mx) + __expf(v5 - mx) + __expf(v6 - mx) + __expf(v7 - mx);
    #pragma unroll
    for (int o = 1; o <= 4; o <<= 1) sum += __shfl_xor(sum, o);
    float ls = __logf(sum);
    float4 r0, r1;
    r0.x = (v0 - mx) - ls; r0.y = (v1 - mx) - ls; r0.z = (v2 - mx) - ls; r0.w = (v3 - mx) - ls;
    r1.x = (v4 - mx) - ls; r1.y = (v5 - mx) - ls; r1.z = (v6 - mx) - ls; r1.w = (v7 - mx) - ls;
    *(float4*)&out[(size_t)n * ODIM + c8] = r0;
    *(float4*)&out[(size_t)n * ODIM + c8 + 4] = r1;
  }
}

extern "C" void kernel_launch(void* const* d_in, const int* in_sizes, int n_in,
                              void* d_out, int out_size, void* d_ws, size_t ws_size,
                              hipStream_t stream) {
  const float* x   = (const float*)d_in[0];
  const void*  ei  = d_in[1];
  const float* W1  = (const float*)d_in[2];
  const float* as1 = (const float*)d_in[3];
  const float* ad1 = (const float*)d_in[4];
  const float* b1  = (const float*)d_in[5];
  const float* W2  = (const float*)d_in[6];
  const float* as2 = (const float*)d_in[7];
  const float* ad2 = (const float*)d_in[8];
  const float* b2  = (const float*)d_in[9];
  float* out = (float*)d_out;

  char* ws = (char*)d_ws;
  size_t o = 0;
  auto alloc = [&](size_t bytes) { void* p = (void*)(ws + o); o += (bytes + 255) & ~(size_t)255; return p; };
  ushort_t* h1b   = (ushort_t*)alloc((size_t)N_NODES * HID * 2);
  ushort_t* out1b = (ushort_t*)alloc((size_t)N_NODES * HID * 2);
  ushort_t* h2b   = (ushort_t*)alloc((size_t)N_NODES * ODIM * 2);
  unsigned char* h1f8 = (unsigned char*)alloc((size_t)N_NODES * HID);
  ushort_t* Wt1   = (ushort_t*)alloc((size_t)128 * 128 * 2);
  ushort_t* Wt2   = (ushort_t*)alloc((size_t)64 * 128 * 2);
  float* als1 = (float*)alloc((size_t)N_NODES * 4 * 4);
  float* ald1 = (float*)alloc((size_t)N_NODES * 4 * 4);
  float* als2 = (float*)alloc((size_t)N_NODES * 4);
  float* ald2 = (float*)alloc((size_t)N_NODES * 4);
  int*   degr = (int*)alloc((size_t)NREP * N_NODES * 4);
  int*   repbase = (int*)alloc((size_t)NREP * N_NODES * 4);
  int*   offs = (int*)alloc((size_t)(N_NODES + 1) * 4);
  int*   rank = (int*)alloc((size_t)E_TOT * 4);
  int*   srcs = (int*)alloc((size_t)E_TOT * 4);
  int*   bsums= (int*)alloc((size_t)NB1 * 4);
  int*   flag = (int*)alloc(4);
  // h2f8 (3.2 MB) aliases rank (3.4 MB): rank is dead after k_scatter
  unsigned char* h2f8 = (unsigned char*)rank;

  hipMemsetAsync(degr, 0, (size_t)NREP * N_NODES * 4, stream);
  k_prep   <<<65,    256, 0, stream>>>(W1, W2, Wt1, Wt2, ei, flag);

  int egrid = (E_TOT + 255) / 256;
  k_hist   <<<egrid, 256, 0, stream>>>(ei, flag, degr, rank);
  k_scan1  <<<NB1,   256, 0, stream>>>(degr, offs, bsums);
  k_scan2  <<<1,     256, 0, stream>>>(bsums);
  k_scan3  <<<NB1,   256, 0, stream>>>(offs, bsums, degr, repbase);
  k_scatter<<<egrid, 256, 0, stream>>>(ei, flag, repbase, rank, srcs);

  k_mm1  <<<512, 256, 0, stream>>>(x, Wt1, h1b, h1f8);
  k_al1  <<<N_NODES / 16, 256, 0, stream>>>(h1b, as1, ad1, als1, ald1);
  k_agg1 <<<N_NODES / 8, 256, 0, stream>>>(h1f8, als1, ald1, offs, srcs, b1, out1b);

  k_mm2  <<<512, 256, 0, stream>>>(out1b, Wt2, h2b, h2f8);
  k_al2  <<<(N_NODES + 31) / 32, 256, 0, stream>>>(h2b, as2, ad2, als2, ald2);
  k_agg2 <<<N_NODES / 8, 256, 0, stream>>>(h2f8, als2, ald2, offs, srcs, b2, out);
}

// Round 11
// 133.344 us; speedup vs baseline: 1.5207x; 1.0074x over previous
//
#include <hip/hip_runtime.h>
#include <hip/hip_bf16.h>
#include <math.h>

#define N_NODES 50000
#define N_EDGES 800000
#define E_TOT   (N_EDGES + N_NODES)
#define IN_DIM  128
#define HID     128      // HEADS*HIDDEN (layer-1 output width)
#define ODIM    64
#define NEG     0.2f
#define NB1     ((N_NODES + 255) / 256)   // scan blocks = 196
#define NCHUNK  ((N_NODES + 31) / 32)     // 32-node chunks for MFMA GEMMs
#define NREP    8

typedef short bf16x8 __attribute__((ext_vector_type(8)));
typedef float f32x4 __attribute__((ext_vector_type(4)));
typedef float f32x2 __attribute__((ext_vector_type(2)));
typedef unsigned short ushort_t;

__device__ __forceinline__ float lrelu(float x) { return x >= 0.f ? x : NEG * x; }

// bf16 <-> f32 helpers (RNE rounding on store)
__device__ __forceinline__ unsigned short f2b(float v) {
  unsigned int b = __float_as_uint(v);
  b += 0x7fffu + ((b >> 16) & 1u);
  return (unsigned short)(b >> 16);
}
__device__ __forceinline__ float b2f(unsigned short u) {
  return __uint_as_float(((unsigned int)u) << 16);
}
__device__ __forceinline__ unsigned int f2b2(float lo, float hi) {
  union { __hip_bfloat162 h; unsigned int u; } cv;
  cv.h = __float22bfloat162_rn(make_float2(lo, hi));
  return cv.u;
}
// unpack packed 2xbf16 word
__device__ __forceinline__ float blo(unsigned int v) { return __uint_as_float(v << 16); }
__device__ __forceinline__ float bhi(unsigned int v) { return __uint_as_float(v & 0xffff0000u); }

// fp8 e4m3 (OCP) hardware converts
__device__ __forceinline__ f32x2 f8x2lo(unsigned int v) {
  return __builtin_amdgcn_cvt_pk_f32_fp8((int)v, false);
}
__device__ __forceinline__ f32x2 f8x2hi(unsigned int v) {
  return __builtin_amdgcn_cvt_pk_f32_fp8((int)v, true);
}
__device__ __forceinline__ unsigned char f2f8(float v) {
  return (unsigned char)(__builtin_amdgcn_cvt_pk_fp8_f32(v, v, 0, false) & 0xff);
}

__device__ __forceinline__ int e_src(const void* ei, int f, int e) {
  if (e >= N_EDGES) return e - N_EDGES;              // self loop
  return f ? (int)((const long long*)ei)[e] : ((const int*)ei)[e];
}
__device__ __forceinline__ int e_dst(const void* ei, int f, int e) {
  if (e >= N_EDGES) return e - N_EDGES;              // self loop
  return f ? (int)((const long long*)ei)[N_EDGES + e] : ((const int*)ei)[N_EDGES + e];
}

// ---------- weight prep (bf16 W^T) + dtype detect + degr zero (fused memset) ----------
__global__ void k_prep(const float* __restrict__ W1, const float* __restrict__ W2,
                       ushort_t* __restrict__ Wt1, ushort_t* __restrict__ Wt2,
                       const void* ei, int* flag, int4* __restrict__ degr4) {
  if (blockIdx.x == 64) {
    if (threadIdx.x == 0) {
      const int* p = (const int*)ei;
      int allz = 1;
      for (int i = 0; i < 64; ++i) if (p[2 * i + 1] != 0) { allz = 0; break; }
      *flag = allz;  // 1 => buffer is int64
    }
    return;
  }
  if (blockIdx.x > 64) {   // zero degr: NREP*N_NODES ints = 100000 int4
    int i = (blockIdx.x - 65) * 256 + threadIdx.x;
    if (i < NREP * N_NODES / 4) degr4[i] = make_int4(0, 0, 0, 0);
    return;
  }
  int i = blockIdx.x * 256 + threadIdx.x;
  if (i < 128 * 128) { int k = i >> 7, n = i & 127; Wt1[n * 128 + k] = f2b(W1[i]); }
  if (i < 128 * 64)  { int k = i >> 6, n = i & 63;  Wt2[n * 128 + k] = f2b(W2[i]); }
}

// ---------- CSR build: 8-way replicated histogram (cuts atomic line-bounce) ----------
__global__ void k_hist(const void* ei, const int* flag, int* degr, int* rank) {
  int e = blockIdx.x * 256 + threadIdx.x;
  if (e >= E_TOT) return;
  int r = blockIdx.x & (NREP - 1);
  int d = e_dst(ei, *flag, e);
  rank[e] = atomicAdd(&degr[r * N_NODES + d], 1);
}

__global__ void k_scan1(const int* __restrict__ degr, int* __restrict__ offs, int* __restrict__ bsums) {
  __shared__ int sm[256];
  int t = threadIdx.x, i = blockIdx.x * 256 + t;
  int v = 0;
  if (i < N_NODES) {
    #pragma unroll
    for (int r = 0; r < NREP; ++r) v += degr[r * N_NODES + i];
  }
  sm[t] = v;
  __syncthreads();
  for (int o = 1; o < 256; o <<= 1) {
    int add = (t >= o) ? sm[t - o] : 0;
    __syncthreads();
    sm[t] += add;
    __syncthreads();
  }
  if (i < N_NODES) offs[i] = sm[t] - v;   // exclusive (block-local)
  if (t == 255) bsums[blockIdx.x] = sm[255];
}

// finalize offs (recomputes bsums prefix in-block; no separate scan2) + per-replica bases
__global__ void k_scan3(int* __restrict__ offs, const int* __restrict__ bsums,
                        const int* __restrict__ degr, int* __restrict__ repbase) {
  __shared__ int red[4];
  int t = threadIdx.x;
  int v = (t < blockIdx.x) ? bsums[t] : 0;          // NB1 = 196 <= 256 threads
  #pragma unroll
  for (int o = 32; o >= 1; o >>= 1) v += __shfl_xor(v, o);
  if ((t & 63) == 0) red[t >> 6] = v;
  __syncthreads();
  int pre = red[0] + red[1] + red[2] + red[3];
  int i = blockIdx.x * 256 + t;
  if (i < N_NODES) {
    int o = offs[i] + pre;
    offs[i] = o;
    int run = o;
    #pragma unroll
    for (int r = 0; r < NREP; ++r) {
      repbase[r * N_NODES + i] = run;
      run += degr[r * N_NODES + i];
    }
  }
  if (i == 0) offs[N_NODES] = E_TOT;
}

__global__ void k_scatter(const void* ei, const int* __restrict__ flag,
                          const int* __restrict__ repbase,
                          const int* __restrict__ rank, int* __restrict__ srcs) {
  int e = blockIdx.x * 256 + threadIdx.x;
  if (e >= E_TOT) return;
  int f = *flag;
  int d = e_dst(ei, f, e);
  int r = blockIdx.x & (NREP - 1);
  srcs[repbase[r * N_NODES + d] + rank[e]] = e_src(ei, f, e);
}

// ---------- MFMA GEMM1: h1b(bf16) + h1f8(fp8) = bf16(x) @ W1 ----------
__global__ __launch_bounds__(256) void k_mm1(const float* __restrict__ x,
                                             const ushort_t* __restrict__ Wt,
                                             ushort_t* __restrict__ h1b,
                                             unsigned char* __restrict__ h1f8) {
  __shared__ ushort_t xs[32 * 128];   // 8 KB
  int t = threadIdx.x;
  int w = t >> 6, l = t & 63;
  int lr = l & 15, lk = l >> 4;
  int nodeSub = (w & 1) * 16, colBase = (w >> 1) * 64;
  bf16x8 bfrag[4][4];
  #pragma unroll
  for (int ct = 0; ct < 4; ++ct)
    #pragma unroll
    for (int ks = 0; ks < 4; ++ks) {
      int n = colBase + ct * 16 + lr;
      int k = ks * 32 + lk * 8;
      bfrag[ct][ks] = *(const bf16x8*)&Wt[n * 128 + k];
    }
  int rr = t >> 3, c0 = (t & 7) * 16;   // staging: row, 16-elem col group
  for (int chunk = blockIdx.x; chunk < NCHUNK; chunk += gridDim.x) {
    int base = chunk * 32;
    int srcRow = base + rr; if (srcRow >= N_NODES) srcRow = N_NODES - 1;
    const float4* xr = (const float4*)&x[(size_t)srcRow * IN_DIM + c0];
    float4 f0 = xr[0], f1 = xr[1], f2 = xr[2], f3 = xr[3];
    uint4 w0, w1;
    w0.x = f2b2(f0.x, f0.y); w0.y = f2b2(f0.z, f0.w);
    w0.z = f2b2(f1.x, f1.y); w0.w = f2b2(f1.z, f1.w);
    w1.x = f2b2(f2.x, f2.y); w1.y = f2b2(f2.z, f2.w);
    w1.z = f2b2(f3.x, f3.y); w1.w = f2b2(f3.z, f3.w);
    char* xsb = (char*)xs;
    int swz = (rr & 7) << 4;
    *(uint4*)(xsb + rr * 256 + ((c0 * 2 +  0) ^ swz)) = w0;
    *(uint4*)(xsb + rr * 256 + ((c0 * 2 + 16) ^ swz)) = w1;
    __syncthreads();
    f32x4 acc[4] = {{0,0,0,0},{0,0,0,0},{0,0,0,0},{0,0,0,0}};
    int arow = nodeSub + lr;
    #pragma unroll
    for (int ks = 0; ks < 4; ++ks) {
      bf16x8 a = *(const bf16x8*)((const char*)xs + arow * 256 +
                                  ((ks * 64 + lk * 16) ^ ((arow & 7) << 4)));
      #pragma unroll
      for (int ct = 0; ct < 4; ++ct)
        acc[ct] = __builtin_amdgcn_mfma_f32_16x16x32_bf16(a, bfrag[ct][ks], acc[ct], 0, 0, 0);
    }
    __syncthreads();
    #pragma unroll
    for (int ct = 0; ct < 4; ++ct)
      #pragma unroll
      for (int r = 0; r < 4; ++r) {
        int node = base + nodeSub + lk * 4 + r;
        if (node < N_NODES) {
          float v = acc[ct][r];
          int col = colBase + ct * 16 + lr;
          h1b[(size_t)node * HID + col] = f2b(v);
          h1f8[(size_t)node * HID + col] = f2f8(v);
        }
      }
  }
}

// ---------- MFMA GEMM2: h2b(bf16) + h2f8(fp8) = out1b @ W2 ----------
__global__ __launch_bounds__(256) void k_mm2(const ushort_t* __restrict__ xb,
                                             const ushort_t* __restrict__ Wt,
                                             ushort_t* __restrict__ h2b,
                                             unsigned char* __restrict__ h2f8) {
  __shared__ ushort_t xs[32 * 128];   // 8 KB
  int t = threadIdx.x;
  int w = t >> 6, l = t & 63;
  int lr = l & 15, lk = l >> 4;
  int nodeSub = (w & 1) * 16, colBase = (w >> 1) * 32;
  bf16x8 bfrag[2][4];
  #pragma unroll
  for (int ct = 0; ct < 2; ++ct)
    #pragma unroll
    for (int ks = 0; ks < 4; ++ks) {
      int n = colBase + ct * 16 + lr;
      int k = ks * 32 + lk * 8;
      bfrag[ct][ks] = *(const bf16x8*)&Wt[n * 128 + k];
    }
  int rr = t >> 3, c0 = (t & 7) * 16;
  for (int chunk = blockIdx.x; chunk < NCHUNK; chunk += gridDim.x) {
    int base = chunk * 32;
    int srcRow = base + rr; if (srcRow >= N_NODES) srcRow = N_NODES - 1;
    const uint4* xr = (const uint4*)&xb[(size_t)srcRow * HID + c0];
    uint4 w0 = xr[0], w1 = xr[1];
    char* xsb = (char*)xs;
    int swz = (rr & 7) << 4;
    *(uint4*)(xsb + rr * 256 + ((c0 * 2 +  0) ^ swz)) = w0;
    *(uint4*)(xsb + rr * 256 + ((c0 * 2 + 16) ^ swz)) = w1;
    __syncthreads();
    f32x4 acc[2] = {{0,0,0,0},{0,0,0,0}};
    int arow = nodeSub + lr;
    #pragma unroll
    for (int ks = 0; ks < 4; ++ks) {
      bf16x8 a = *(const bf16x8*)((const char*)xs + arow * 256 +
                                  ((ks * 64 + lk * 16) ^ ((arow & 7) << 4)));
      #pragma unroll
      for (int ct = 0; ct < 2; ++ct)
        acc[ct] = __builtin_amdgcn_mfma_f32_16x16x32_bf16(a, bfrag[ct][ks], acc[ct], 0, 0, 0);
    }
    __syncthreads();
    #pragma unroll
    for (int ct = 0; ct < 2; ++ct)
      #pragma unroll
      for (int r = 0; r < 4; ++r) {
        int node = base + nodeSub + lk * 4 + r;
        if (node < N_NODES) {
          float v = acc[ct][r];
          int col = colBase + ct * 16 + lr;
          h2b[(size_t)node * ODIM + col] = f2b(v);
          h2f8[(size_t)node * ODIM + col] = f2f8(v);
        }
      }
  }
}

// ---------- attention logits: 16B loads, 8 cols/lane ----------
__global__ __launch_bounds__(256) void k_al1(const ushort_t* __restrict__ h1b,
                                             const float* __restrict__ asrc,
                                             const float* __restrict__ adst, float* __restrict__ als,
                                             float* __restrict__ ald) {
  int t = threadIdx.x;
  int n = blockIdx.x * 16 + (t >> 4);
  int c8 = (t & 15) * 8;
  uint4 v = *(const uint4*)&h1b[(size_t)n * HID + c8];
  float4 a0 = *(const float4*)&asrc[c8], a1 = *(const float4*)&asrc[c8 + 4];
  float4 d0 = *(const float4*)&adst[c8], d1 = *(const float4*)&adst[c8 + 4];
  float f0 = blo(v.x), f1 = bhi(v.x), f2 = blo(v.y), f3 = bhi(v.y);
  float f4 = blo(v.z), f5 = bhi(v.z), f6 = blo(v.w), f7 = bhi(v.w);
  float s = f0*a0.x + f1*a0.y + f2*a0.z + f3*a0.w + f4*a1.x + f5*a1.y + f6*a1.z + f7*a1.w;
  float d = f0*d0.x + f1*d0.y + f2*d0.z + f3*d0.w + f4*d1.x + f5*d1.y + f6*d1.z + f7*d1.w;
  s += __shfl_xor(s, 1); s += __shfl_xor(s, 2);
  d += __shfl_xor(d, 1); d += __shfl_xor(d, 2);
  if ((t & 3) == 0) {
    int head = (t & 15) >> 2;
    als[n * 4 + head] = s;
    ald[n * 4 + head] = d;
  }
}

__global__ __launch_bounds__(256) void k_al2(const ushort_t* __restrict__ h2b,
                                             const float* __restrict__ asrc,
                                             const float* __restrict__ adst, float* __restrict__ als,
                                             float* __restrict__ ald) {
  int t = threadIdx.x;
  int n = blockIdx.x * 32 + (t >> 3);
  if (n >= N_NODES) return;
  int c8 = (t & 7) * 8;
  uint4 v = *(const uint4*)&h2b[(size_t)n * ODIM + c8];
  float4 a0 = *(const float4*)&asrc[c8], a1 = *(const float4*)&asrc[c8 + 4];
  float4 d0 = *(const float4*)&adst[c8], d1 = *(const float4*)&adst[c8 + 4];
  float f0 = blo(v.x), f1 = bhi(v.x), f2 = blo(v.y), f3 = bhi(v.y);
  float f4 = blo(v.z), f5 = bhi(v.z), f6 = blo(v.w), f7 = bhi(v.w);
  float s = f0*a0.x + f1*a0.y + f2*a0.z + f3*a0.w + f4*a1.x + f5*a1.y + f6*a1.z + f7*a1.w;
  float d = f0*d0.x + f1*d0.y + f2*d0.z + f3*d0.w + f4*d1.x + f5*d1.y + f6*d1.z + f7*d1.w;
  s += __shfl_xor(s, 1); s += __shfl_xor(s, 2); s += __shfl_xor(s, 4);
  d += __shfl_xor(d, 1); d += __shfl_xor(d, 2); d += __shfl_xor(d, 4);
  if ((t & 7) == 0) { als[n] = s; ald[n] = d; }
}

// ---------- layer-1 aggregate: TWO nodes per wave; SUBGROUP-UNIFORM loads (no bpermute);
// each 16-lane subgroup loads its edge's src/als itself, computes its head's weight in-lane.
__global__ __launch_bounds__(256) void k_agg1(const unsigned char* __restrict__ h1f8,
                                              const float* __restrict__ als,
                                              const float* __restrict__ ald, const int* __restrict__ offs,
                                              const int* __restrict__ srcs, const float* __restrict__ b1,
                                              ushort_t* __restrict__ out1b) {
  int t = threadIdx.x;
  int w = t >> 6, l = t & 63;
  int hw = l >> 5, lh = l & 31;          // half index, lane-in-half
  int sg = lh >> 4, cl = lh & 15, head = cl >> 2;
  int n = blockIdx.x * 8 + w * 2 + hw;   // grid = N/8 = 6250 exact
  int off0 = offs[n], deg = offs[n + 1] - off0;
  float adh = ald[n * 4 + head];
  const unsigned char* hb = h1f8 + cl * 8;

  float ds = 0.f;
  float num0 = 0, num1 = 0, num2 = 0, num3 = 0, num4 = 0, num5 = 0, num6 = 0, num7 = 0;

  // subgroup sg handles edges j ≡ sg (mod 2); unroll 2 (j, j+2)
  int j = sg;
  for (; j + 2 < deg; j += 4) {
    int sA = srcs[off0 + j];
    int sB = srcs[off0 + j + 2];
    float aA = als[sA * 4 + head];
    float aB = als[sB * 4 + head];
    uint2 vA = *(const uint2*)(hb + (sA << 7));
    uint2 vB = *(const uint2*)(hb + (sB << 7));
    float wA = __expf(lrelu(aA + adh));
    float wB = __expf(lrelu(aB + adh));
    ds += wA + wB;
    f32x2 p0 = f8x2lo(vA.x), p1 = f8x2hi(vA.x);
    f32x2 p2 = f8x2lo(vA.y), p3 = f8x2hi(vA.y);
    num0 = fmaf(wA, p0.x, num0); num1 = fmaf(wA, p0.y, num1);
    num2 = fmaf(wA, p1.x, num2); num3 = fmaf(wA, p1.y, num3);
    num4 = fmaf(wA, p2.x, num4); num5 = fmaf(wA, p2.y, num5);
    num6 = fmaf(wA, p3.x, num6); num7 = fmaf(wA, p3.y, num7);
    p0 = f8x2lo(vB.x); p1 = f8x2hi(vB.x);
    p2 = f8x2lo(vB.y); p3 = f8x2hi(vB.y);
    num0 = fmaf(wB, p0.x, num0); num1 = fmaf(wB, p0.y, num1);
    num2 = fmaf(wB, p1.x, num2); num3 = fmaf(wB, p1.y, num3);
    num4 = fmaf(wB, p2.x, num4); num5 = fmaf(wB, p2.y, num5);
    num6 = fmaf(wB, p3.x, num6); num7 = fmaf(wB, p3.y, num7);
  }
  if (j < deg) {
    int sA = srcs[off0 + j];
    float aA = als[sA * 4 + head];
    uint2 vA = *(const uint2*)(hb + (sA << 7));
    float wA = __expf(lrelu(aA + adh));
    ds += wA;
    f32x2 p0 = f8x2lo(vA.x), p1 = f8x2hi(vA.x);
    f32x2 p2 = f8x2lo(vA.y), p3 = f8x2hi(vA.y);
    num0 = fmaf(wA, p0.x, num0); num1 = fmaf(wA, p0.y, num1);
    num2 = fmaf(wA, p1.x, num2); num3 = fmaf(wA, p1.y, num3);
    num4 = fmaf(wA, p2.x, num4); num5 = fmaf(wA, p2.y, num5);
    num6 = fmaf(wA, p3.x, num6); num7 = fmaf(wA, p3.y, num7);
  }
  // combine the 2 subgroups within the half (never crosses the 32-lane boundary)
  num0 += __shfl_xor(num0, 16); num1 += __shfl_xor(num1, 16);
  num2 += __shfl_xor(num2, 16); num3 += __shfl_xor(num3, 16);
  num4 += __shfl_xor(num4, 16); num5 += __shfl_xor(num5, 16);
  num6 += __shfl_xor(num6, 16); num7 += __shfl_xor(num7, 16);
  ds += __shfl_xor(ds, 16);
  if (lh < 16) {
    float rd = 1.f / ds;
    int c8 = cl * 8;
    float4 bb0 = *(const float4*)&b1[c8];
    float4 bb1 = *(const float4*)&b1[c8 + 4];
    float o0 = fmaxf(num0 * rd + bb0.x, 0.f);
    float o1 = fmaxf(num1 * rd + bb0.y, 0.f);
    float o2 = fmaxf(num2 * rd + bb0.z, 0.f);
    float o3 = fmaxf(num3 * rd + bb0.w, 0.f);
    float o4 = fmaxf(num4 * rd + bb1.x, 0.f);
    float o5 = fmaxf(num5 * rd + bb1.y, 0.f);
    float o6 = fmaxf(num6 * rd + bb1.z, 0.f);
    float o7 = fmaxf(num7 * rd + bb1.w, 0.f);
    uint4 pk;
    pk.x = f2b2(o0, o1); pk.y = f2b2(o2, o3);
    pk.z = f2b2(o4, o5); pk.w = f2b2(o6, o7);
    *(uint4*)&out1b[(size_t)n * HID + c8] = pk;
  }
}

// ---------- layer-2 aggregate + log_softmax: TWO nodes per wave; subgroup-uniform loads;
// 4 subgroups/half (8 lanes x 8B = full 64B row), edges j ≡ sg (mod 4), unroll 2.
__global__ __launch_bounds__(256) void k_agg2(const unsigned char* __restrict__ h2f8,
                                              const float* __restrict__ als,
                                              const float* __restrict__ ald, const int* __restrict__ offs,
                                              const int* __restrict__ srcs, const float* __restrict__ b2,
                                              float* __restrict__ out) {
  int t = threadIdx.x;
  int w = t >> 6, l = t & 63;
  int hw = l >> 5, lh = l & 31;
  int sg = lh >> 3, cl = lh & 7;
  int n = blockIdx.x * 8 + w * 2 + hw;
  int off0 = offs[n], deg = offs[n + 1] - off0;
  float adv = ald[n];
  const unsigned char* hb = h2f8 + cl * 8;

  float ds = 0.f;
  float num0 = 0, num1 = 0, num2 = 0, num3 = 0, num4 = 0, num5 = 0, num6 = 0, num7 = 0;

  int j = sg;
  for (; j + 4 < deg; j += 8) {
    int sA = srcs[off0 + j];
    int sB = srcs[off0 + j + 4];
    float aA = als[sA];
    float aB = als[sB];
    uint2 vA = *(const uint2*)(hb + (sA << 6));
    uint2 vB = *(const uint2*)(hb + (sB << 6));
    float wA = __expf(lrelu(aA + adv));
    float wB = __expf(lrelu(aB + adv));
    ds += wA + wB;
    f32x2 p0 = f8x2lo(vA.x), p1 = f8x2hi(vA.x);
    f32x2 p2 = f8x2lo(vA.y), p3 = f8x2hi(vA.y);
    num0 = fmaf(wA, p0.x, num0); num1 = fmaf(wA, p0.y, num1);
    num2 = fmaf(wA, p1.x, num2); num3 = fmaf(wA, p1.y, num3);
    num4 = fmaf(wA, p2.x, num4); num5 = fmaf(wA, p2.y, num5);
    num6 = fmaf(wA, p3.x, num6); num7 = fmaf(wA, p3.y, num7);
    p0 = f8x2lo(vB.x); p1 = f8x2hi(vB.x);
    p2 = f8x2lo(vB.y); p3 = f8x2hi(vB.y);
    num0 = fmaf(wB, p0.x, num0); num1 = fmaf(wB, p0.y, num1);
    num2 = fmaf(wB, p1.x, num2); num3 = fmaf(wB, p1.y, num3);
    num4 = fmaf(wB, p2.x, num4); num5 = fmaf(wB, p2.y, num5);
    num6 = fmaf(wB, p3.x, num6); num7 = fmaf(wB, p3.y, num7);
  }
  if (j < deg) {
    int sA = srcs[off0 + j];
    float aA = als[sA];
    uint2 vA = *(const uint2*)(hb + (sA << 6));
    float wA = __expf(lrelu(aA + adv));
    ds += wA;
    f32x2 p0 = f8x2lo(vA.x), p1 = f8x2hi(vA.x);
    f32x2 p2 = f8x2lo(vA.y), p3 = f8x2hi(vA.y);
    num0 = fmaf(wA, p0.x, num0); num1 = fmaf(wA, p0.y, num1);
    num2 = fmaf(wA, p1.x, num2); num3 = fmaf(wA, p1.y, num3);
    num4 = fmaf(wA, p2.x, num4); num5 = fmaf(wA, p2.y, num5);
    num6 = fmaf(wA, p3.x, num6); num7 = fmaf(wA, p3.y, num7);
  }
  // combine the 4 subgroups within the half (offsets 8,16 stay inside 32 lanes)
  #pragma unroll
  for (int o = 8; o <= 16; o <<= 1) {
    num0 += __shfl_xor(num0, o); num1 += __shfl_xor(num1, o);
    num2 += __shfl_xor(num2, o); num3 += __shfl_xor(num3, o);
    num4 += __shfl_xor(num4, o); num5 += __shfl_xor(num5, o);
    num6 += __shfl_xor(num6, o); num7 += __shfl_xor(num7, o);
    ds += __shfl_xor(ds, o);
  }
  if (lh < 8) {
    float rd = 1.f / ds;
    int c8 = cl * 8;
    float4 bb0 = *(const float4*)&b2[c8];
    float4 bb1 = *(const float4*)&b2[c8 + 4];
    float v0 = num0 * rd + bb0.x, v1 = num1 * rd + bb0.y;
    float v2 = num2 * rd + bb0.z, v3 = num3 * rd + bb0.w;
    float v4 = num4 * rd + bb1.x, v5 = num5 * rd + bb1.y;
    float v6 = num6 * rd + bb1.z, v7 = num7 * rd + bb1.w;
    // log_softmax over 64 outputs held by 8 lanes x 8 regs (xor 1,2,4 stays in the 8-lane group)
    float mx = fmaxf(fmaxf(fmaxf(v0, v1), fmaxf(v2, v3)), fmaxf(fmaxf(v4, v5), fmaxf(v6, v7)));
    #pragma unroll
    for (int o = 1; o <= 4; o <<= 1) mx = fmaxf(mx, __shfl_xor(mx, o));
    float sum = __expf(v0 - mx) + __expf(v1 - mx) + __expf(v2 - mx) + __expf(v3 - mx)
              + __expf(v4 - mx) + __expf(v5 - mx) + __expf(v6 - mx) + __expf(v7 - mx);
    #pragma unroll
    for (int o = 1; o <= 4; o <<= 1) sum += __shfl_xor(sum, o);
    float ls = __logf(sum);
    float4 r0, r1;
    r0.x = (v0 - mx) - ls; r0.y = (v1 - mx) - ls; r0.z = (v2 - mx) - ls; r0.w = (v3 - mx) - ls;
    r1.x = (v4 - mx) - ls; r1.y = (v5 - mx) - ls; r1.z = (v6 - mx) - ls; r1.w = (v7 - mx) - ls;
    *(float4*)&out[(size_t)n * ODIM + c8] = r0;
    *(float4*)&out[(size_t)n * ODIM + c8 + 4] = r1;
  }
}

extern "C" void kernel_launch(void* const* d_in, const int* in_sizes, int n_in,
                              void* d_out, int out_size, void* d_ws, size_t ws_size,
                              hipStream_t stream) {
  const float* x   = (const float*)d_in[0];
  const void*  ei  = d_in[1];
  const float* W1  = (const float*)d_in[2];
  const float* as1 = (const float*)d_in[3];
  const float* ad1 = (const float*)d_in[4];
  const float* b1  = (const float*)d_in[5];
  const float* W2  = (const float*)d_in[6];
  const float* as2 = (const float*)d_in[7];
  const float* ad2 = (const float*)d_in[8];
  const float* b2  = (const float*)d_in[9];
  float* out = (float*)d_out;

  char* ws = (char*)d_ws;
  size_t o = 0;
  auto alloc = [&](size_t bytes) { void* p = (void*)(ws + o); o += (bytes + 255) & ~(size_t)255; return p; };
  ushort_t* h1b   = (ushort_t*)alloc((size_t)N_NODES * HID * 2);
  ushort_t* out1b = (ushort_t*)alloc((size_t)N_NODES * HID * 2);
  ushort_t* h2b   = (ushort_t*)alloc((size_t)N_NODES * ODIM * 2);
  unsigned char* h1f8 = (unsigned char*)alloc((size_t)N_NODES * HID);
  ushort_t* Wt1   = (ushort_t*)alloc((size_t)128 * 128 * 2);
  ushort_t* Wt2   = (ushort_t*)alloc((size_t)64 * 128 * 2);
  float* als1 = (float*)alloc((size_t)N_NODES * 4 * 4);
  float* ald1 = (float*)alloc((size_t)N_NODES * 4 * 4);
  float* als2 = (float*)alloc((size_t)N_NODES * 4);
  float* ald2 = (float*)alloc((size_t)N_NODES * 4);
  int*   degr = (int*)alloc((size_t)NREP * N_NODES * 4);
  int*   repbase = (int*)alloc((size_t)NREP * N_NODES * 4);
  int*   offs = (int*)alloc((size_t)(N_NODES + 1) * 4);
  int*   rank = (int*)alloc((size_t)E_TOT * 4);
  int*   srcs = (int*)alloc((size_t)E_TOT * 4);
  int*   bsums= (int*)alloc((size_t)NB1 * 4);
  int*   flag = (int*)alloc(4);
  // h2f8 (3.2 MB) aliases rank (3.4 MB): rank is dead after k_scatter
  unsigned char* h2f8 = (unsigned char*)rank;

  // k_prep: blocks 0..63 weight prep, 64 detect, 65.. zero degr (fused memset)
  int prepGrid = 65 + (NREP * N_NODES / 4 + 255) / 256;
  k_prep   <<<prepGrid, 256, 0, stream>>>(W1, W2, Wt1, Wt2, ei, flag, (int4*)degr);

  int egrid = (E_TOT + 255) / 256;
  k_hist   <<<egrid, 256, 0, stream>>>(ei, flag, degr, rank);
  k_scan1  <<<NB1,   256, 0, stream>>>(degr, offs, bsums);
  k_scan3  <<<NB1,   256, 0, stream>>>(offs, bsums, degr, repbase);
  k_scatter<<<egrid, 256, 0, stream>>>(ei, flag, repbase, rank, srcs);

  k_mm1  <<<512, 256, 0, stream>>>(x, Wt1, h1b, h1f8);
  k_al1  <<<N_NODES / 16, 256, 0, stream>>>(h1b, as1, ad1, als1, ald1);
  k_agg1 <<<N_NODES / 8, 256, 0, stream>>>(h1f8, als1, ald1, offs, srcs, b1, out1b);

  k_mm2  <<<512, 256, 0, stream>>>(out1b, Wt2, h2b, h2f8);
  k_al2  <<<(N_NODES + 31) / 32, 256, 0, stream>>>(h2b, as2, ad2, als2, ald2);
  k_agg2 <<<N_NODES / 8, 256, 0, stream>>>(h2f8, als2, ald2, offs, srcs, b2, out);
}

// Round 12
// 119.925 us; speedup vs baseline: 1.6908x; 1.1119x over previous
//
#include <hip/hip_runtime.h>
#include <hip/hip_bf16.h>
#include <math.h>

#define N_NODES 50000
#define N_EDGES 800000
#define E_TOT   (N_EDGES + N_NODES)
#define IN_DIM  128
#define HID     128      // HEADS*HIDDEN (layer-1 output width)
#define ODIM    64
#define NEG     0.2f
#define NB1     ((N_NODES + 255) / 256)   // scan blocks = 196
#define NCHUNK  ((N_NODES + 31) / 32)     // 32-node chunks for MFMA GEMMs
#define NREP    8
#define MM1B    512                        // mm1 blocks in the fused mm1+hist dispatch
#define EGRID   ((E_TOT + 255) / 256)      // hist/scatter blocks = 3321

typedef short bf16x8 __attribute__((ext_vector_type(8)));
typedef float f32x4 __attribute__((ext_vector_type(4)));
typedef float f32x2 __attribute__((ext_vector_type(2)));
typedef unsigned short ushort_t;

__device__ __forceinline__ float lrelu(float x) { return x >= 0.f ? x : NEG * x; }

// bf16 <-> f32 helpers (RNE rounding on store)
__device__ __forceinline__ unsigned short f2b(float v) {
  unsigned int b = __float_as_uint(v);
  b += 0x7fffu + ((b >> 16) & 1u);
  return (unsigned short)(b >> 16);
}
__device__ __forceinline__ unsigned int f2b2(float lo, float hi) {
  union { __hip_bfloat162 h; unsigned int u; } cv;
  cv.h = __float22bfloat162_rn(make_float2(lo, hi));
  return cv.u;
}
// fp8 e4m3 (OCP) hardware converts
__device__ __forceinline__ f32x2 f8x2lo(unsigned int v) {
  return __builtin_amdgcn_cvt_pk_f32_fp8((int)v, false);
}
__device__ __forceinline__ f32x2 f8x2hi(unsigned int v) {
  return __builtin_amdgcn_cvt_pk_f32_fp8((int)v, true);
}
__device__ __forceinline__ unsigned char f2f8(float v) {
  return (unsigned char)(__builtin_amdgcn_cvt_pk_fp8_f32(v, v, 0, false) & 0xff);
}

__device__ __forceinline__ int e_src(const void* ei, int f, int e) {
  if (e >= N_EDGES) return e - N_EDGES;              // self loop
  return f ? (int)((const long long*)ei)[e] : ((const int*)ei)[e];
}
__device__ __forceinline__ int e_dst(const void* ei, int f, int e) {
  if (e >= N_EDGES) return e - N_EDGES;              // self loop
  return f ? (int)((const long long*)ei)[N_EDGES + e] : ((const int*)ei)[N_EDGES + e];
}

// ---------- weight prep (bf16 W^T) + dtype detect + degr zero (fused memset) ----------
__global__ void k_prep(const float* __restrict__ W1, const float* __restrict__ W2,
                       ushort_t* __restrict__ Wt1, ushort_t* __restrict__ Wt2,
                       const void* ei, int* flag, int4* __restrict__ degr4) {
  if (blockIdx.x == 64) {
    if (threadIdx.x == 0) {
      const int* p = (const int*)ei;
      int allz = 1;
      for (int i = 0; i < 64; ++i) if (p[2 * i + 1] != 0) { allz = 0; break; }
      *flag = allz;  // 1 => buffer is int64
    }
    return;
  }
  if (blockIdx.x > 64) {   // zero degr: NREP*N_NODES ints = 100000 int4
    int i = (blockIdx.x - 65) * 256 + threadIdx.x;
    if (i < NREP * N_NODES / 4) degr4[i] = make_int4(0, 0, 0, 0);
    return;
  }
  int i = blockIdx.x * 256 + threadIdx.x;
  if (i < 128 * 128) { int k = i >> 7, n = i & 127; Wt1[n * 128 + k] = f2b(W1[i]); }
  if (i < 128 * 64)  { int k = i >> 6, n = i & 63;  Wt2[n * 128 + k] = f2b(W2[i]); }
}

__global__ void k_scan1(const int* __restrict__ degr, int* __restrict__ offs, int* __restrict__ bsums) {
  __shared__ int sm[256];
  int t = threadIdx.x, i = blockIdx.x * 256 + t;
  int v = 0;
  if (i < N_NODES) {
    #pragma unroll
    for (int r = 0; r < NREP; ++r) v += degr[r * N_NODES + i];
  }
  sm[t] = v;
  __syncthreads();
  for (int o = 1; o < 256; o <<= 1) {
    int add = (t >= o) ? sm[t - o] : 0;
    __syncthreads();
    sm[t] += add;
    __syncthreads();
  }
  if (i < N_NODES) offs[i] = sm[t] - v;   // exclusive (block-local)
  if (t == 255) bsums[blockIdx.x] = sm[255];
}

// finalize offs (recomputes bsums prefix in-block; no separate scan2) + per-replica bases
__global__ void k_scan3(int* __restrict__ offs, const int* __restrict__ bsums,
                        const int* __restrict__ degr, int* __restrict__ repbase) {
  __shared__ int red[4];
  int t = threadIdx.x;
  int v = (t < blockIdx.x) ? bsums[t] : 0;          // NB1 = 196 <= 256 threads
  #pragma unroll
  for (int o = 32; o >= 1; o >>= 1) v += __shfl_xor(v, o);
  if ((t & 63) == 0) red[t >> 6] = v;
  __syncthreads();
  int pre = red[0] + red[1] + red[2] + red[3];
  int i = blockIdx.x * 256 + t;
  if (i < N_NODES) {
    int o = offs[i] + pre;
    offs[i] = o;
    int run = o;
    #pragma unroll
    for (int r = 0; r < NREP; ++r) {
      repbase[r * N_NODES + i] = run;
      run += degr[r * N_NODES + i];
    }
  }
  if (i == 0) offs[N_NODES] = E_TOT;
}

__global__ void k_scatter(const void* ei, const int* __restrict__ flag,
                          const int* __restrict__ repbase,
                          const int* __restrict__ rank, int* __restrict__ srcs) {
  int e = blockIdx.x * 256 + threadIdx.x;
  if (e >= E_TOT) return;
  int f = *flag;
  int d = e_dst(ei, f, e);
  int r = blockIdx.x & (NREP - 1);
  srcs[repbase[r * N_NODES + d] + rank[e]] = e_src(ei, f, e);
}

// ---------- FUSED: MFMA GEMM1 (blocks < MM1B) + histogram (blocks >= MM1B) ----------
// GEMM1: h1f8(fp8) = fp8(bf16(x) @ W1); als1/ald1 computed in epilogue (no h1b buffer).
__global__ __launch_bounds__(256) void k_mm1h(const float* __restrict__ x,
                                              const ushort_t* __restrict__ Wt,
                                              unsigned char* __restrict__ h1f8,
                                              float* __restrict__ als1,
                                              float* __restrict__ ald1,
                                              const float* __restrict__ asrc,
                                              const float* __restrict__ adst,
                                              const void* ei, const int* __restrict__ flag,
                                              int* __restrict__ degr, int* __restrict__ rank) {
  if (blockIdx.x >= MM1B) {     // ---- histogram path ----
    int e = (blockIdx.x - MM1B) * 256 + threadIdx.x;
    if (e < E_TOT) {
      int r = (blockIdx.x - MM1B) & (NREP - 1);
      int d = e_dst(ei, *flag, e);
      rank[e] = atomicAdd(&degr[r * N_NODES + d], 1);
    }
    return;
  }
  // ---- GEMM1 path ----
  __shared__ ushort_t xs[32 * 128];   // 8 KB
  int t = threadIdx.x;
  int w = t >> 6, l = t & 63;
  int lr = l & 15, lk = l >> 4;
  int nodeSub = (w & 1) * 16, colBase = (w >> 1) * 64;
  int headBase = colBase >> 5;        // 0 or 2
  bf16x8 bfrag[4][4];
  #pragma unroll
  for (int ct = 0; ct < 4; ++ct)
    #pragma unroll
    for (int ks = 0; ks < 4; ++ks) {
      int n = colBase + ct * 16 + lr;
      int k = ks * 32 + lk * 8;
      bfrag[ct][ks] = *(const bf16x8*)&Wt[n * 128 + k];
    }
  // attention vectors for this lane's 4 columns (hoisted)
  float as0 = asrc[colBase + lr],      as1v = asrc[colBase + 16 + lr];
  float as2 = asrc[colBase + 32 + lr], as3 = asrc[colBase + 48 + lr];
  float ad0 = adst[colBase + lr],      ad1v = adst[colBase + 16 + lr];
  float ad2 = adst[colBase + 32 + lr], ad3 = adst[colBase + 48 + lr];
  int rr = t >> 3, c0 = (t & 7) * 16;   // staging: row, 16-elem col group
  for (int chunk = blockIdx.x; chunk < NCHUNK; chunk += MM1B) {
    int base = chunk * 32;
    int srcRow = base + rr; if (srcRow >= N_NODES) srcRow = N_NODES - 1;
    const float4* xr = (const float4*)&x[(size_t)srcRow * IN_DIM + c0];
    float4 f0 = xr[0], f1 = xr[1], f2 = xr[2], f3 = xr[3];
    uint4 w0, w1;
    w0.x = f2b2(f0.x, f0.y); w0.y = f2b2(f0.z, f0.w);
    w0.z = f2b2(f1.x, f1.y); w0.w = f2b2(f1.z, f1.w);
    w1.x = f2b2(f2.x, f2.y); w1.y = f2b2(f2.z, f2.w);
    w1.z = f2b2(f3.x, f3.y); w1.w = f2b2(f3.z, f3.w);
    char* xsb = (char*)xs;
    int swz = (rr & 7) << 4;
    *(uint4*)(xsb + rr * 256 + ((c0 * 2 +  0) ^ swz)) = w0;
    *(uint4*)(xsb + rr * 256 + ((c0 * 2 + 16) ^ swz)) = w1;
    __syncthreads();
    f32x4 acc[4] = {{0,0,0,0},{0,0,0,0},{0,0,0,0},{0,0,0,0}};
    int arow = nodeSub + lr;
    #pragma unroll
    for (int ks = 0; ks < 4; ++ks) {
      bf16x8 a = *(const bf16x8*)((const char*)xs + arow * 256 +
                                  ((ks * 64 + lk * 16) ^ ((arow & 7) << 4)));
      #pragma unroll
      for (int ct = 0; ct < 4; ++ct)
        acc[ct] = __builtin_amdgcn_mfma_f32_16x16x32_bf16(a, bfrag[ct][ks], acc[ct], 0, 0, 0);
    }
    __syncthreads();
    #pragma unroll
    for (int r = 0; r < 4; ++r) {
      int node = base + nodeSub + lk * 4 + r;
      // fp8 stores (4 cols/lane for this r)
      if (node < N_NODES) {
        h1f8[(size_t)node * HID + colBase +      lr] = f2f8(acc[0][r]);
        h1f8[(size_t)node * HID + colBase + 16 + lr] = f2f8(acc[1][r]);
        h1f8[(size_t)node * HID + colBase + 32 + lr] = f2f8(acc[2][r]);
        h1f8[(size_t)node * HID + colBase + 48 + lr] = f2f8(acc[3][r]);
      }
      // attention-logit partials: heads headBase (ct 0,1) and headBase+1 (ct 2,3)
      float s01 = acc[0][r] * as0 + acc[1][r] * as1v;
      float s23 = acc[2][r] * as2 + acc[3][r] * as3;
      float d01 = acc[0][r] * ad0 + acc[1][r] * ad1v;
      float d23 = acc[2][r] * ad2 + acc[3][r] * ad3;
      #pragma unroll
      for (int o = 1; o <= 8; o <<= 1) {
        s01 += __shfl_xor(s01, o); s23 += __shfl_xor(s23, o);
        d01 += __shfl_xor(d01, o); d23 += __shfl_xor(d23, o);
      }
      if (lr == 0 && node < N_NODES) {
        als1[node * 4 + headBase]     = s01;
        als1[node * 4 + headBase + 1] = s23;
        ald1[node * 4 + headBase]     = d01;
        ald1[node * 4 + headBase + 1] = d23;
      }
    }
  }
}

// ---------- MFMA GEMM2: h2f8(fp8) = fp8(out1b @ W2); als2/ald2 fused in epilogue ----------
__global__ __launch_bounds__(256) void k_mm2(const ushort_t* __restrict__ xb,
                                             const ushort_t* __restrict__ Wt,
                                             unsigned char* __restrict__ h2f8,
                                             float* __restrict__ als2,
                                             float* __restrict__ ald2,
                                             const float* __restrict__ asrc,
                                             const float* __restrict__ adst) {
  __shared__ ushort_t xs[32 * 128];   // 8 KB
  __shared__ float als_lds[32], ald_lds[32];
  int t = threadIdx.x;
  int w = t >> 6, l = t & 63;
  int lr = l & 15, lk = l >> 4;
  int nodeSub = (w & 1) * 16, colBase = (w >> 1) * 32;
  bf16x8 bfrag[2][4];
  #pragma unroll
  for (int ct = 0; ct < 2; ++ct)
    #pragma unroll
    for (int ks = 0; ks < 4; ++ks) {
      int n = colBase + ct * 16 + lr;
      int k = ks * 32 + lk * 8;
      bfrag[ct][ks] = *(const bf16x8*)&Wt[n * 128 + k];
    }
  float as0 = asrc[colBase + lr], as1v = asrc[colBase + 16 + lr];
  float ad0 = adst[colBase + lr], ad1v = adst[colBase + 16 + lr];
  int rr = t >> 3, c0 = (t & 7) * 16;
  for (int chunk = blockIdx.x; chunk < NCHUNK; chunk += gridDim.x) {
    int base = chunk * 32;
    int srcRow = base + rr; if (srcRow >= N_NODES) srcRow = N_NODES - 1;
    const uint4* xr = (const uint4*)&xb[(size_t)srcRow * HID + c0];
    uint4 w0 = xr[0], w1 = xr[1];
    char* xsb = (char*)xs;
    int swz = (rr & 7) << 4;
    *(uint4*)(xsb + rr * 256 + ((c0 * 2 +  0) ^ swz)) = w0;
    *(uint4*)(xsb + rr * 256 + ((c0 * 2 + 16) ^ swz)) = w1;
    __syncthreads();
    f32x4 acc[2] = {{0,0,0,0},{0,0,0,0}};
    int arow = nodeSub + lr;
    #pragma unroll
    for (int ks = 0; ks < 4; ++ks) {
      bf16x8 a = *(const bf16x8*)((const char*)xs + arow * 256 +
                                  ((ks * 64 + lk * 16) ^ ((arow & 7) << 4)));
      #pragma unroll
      for (int ct = 0; ct < 2; ++ct)
        acc[ct] = __builtin_amdgcn_mfma_f32_16x16x32_bf16(a, bfrag[ct][ks], acc[ct], 0, 0, 0);
    }
    if (t < 32) { als_lds[t] = 0.f; ald_lds[t] = 0.f; }
    __syncthreads();
    #pragma unroll
    for (int r = 0; r < 4; ++r) {
      int nodeLocal = nodeSub + lk * 4 + r;
      int node = base + nodeLocal;
      if (node < N_NODES) {
        h2f8[(size_t)node * ODIM + colBase +      lr] = f2f8(acc[0][r]);
        h2f8[(size_t)node * ODIM + colBase + 16 + lr] = f2f8(acc[1][r]);
      }
      float s = acc[0][r] * as0 + acc[1][r] * as1v;
      float d = acc[0][r] * ad0 + acc[1][r] * ad1v;
      #pragma unroll
      for (int o = 1; o <= 8; o <<= 1) {
        s += __shfl_xor(s, o);
        d += __shfl_xor(d, o);
      }
      if (lr == 0) {
        atomicAdd(&als_lds[nodeLocal], s);   // two colBase waves combine here
        atomicAdd(&ald_lds[nodeLocal], d);
      }
    }
    __syncthreads();
    if (t < 32) {
      int node = base + t;
      if (node < N_NODES) { als2[node] = als_lds[t]; ald2[node] = ald_lds[t]; }
    }
  }
}

// ---------- layer-1 aggregate: TWO nodes per wave; SUBGROUP-UNIFORM loads (no bpermute) ----------
__global__ __launch_bounds__(256) void k_agg1(const unsigned char* __restrict__ h1f8,
                                              const float* __restrict__ als,
                                              const float* __restrict__ ald, const int* __restrict__ offs,
                                              const int* __restrict__ srcs, const float* __restrict__ b1,
                                              ushort_t* __restrict__ out1b) {
  int t = threadIdx.x;
  int w = t >> 6, l = t & 63;
  int hw = l >> 5, lh = l & 31;          // half index, lane-in-half
  int sg = lh >> 4, cl = lh & 15, head = cl >> 2;
  int n = blockIdx.x * 8 + w * 2 + hw;   // grid = N/8 = 6250 exact
  int off0 = offs[n], deg = offs[n + 1] - off0;
  float adh = ald[n * 4 + head];
  const unsigned char* hb = h1f8 + cl * 8;

  float ds = 0.f;
  float num0 = 0, num1 = 0, num2 = 0, num3 = 0, num4 = 0, num5 = 0, num6 = 0, num7 = 0;

  int j = sg;
  for (; j + 2 < deg; j += 4) {
    int sA = srcs[off0 + j];
    int sB = srcs[off0 + j + 2];
    float aA = als[sA * 4 + head];
    float aB = als[sB * 4 + head];
    uint2 vA = *(const uint2*)(hb + (sA << 7));
    uint2 vB = *(const uint2*)(hb + (sB << 7));
    float wA = __expf(lrelu(aA + adh));
    float wB = __expf(lrelu(aB + adh));
    ds += wA + wB;
    f32x2 p0 = f8x2lo(vA.x), p1 = f8x2hi(vA.x);
    f32x2 p2 = f8x2lo(vA.y), p3 = f8x2hi(vA.y);
    num0 = fmaf(wA, p0.x, num0); num1 = fmaf(wA, p0.y, num1);
    num2 = fmaf(wA, p1.x, num2); num3 = fmaf(wA, p1.y, num3);
    num4 = fmaf(wA, p2.x, num4); num5 = fmaf(wA, p2.y, num5);
    num6 = fmaf(wA, p3.x, num6); num7 = fmaf(wA, p3.y, num7);
    p0 = f8x2lo(vB.x); p1 = f8x2hi(vB.x);
    p2 = f8x2lo(vB.y); p3 = f8x2hi(vB.y);
    num0 = fmaf(wB, p0.x, num0); num1 = fmaf(wB, p0.y, num1);
    num2 = fmaf(wB, p1.x, num2); num3 = fmaf(wB, p1.y, num3);
    num4 = fmaf(wB, p2.x, num4); num5 = fmaf(wB, p2.y, num5);
    num6 = fmaf(wB, p3.x, num6); num7 = fmaf(wB, p3.y, num7);
  }
  if (j < deg) {
    int sA = srcs[off0 + j];
    float aA = als[sA * 4 + head];
    uint2 vA = *(const uint2*)(hb + (sA << 7));
    float wA = __expf(lrelu(aA + adh));
    ds += wA;
    f32x2 p0 = f8x2lo(vA.x), p1 = f8x2hi(vA.x);
    f32x2 p2 = f8x2lo(vA.y), p3 = f8x2hi(vA.y);
    num0 = fmaf(wA, p0.x, num0); num1 = fmaf(wA, p0.y, num1);
    num2 = fmaf(wA, p1.x, num2); num3 = fmaf(wA, p1.y, num3);
    num4 = fmaf(wA, p2.x, num4); num5 = fmaf(wA, p2.y, num5);
    num6 = fmaf(wA, p3.x, num6); num7 = fmaf(wA, p3.y, num7);
  }
  num0 += __shfl_xor(num0, 16); num1 += __shfl_xor(num1, 16);
  num2 += __shfl_xor(num2, 16); num3 += __shfl_xor(num3, 16);
  num4 += __shfl_xor(num4, 16); num5 += __shfl_xor(num5, 16);
  num6 += __shfl_xor(num6, 16); num7 += __shfl_xor(num7, 16);
  ds += __shfl_xor(ds, 16);
  if (lh < 16) {
    float rd = 1.f / ds;
    int c8 = cl * 8;
    float4 bb0 = *(const float4*)&b1[c8];
    float4 bb1 = *(const float4*)&b1[c8 + 4];
    float o0 = fmaxf(num0 * rd + bb0.x, 0.f);
    float o1 = fmaxf(num1 * rd + bb0.y, 0.f);
    float o2 = fmaxf(num2 * rd + bb0.z, 0.f);
    float o3 = fmaxf(num3 * rd + bb0.w, 0.f);
    float o4 = fmaxf(num4 * rd + bb1.x, 0.f);
    float o5 = fmaxf(num5 * rd + bb1.y, 0.f);
    float o6 = fmaxf(num6 * rd + bb1.z, 0.f);
    float o7 = fmaxf(num7 * rd + bb1.w, 0.f);
    uint4 pk;
    pk.x = f2b2(o0, o1); pk.y = f2b2(o2, o3);
    pk.z = f2b2(o4, o5); pk.w = f2b2(o6, o7);
    *(uint4*)&out1b[(size_t)n * HID + c8] = pk;
  }
}

// ---------- layer-2 aggregate + log_softmax: TWO nodes per wave; subgroup-uniform loads ----------
__global__ __launch_bounds__(256) void k_agg2(const unsigned char* __restrict__ h2f8,
                                              const float* __restrict__ als,
                                              const float* __restrict__ ald, const int* __restrict__ offs,
                                              const int* __restrict__ srcs, const float* __restrict__ b2,
                                              float* __restrict__ out) {
  int t = threadIdx.x;
  int w = t >> 6, l = t & 63;
  int hw = l >> 5, lh = l & 31;
  int sg = lh >> 3, cl = lh & 7;
  int n = blockIdx.x * 8 + w * 2 + hw;
  int off0 = offs[n], deg = offs[n + 1] - off0;
  float adv = ald[n];
  const unsigned char* hb = h2f8 + cl * 8;

  float ds = 0.f;
  float num0 = 0, num1 = 0, num2 = 0, num3 = 0, num4 = 0, num5 = 0, num6 = 0, num7 = 0;

  int j = sg;
  for (; j + 4 < deg; j += 8) {
    int sA = srcs[off0 + j];
    int sB = srcs[off0 + j + 4];
    float aA = als[sA];
    float aB = als[sB];
    uint2 vA = *(const uint2*)(hb + (sA << 6));
    uint2 vB = *(const uint2*)(hb + (sB << 6));
    float wA = __expf(lrelu(aA + adv));
    float wB = __expf(lrelu(aB + adv));
    ds += wA + wB;
    f32x2 p0 = f8x2lo(vA.x), p1 = f8x2hi(vA.x);
    f32x2 p2 = f8x2lo(vA.y), p3 = f8x2hi(vA.y);
    num0 = fmaf(wA, p0.x, num0); num1 = fmaf(wA, p0.y, num1);
    num2 = fmaf(wA, p1.x, num2); num3 = fmaf(wA, p1.y, num3);
    num4 = fmaf(wA, p2.x, num4); num5 = fmaf(wA, p2.y, num5);
    num6 = fmaf(wA, p3.x, num6); num7 = fmaf(wA, p3.y, num7);
    p0 = f8x2lo(vB.x); p1 = f8x2hi(vB.x);
    p2 = f8x2lo(vB.y); p3 = f8x2hi(vB.y);
    num0 = fmaf(wB, p0.x, num0); num1 = fmaf(wB, p0.y, num1);
    num2 = fmaf(wB, p1.x, num2); num3 = fmaf(wB, p1.y, num3);
    num4 = fmaf(wB, p2.x, num4); num5 = fmaf(wB, p2.y, num5);
    num6 = fmaf(wB, p3.x, num6); num7 = fmaf(wB, p3.y, num7);
  }
  if (j < deg) {
    int sA = srcs[off0 + j];
    float aA = als[sA];
    uint2 vA = *(const uint2*)(hb + (sA << 6));
    float wA = __expf(lrelu(aA + adv));
    ds += wA;
    f32x2 p0 = f8x2lo(vA.x), p1 = f8x2hi(vA.x);
    f32x2 p2 = f8x2lo(vA.y), p3 = f8x2hi(vA.y);
    num0 = fmaf(wA, p0.x, num0); num1 = fmaf(wA, p0.y, num1);
    num2 = fmaf(wA, p1.x, num2); num3 = fmaf(wA, p1.y, num3);
    num4 = fmaf(wA, p2.x, num4); num5 = fmaf(wA, p2.y, num5);
    num6 = fmaf(wA, p3.x, num6); num7 = fmaf(wA, p3.y, num7);
  }
  #pragma unroll
  for (int o = 8; o <= 16; o <<= 1) {
    num0 += __shfl_xor(num0, o); num1 += __shfl_xor(num1, o);
    num2 += __shfl_xor(num2, o); num3 += __shfl_xor(num3, o);
    num4 += __shfl_xor(num4, o); num5 += __shfl_xor(num5, o);
    num6 += __shfl_xor(num6, o); num7 += __shfl_xor(num7, o);
    ds += __shfl_xor(ds, o);
  }
  if (lh < 8) {
    float rd = 1.f / ds;
    int c8 = cl * 8;
    float4 bb0 = *(const float4*)&b2[c8];
    float4 bb1 = *(const float4*)&b2[c8 + 4];
    float v0 = num0 * rd + bb0.x, v1 = num1 * rd + bb0.y;
    float v2 = num2 * rd + bb0.z, v3 = num3 * rd + bb0.w;
    float v4 = num4 * rd + bb1.x, v5 = num5 * rd + bb1.y;
    float v6 = num6 * rd + bb1.z, v7 = num7 * rd + bb1.w;
    float mx = fmaxf(fmaxf(fmaxf(v0, v1), fmaxf(v2, v3)), fmaxf(fmaxf(v4, v5), fmaxf(v6, v7)));
    #pragma unroll
    for (int o = 1; o <= 4; o <<= 1) mx = fmaxf(mx, __shfl_xor(mx, o));
    float sum = __expf(v0 - mx) + __expf(v1 - mx) + __expf(v2 - mx) + __expf(v3 - mx)
              + __expf(v4 - mx) + __expf(v5 - mx) + __expf(v6 - mx) + __expf(v7 - mx);
    #pragma unroll
    for (int o = 1; o <= 4; o <<= 1) sum += __shfl_xor(sum, o);
    float ls = __logf(sum);
    float4 r0, r1;
    r0.x = (v0 - mx) - ls; r0.y = (v1 - mx) - ls; r0.z = (v2 - mx) - ls; r0.w = (v3 - mx) - ls;
    r1.x = (v4 - mx) - ls; r1.y = (v5 - mx) - ls; r1.z = (v6 - mx) - ls; r1.w = (v7 - mx) - ls;
    *(float4*)&out[(size_t)n * ODIM + c8] = r0;
    *(float4*)&out[(size_t)n * ODIM + c8 + 4] = r1;
  }
}

extern "C" void kernel_launch(void* const* d_in, const int* in_sizes, int n_in,
                              void* d_out, int out_size, void* d_ws, size_t ws_size,
                              hipStream_t stream) {
  const float* x   = (const float*)d_in[0];
  const void*  ei  = d_in[1];
  const float* W1  = (const float*)d_in[2];
  const float* as1 = (const float*)d_in[3];
  const float* ad1 = (const float*)d_in[4];
  const float* b1  = (const float*)d_in[5];
  const float* W2  = (const float*)d_in[6];
  const float* as2 = (const float*)d_in[7];
  const float* ad2 = (const float*)d_in[8];
  const float* b2  = (const float*)d_in[9];
  float* out = (float*)d_out;

  char* ws = (char*)d_ws;
  size_t o = 0;
  auto alloc = [&](size_t bytes) { void* p = (void*)(ws + o); o += (bytes + 255) & ~(size_t)255; return p; };
  ushort_t* out1b = (ushort_t*)alloc((size_t)N_NODES * HID * 2);
  unsigned char* h1f8 = (unsigned char*)alloc((size_t)N_NODES * HID);
  ushort_t* Wt1   = (ushort_t*)alloc((size_t)128 * 128 * 2);
  ushort_t* Wt2   = (ushort_t*)alloc((size_t)64 * 128 * 2);
  float* als1 = (float*)alloc((size_t)N_NODES * 4 * 4);
  float* ald1 = (float*)alloc((size_t)N_NODES * 4 * 4);
  float* als2 = (float*)alloc((size_t)N_NODES * 4);
  float* ald2 = (float*)alloc((size_t)N_NODES * 4);
  int*   degr = (int*)alloc((size_t)NREP * N_NODES * 4);
  int*   repbase = (int*)alloc((size_t)NREP * N_NODES * 4);
  int*   offs = (int*)alloc((size_t)(N_NODES + 1) * 4);
  int*   rank = (int*)alloc((size_t)E_TOT * 4);
  int*   srcs = (int*)alloc((size_t)E_TOT * 4);
  int*   bsums= (int*)alloc((size_t)NB1 * 4);
  int*   flag = (int*)alloc(4);
  // h2f8 (3.2 MB) aliases rank (3.4 MB): rank is dead after k_scatter
  unsigned char* h2f8 = (unsigned char*)rank;

  // k_prep: blocks 0..63 weight prep, 64 detect, 65.. zero degr (fused memset)
  int prepGrid = 65 + (NREP * N_NODES / 4 + 255) / 256;
  k_prep   <<<prepGrid, 256, 0, stream>>>(W1, W2, Wt1, Wt2, ei, flag, (int4*)degr);

  // fused GEMM1 + histogram (data-independent, run concurrently)
  k_mm1h   <<<MM1B + EGRID, 256, 0, stream>>>(x, Wt1, h1f8, als1, ald1, as1, ad1,
                                              ei, flag, degr, rank);
  k_scan1  <<<NB1, 256, 0, stream>>>(degr, offs, bsums);
  k_scan3  <<<NB1, 256, 0, stream>>>(offs, bsums, degr, repbase);
  k_scatter<<<EGRID, 256, 0, stream>>>(ei, flag, repbase, rank, srcs);

  k_agg1 <<<N_NODES / 8, 256, 0, stream>>>(h1f8, als1, ald1, offs, srcs, b1, out1b);

  k_mm2  <<<512, 256, 0, stream>>>(out1b, Wt2, h2f8, als2, ald2, as2, ad2);
  k_agg2 <<<N_NODES / 8, 256, 0, stream>>>(h2f8, als2, ald2, offs, srcs, b2, out);
}